// Round 8
// baseline (477.243 us; speedup 1.0000x reference)
//
#include <hip/hip_runtime.h>

#define N_NODES 50000
#define N_EDGES 800000
#define DIM 64
#define N_LAYERS 3
#define N_GRAPHS 256
#define BN_EPS 1e-5f
#define D3 (DIM * N_LAYERS)
#define N_PART 64
#define NBKT 782          // ceil(50000/64) destination buckets
#define ECAP 2048         // fixed capacity per bucket (mean 1023, sigma ~32)
#define CAP 2048          // LDS staging capacity in bucket_sort

typedef __attribute__((ext_vector_type(8))) short short8;
typedef __attribute__((ext_vector_type(4))) float floatx4;

// ---------------------------------------------------------- bf16 split utils
__device__ inline unsigned short bf16_rn(float f) {
    unsigned u = __float_as_uint(f);
    u += 0x7FFF + ((u >> 16) & 1);
    return (unsigned short)(u >> 16);
}
__device__ inline float bf16_f(unsigned short b) {
    return __uint_as_float(((unsigned)b) << 16);
}
__device__ inline void split8(float4 a, float4 b, short8* hi, short8* lo) {
    float v[8] = {a.x, a.y, a.z, a.w, b.x, b.y, b.z, b.w};
#pragma unroll
    for (int i = 0; i < 8; i++) {
        unsigned short h = bf16_rn(v[i]);
        (*hi)[i] = (short)h;
        (*lo)[i] = (short)bf16_rn(v[i] - bf16_f(h));
    }
}

// ---------------- direct partition: 1 edge/thread, fixed-capacity buckets
__global__ __launch_bounds__(256) void part_direct(const int* __restrict__ src,
                                                   const int* __restrict__ dst,
                                                   int* __restrict__ bcnt,
                                                   unsigned* __restrict__ ebuf) {
    int e = blockIdx.x * 256 + threadIdx.x;
    if (e >= N_EDGES) return;
    int d = dst[e];
    int b = d >> 6;
    int pos = atomicAdd(&bcnt[b], 1);
    if (pos < ECAP)
        ebuf[(size_t)b * ECAP + pos] = ((unsigned)src[e] << 6) | (unsigned)(d & 63);
}

// ------------------------------- exclusive scan of 782 bucket counts
__global__ __launch_bounds__(1024) void scan_small(const int* __restrict__ bcnt,
                                                   int* __restrict__ bstart) {
    __shared__ int s[1024];
    int t = threadIdx.x;
    int v = (t < NBKT) ? bcnt[t] : 0;
    s[t] = v;
    __syncthreads();
    for (int off = 1; off < 1024; off <<= 1) {
        int u = (t >= off) ? s[t - off] : 0;
        __syncthreads();
        s[t] += u;
        __syncthreads();
    }
    if (t < NBKT) bstart[t] = s[t] - v;
    if (t == NBKT - 1) bstart[NBKT] = s[t];
}

// --------- counting-sort each bucket's edges by dst&63 -> per-node CSR + rp
__global__ __launch_bounds__(256) void bucket_sort(const unsigned* __restrict__ ebuf,
                                                   const int* __restrict__ bstart,
                                                   int* __restrict__ csr,
                                                   int* __restrict__ rp) {
    __shared__ unsigned ent[CAP];
    __shared__ int cnt[64], basea[64], fill[64];
    int b = blockIdx.x, tid = threadIdx.x;
    int start = bstart[b];
    int T = bstart[b + 1] - start;
    const unsigned* eb = ebuf + (size_t)b * ECAP;
    if (tid < 64) cnt[tid] = 0;
    for (int i = tid; i < T; i += 256) ent[i] = eb[i];
    __syncthreads();
    for (int i = tid; i < T; i += 256) atomicAdd(&cnt[ent[i] & 63], 1);
    __syncthreads();
    if (tid < 64) {
        int v = cnt[tid], x = v;
#pragma unroll
        for (int off = 1; off < 64; off <<= 1) {
            int y = __shfl_up(x, off);
            if (tid >= off) x += y;
        }
        basea[tid] = x - v;
        fill[tid] = 0;
        rp[b * 64 + tid] = start + x - v;
    }
    __syncthreads();
    for (int i = tid; i < T; i += 256) {
        unsigned e = ent[i];
        int c = e & 63;
        int pos = basea[c] + atomicAdd(&fill[c], 1);
        csr[start + pos] = (int)(e >> 6);
    }
}

// -------------------------------------------- per-graph node counts (sorted)
__global__ __launch_bounds__(256) void count_graphs(const int* __restrict__ batch,
                                                    int* __restrict__ cntg) {
    int grp = blockIdx.x * 256 + threadIdx.x;
    if (grp >= N_NODES / 8) return;
    int n0 = grp * 8, run = 0, cur = batch[n0];
#pragma unroll
    for (int r = 0; r < 8; r++) {
        int b = batch[n0 + r];
        if (b != cur) { atomicAdd(&cntg[cur], run); run = 0; cur = b; }
        run++;
    }
    atomicAdd(&cntg[cur], run);
}

// -------- gather + prev-layer BN affine: z[i] = sc*(h[i]+sum h[j]) + (1+deg)*sh
__global__ __launch_bounds__(256) void gather_kernel(const float* __restrict__ h,
                                                     float* __restrict__ z,
                                                     const int* __restrict__ rp,
                                                     const int* __restrict__ csr,
                                                     const float* __restrict__ ss) {
    int node = blockIdx.x * 4 + (threadIdx.x >> 6);
    if (node >= N_NODES) return;
    int lane = threadIdx.x & 63;
    float acc = h[(size_t)node * DIM + lane];
    int e = rp[node], end = rp[node + 1];
    float degf = 1.f + (float)(end - e);
    for (; e + 8 <= end; e += 8) {
        int s0 = csr[e],     s1 = csr[e + 1], s2 = csr[e + 2], s3 = csr[e + 3];
        int s4 = csr[e + 4], s5 = csr[e + 5], s6 = csr[e + 6], s7 = csr[e + 7];
        float v0 = h[(size_t)s0 * DIM + lane];
        float v1 = h[(size_t)s1 * DIM + lane];
        float v2 = h[(size_t)s2 * DIM + lane];
        float v3 = h[(size_t)s3 * DIM + lane];
        float v4 = h[(size_t)s4 * DIM + lane];
        float v5 = h[(size_t)s5 * DIM + lane];
        float v6 = h[(size_t)s6 * DIM + lane];
        float v7 = h[(size_t)s7 * DIM + lane];
        acc += ((v0 + v1) + (v2 + v3)) + ((v4 + v5) + (v6 + v7));
    }
    for (; e < end; e++) acc += h[(size_t)csr[e] * DIM + lane];
    if (ss) acc = fmaf(acc, ss[lane], degf * ss[DIM + lane]);
    z[(size_t)node * DIM + lane] = acc;
}

// --------------- pack W1/W2 into MFMA B-operand fragments, split bf16 hi/lo
__global__ __launch_bounds__(256) void prep_weights(const float* __restrict__ W1,
                                                    const float* __restrict__ W2,
                                                    unsigned short* __restrict__ wf) {
    int idx = blockIdx.x * 256 + threadIdx.x;
    if (idx >= N_LAYERS * 2 * 4096) return;
    int j    = idx & 7;
    int lane = (idx >> 3) & 63;
    int ks   = (idx >> 9) & 1;
    int nt   = (idx >> 10) & 3;
    int gemm = (idx >> 12) & 1;
    int layer = idx >> 13;
    int n = nt * 16 + (lane & 15);
    int k = ks * 32 + (lane >> 4) * 8 + j;
    const float* W = (gemm ? W2 : W1) + (size_t)layer * DIM * DIM;
    float w = W[k * DIM + n];
    unsigned short hi = bf16_rn(w);
    unsigned short lo = bf16_rn(w - bf16_f(hi));
    size_t base = ((size_t)layer * 2 + gemm) * 8192;
    int f = nt * 2 + ks;
    wf[base + f * 512 + lane * 8 + j]        = hi;
    wf[base + 4096 + f * 512 + lane * 8 + j] = lo;
}

// ------- MFMA MLP: raw z' = relu(relu(zW1+B1)W2+B2) + BN partials + raw pool
#define HS_STRIDE 68
__global__ __launch_bounds__(256) void mlp_mfma(float* __restrict__ z,
    const unsigned short* __restrict__ wfL,
    const float* __restrict__ B1, const float* __restrict__ B2,
    float* __restrict__ sums_part, float* __restrict__ praw,
    const int* __restrict__ batch, int write_z) {
    __shared__ float sH[4][16 * HS_STRIDE];
    __shared__ float sSum[2 * DIM];
    __shared__ int   sBatch[64];

    int tid = threadIdx.x, wave = tid >> 6, lane = tid & 63;
    int blk0 = blockIdx.x * 64;
    if (tid < 2 * DIM) sSum[tid] = 0.f;
    if (tid < 64) sBatch[tid] = (blk0 + tid < N_NODES) ? batch[blk0 + tid] : -1;
    __syncthreads();

    int m = lane & 15, quad = lane >> 4;
    int row0 = blk0 + wave * 16;
    int grow = row0 + m;
    int ar = grow < N_NODES ? grow : N_NODES - 1;

    const float4* zr = (const float4*)(z + (size_t)ar * DIM);
    float4 a0 = zr[quad * 2],     a1 = zr[quad * 2 + 1];
    float4 a2 = zr[8 + quad * 2], a3 = zr[8 + quad * 2 + 1];
    short8 Ah0, Al0, Ah1, Al1;
    split8(a0, a1, &Ah0, &Al0);
    split8(a2, a3, &Ah1, &Al1);

    floatx4 acc[4];
#pragma unroll
    for (int nt = 0; nt < 4; nt++) acc[nt] = (floatx4){0.f, 0.f, 0.f, 0.f};
#pragma unroll
    for (int nt = 0; nt < 4; nt++) {
#pragma unroll
        for (int ks = 0; ks < 2; ks++) {
            const short8 Bh = *(const short8*)(wfL + (nt * 2 + ks) * 512 + lane * 8);
            const short8 Bl = *(const short8*)(wfL + 4096 + (nt * 2 + ks) * 512 + lane * 8);
            short8 Ahf = ks ? Ah1 : Ah0;
            short8 Alf = ks ? Al1 : Al0;
            acc[nt] = __builtin_amdgcn_mfma_f32_16x16x32_bf16(Ahf, Bh, acc[nt], 0, 0, 0);
            acc[nt] = __builtin_amdgcn_mfma_f32_16x16x32_bf16(Ahf, Bl, acc[nt], 0, 0, 0);
            acc[nt] = __builtin_amdgcn_mfma_f32_16x16x32_bf16(Alf, Bh, acc[nt], 0, 0, 0);
        }
    }

    float* Hs = sH[wave];
#pragma unroll
    for (int nt = 0; nt < 4; nt++) {
        int col = nt * 16 + m;
        float b = B1[col];
#pragma unroll
        for (int r = 0; r < 4; r++) {
            int lr = quad * 4 + r;
            Hs[lr * HS_STRIDE + col] = fmaxf(acc[nt][r] + b, 0.f);
        }
    }
    float4 h0 = *(const float4*)&Hs[m * HS_STRIDE + quad * 8];
    float4 h1 = *(const float4*)&Hs[m * HS_STRIDE + quad * 8 + 4];
    float4 h2 = *(const float4*)&Hs[m * HS_STRIDE + 32 + quad * 8];
    float4 h3 = *(const float4*)&Hs[m * HS_STRIDE + 32 + quad * 8 + 4];
    short8 Hh0, Hl0, Hh1, Hl1;
    split8(h0, h1, &Hh0, &Hl0);
    split8(h2, h3, &Hh1, &Hl1);

    floatx4 acc2[4];
#pragma unroll
    for (int nt = 0; nt < 4; nt++) acc2[nt] = (floatx4){0.f, 0.f, 0.f, 0.f};
    const unsigned short* wg2 = wfL + 8192;
#pragma unroll
    for (int nt = 0; nt < 4; nt++) {
#pragma unroll
        for (int ks = 0; ks < 2; ks++) {
            const short8 Bh = *(const short8*)(wg2 + (nt * 2 + ks) * 512 + lane * 8);
            const short8 Bl = *(const short8*)(wg2 + 4096 + (nt * 2 + ks) * 512 + lane * 8);
            short8 Ahf = ks ? Hh1 : Hh0;
            short8 Alf = ks ? Hl1 : Hl0;
            acc2[nt] = __builtin_amdgcn_mfma_f32_16x16x32_bf16(Ahf, Bh, acc2[nt], 0, 0, 0);
            acc2[nt] = __builtin_amdgcn_mfma_f32_16x16x32_bf16(Ahf, Bl, acc2[nt], 0, 0, 0);
            acc2[nt] = __builtin_amdgcn_mfma_f32_16x16x32_bf16(Alf, Bh, acc2[nt], 0, 0, 0);
        }
    }

    // ---- epilogue: raw z write + BN partials + per-graph raw pooling
    int widx = wave * 16;
    int gfirst = sBatch[widx], glast = sBatch[widx + 15];
    bool uni = (gfirst == glast) && (gfirst >= 0);
#pragma unroll
    for (int nt = 0; nt < 4; nt++) {
        int col = nt * 16 + m;
        float b = B2[col];
        float vv[4];
        float s = 0.f, s2 = 0.f;
#pragma unroll
        for (int r = 0; r < 4; r++) {
            int gr = row0 + quad * 4 + r;
            float v = fmaxf(acc2[nt][r] + b, 0.f);
            if (gr < N_NODES) {
                if (write_z) z[(size_t)gr * DIM + col] = v;
                s += v;
                s2 = fmaf(v, v, s2);
                vv[r] = v;
            } else {
                vv[r] = 0.f;
            }
        }
        float sf = s, s2f = s2;
        sf  += __shfl_xor(sf, 16);  sf  += __shfl_xor(sf, 32);
        s2f += __shfl_xor(s2f, 16); s2f += __shfl_xor(s2f, 32);
        if (quad == 0) {
            atomicAdd(&sSum[col], sf);
            atomicAdd(&sSum[DIM + col], s2f);
            if (uni) atomicAdd(&praw[(size_t)gfirst * DIM + col], sf);
        }
        if (!uni) {
            int cur = -1; float run = 0.f;
#pragma unroll
            for (int r = 0; r < 4; r++) {
                int g = sBatch[widx + quad * 4 + r];
                if (g != cur) {
                    if (cur >= 0 && run != 0.f)
                        atomicAdd(&praw[(size_t)cur * DIM + col], run);
                    run = 0.f; cur = g;
                }
                run += vv[r];
            }
            if (cur >= 0 && run != 0.f)
                atomicAdd(&praw[(size_t)cur * DIM + col], run);
        }
    }
    __syncthreads();
    if (tid < 2 * DIM)
        atomicAdd(&sums_part[(size_t)(blockIdx.x & (N_PART - 1)) * 2 * DIM + tid], sSum[tid]);
}

// --------------------------------------------- BN scale/shift from partials
__global__ void finalize_stats(const float* __restrict__ sp,
                               const float* __restrict__ gamma,
                               const float* __restrict__ beta,
                               float* __restrict__ ss) {
    int c = threadIdx.x;
    float s = 0.f, q = 0.f;
    for (int p = 0; p < N_PART; p++) {
        s += sp[p * 2 * DIM + c];
        q += sp[p * 2 * DIM + DIM + c];
    }
    const float inv_n = 1.0f / (float)N_NODES;
    float mu  = s * inv_n;
    float var = q * inv_n - mu * mu;
    float sc  = gamma[c] / sqrtf(var + BN_EPS);
    ss[c]       = sc;
    ss[DIM + c] = beta[c] - mu * sc;
}

// ------------------- pooled[g][L*64+c] = sc*praw + cnt_g*sh
__global__ __launch_bounds__(256) void assemble_pooled(const float* __restrict__ praw,
                                                       const float* __restrict__ ssAll,
                                                       const int* __restrict__ cntg,
                                                       float* __restrict__ pooled) {
    int idx = blockIdx.x * 256 + threadIdx.x;
    if (idx >= N_GRAPHS * D3) return;
    int g = idx / D3, j = idx - g * D3, L = j >> 6, c = j & 63;
    float sc = ssAll[L * 2 * DIM + c], sh = ssAll[L * 2 * DIM + DIM + c];
    pooled[idx] = fmaf(sc, praw[((size_t)L * N_GRAPHS + g) * DIM + c],
                       (float)cntg[g] * sh);
}

// ------------------------------------------------ final 2-layer MLP on pooled
__global__ __launch_bounds__(192) void final_mlp(const float* __restrict__ pooled,
    const float* __restrict__ PW1, const float* __restrict__ PB1,
    const float* __restrict__ PW2, const float* __restrict__ PB2,
    float* __restrict__ out) {
    __shared__ float row[D3];
    __shared__ float hid[D3];
    int g = blockIdx.x, j = threadIdx.x;
    row[j] = pooled[(size_t)g * D3 + j];
    __syncthreads();
    float acc = PB1[j];
    for (int k = 0; k < D3; k++) acc = fmaf(row[k], PW1[k * D3 + j], acc);
    hid[j] = fmaxf(acc, 0.f);
    __syncthreads();
    float acc2 = PB2[j];
    for (int k = 0; k < D3; k++) acc2 = fmaf(hid[k], PW2[k * D3 + j], acc2);
    out[(size_t)g * D3 + j] = acc2;
}

extern "C" void kernel_launch(void* const* d_in, const int* in_sizes, int n_in,
                              void* d_out, int out_size, void* d_ws, size_t ws_size,
                              hipStream_t stream) {
    const float* x     = (const float*)d_in[0];
    const int*   ei    = (const int*)d_in[1];
    const int*   batch = (const int*)d_in[2];
    const float* W1    = (const float*)d_in[3];
    const float* B1    = (const float*)d_in[4];
    const float* W2    = (const float*)d_in[5];
    const float* B2    = (const float*)d_in[6];
    const float* gamma = (const float*)d_in[7];
    const float* beta  = (const float*)d_in[8];
    const float* PW1   = (const float*)d_in[9];
    const float* PB1   = (const float*)d_in[10];
    const float* PW2   = (const float*)d_in[11];
    const float* PB2   = (const float*)d_in[12];
    float* out = (float*)d_out;

    // -------- workspace layout (ebuf aliases bufB: 782*2048 u32 = 6.4MB < 12.8MB)
    float*    bufA  = (float*)d_ws;                              // 3,200,000 f
    float*    bufB  = bufA + (size_t)N_NODES * DIM;              // 3,200,000 f
    unsigned* ebuf  = (unsigned*)bufB;                           // alias
    int*      csr   = (int*)(bufB + (size_t)N_NODES * DIM);      // 800,000 i
    int*      rp    = csr + N_EDGES;                             // 50,056 i
    int*      bstart = rp + 50056;                               // 784 i
    unsigned short* wfrag = (unsigned short*)(bstart + 784);     // 49,152 u16
    float*    ssbuf = (float*)(wfrag + 49152);                   // 384 f
    float*    pooled = ssbuf + N_LAYERS * 2 * DIM;               // 49,152 f
    // ---- zeroed region
    int*      bcnt  = (int*)(pooled + N_GRAPHS * D3);            // 784 i
    int*      cntg  = bcnt + 784;                                // 256 i
    float*    sums_part = (float*)(cntg + N_GRAPHS);             // 24,576 f
    float*    praw  = sums_part + N_LAYERS * N_PART * 2 * DIM;   // 49,152 f

    const int* src = ei;
    const int* dst = ei + N_EDGES;

    const size_t zero_bytes =
        (size_t)(784 + N_GRAPHS) * sizeof(int) +
        (size_t)(N_LAYERS * N_PART * 2 * DIM + N_LAYERS * N_GRAPHS * DIM) * sizeof(float);
    hipMemsetAsync(bcnt, 0, zero_bytes, stream);

    // -------- CSR build: direct fixed-capacity partition + per-bucket sort
    part_direct<<<(N_EDGES + 255) / 256, 256, 0, stream>>>(src, dst, bcnt, ebuf);
    scan_small<<<1, 1024, 0, stream>>>(bcnt, bstart);
    bucket_sort<<<NBKT, 256, 0, stream>>>(ebuf, bstart, csr, rp);
    prep_weights<<<(N_LAYERS * 2 * 4096 + 255) / 256, 256, 0, stream>>>(W1, W2, wfrag);
    count_graphs<<<(N_NODES / 8 + 255) / 256, 256, 0, stream>>>(batch, cntg);

    // -------- layers: gather(+affine) -> mlp(raw z + stats + raw pool)
    const float* P = x;
    float* Q = bufA;
    const float* ssPrev = nullptr;
    const int MB = (N_NODES + 63) / 64;   // 782
    for (int L = 0; L < N_LAYERS; ++L) {
        int write_z = (L < N_LAYERS - 1);
        gather_kernel<<<(N_NODES + 3) / 4, 256, 0, stream>>>(P, Q, rp, csr, ssPrev);
        mlp_mfma<<<MB, 256, 0, stream>>>(
            Q, wfrag + (size_t)L * 2 * 8192, B1 + (size_t)L * DIM, B2 + (size_t)L * DIM,
            sums_part + (size_t)L * N_PART * 2 * DIM,
            praw + (size_t)L * N_GRAPHS * DIM, batch, write_z);
        finalize_stats<<<1, DIM, 0, stream>>>(sums_part + (size_t)L * N_PART * 2 * DIM,
                                              gamma + (size_t)L * DIM,
                                              beta + (size_t)L * DIM,
                                              ssbuf + (size_t)L * 2 * DIM);
        ssPrev = ssbuf + (size_t)L * 2 * DIM;
        P = Q;
        Q = (Q == bufA) ? bufB : bufA;
    }

    assemble_pooled<<<(N_GRAPHS * D3 + 255) / 256, 256, 0, stream>>>(praw, ssbuf, cntg, pooled);
    final_mlp<<<N_GRAPHS, 192, 0, stream>>>(pooled, PW1, PB1, PW2, PB2, out);
}

// Round 9
// 307.673 us; speedup vs baseline: 1.5511x; 1.5511x over previous
//
#include <hip/hip_runtime.h>

#define N_NODES 50000
#define N_EDGES 800000
#define DIM 64
#define N_LAYERS 3
#define N_GRAPHS 256
#define BN_EPS 1e-5f
#define D3 (DIM * N_LAYERS)
#define N_PART 64
#define NBKT 782          // ceil(50000/64) destination buckets
#define NPB 196           // partition blocks (4096 edges each)
#define ECAP 2048         // fixed capacity per bucket (mean 1023, sigma ~32)

typedef __attribute__((ext_vector_type(8))) short short8;
typedef __attribute__((ext_vector_type(4))) float floatx4;

// ---------------------------------------------------------- bf16 split utils
__device__ inline unsigned short bf16_rn(float f) {
    unsigned u = __float_as_uint(f);
    u += 0x7FFF + ((u >> 16) & 1);
    return (unsigned short)(u >> 16);
}
__device__ inline float bf16_f(unsigned short b) {
    return __uint_as_float(((unsigned)b) << 16);
}
__device__ inline void split8(float4 a, float4 b, short8* hi, short8* lo) {
    float v[8] = {a.x, a.y, a.z, a.w, b.x, b.y, b.z, b.w};
#pragma unroll
    for (int i = 0; i < 8; i++) {
        unsigned short h = bf16_rn(v[i]);
        (*hi)[i] = (short)h;
        (*lo)[i] = (short)bf16_rn(v[i] - bf16_f(h));
    }
}

// -------- pass 1: per-block LDS hist over buckets -> counts[bucket][block]
__global__ __launch_bounds__(256) void pass1_hist(const int* __restrict__ dst,
                                                  int* __restrict__ counts) {
    __shared__ int hcnt[NBKT];
    for (int i = threadIdx.x; i < NBKT; i += 256) hcnt[i] = 0;
    __syncthreads();
    int base = blockIdx.x * 4096;
#pragma unroll
    for (int k = 0; k < 16; k++) {
        int e = base + k * 256 + threadIdx.x;
        if (e < N_EDGES) atomicAdd(&hcnt[dst[e] >> 6], 1);   // LDS atomic (native)
    }
    __syncthreads();
    for (int i = threadIdx.x; i < NBKT; i += 256)
        counts[i * NPB + blockIdx.x] = hcnt[i];
}

// -------- per-bucket exclusive scan over the 196 block counts -> offs, totals
__global__ __launch_bounds__(256) void bucket_scan(const int* __restrict__ counts,
                                                   int* __restrict__ offs,
                                                   int* __restrict__ bcnt) {
    __shared__ int s[256];
    int b = blockIdx.x, t = threadIdx.x;
    int v = (t < NPB) ? counts[b * NPB + t] : 0;
    s[t] = v;
    __syncthreads();
    for (int off = 1; off < 256; off <<= 1) {
        int u = (t >= off) ? s[t - off] : 0;
        __syncthreads();
        s[t] += u;
        __syncthreads();
    }
    if (t < NPB) offs[b * NPB + t] = s[t] - v;
    if (t == NPB - 1) bcnt[b] = s[t];
}

// ------------------------------- exclusive scan of 782 bucket totals
__global__ __launch_bounds__(1024) void scan_small(const int* __restrict__ bcnt,
                                                   int* __restrict__ bstart) {
    __shared__ int s[1024];
    int t = threadIdx.x;
    int v = (t < NBKT) ? bcnt[t] : 0;
    s[t] = v;
    __syncthreads();
    for (int off = 1; off < 1024; off <<= 1) {
        int u = (t >= off) ? s[t - off] : 0;
        __syncthreads();
        s[t] += u;
        __syncthreads();
    }
    if (t < NBKT) bstart[t] = s[t] - v;
    if (t == NBKT - 1) bstart[NBKT] = s[t];
}

// -------- pass 2: deterministic scatter via LDS position counters (no global atomics)
__global__ __launch_bounds__(256) void pass2_scatter(const int* __restrict__ src,
                                                     const int* __restrict__ dst,
                                                     const int* __restrict__ offs,
                                                     unsigned* __restrict__ ebuf) {
    __shared__ int loff[NBKT];
    int blk = blockIdx.x;
    for (int i = threadIdx.x; i < NBKT; i += 256)
        loff[i] = offs[i * NPB + blk];
    __syncthreads();
    int base = blk * 4096;
#pragma unroll
    for (int k = 0; k < 16; k++) {
        int e = base + k * 256 + threadIdx.x;
        if (e < N_EDGES) {
            int d = dst[e];
            int b = d >> 6;
            int pos = atomicAdd(&loff[b], 1);     // LDS int atomic (native)
            ebuf[(size_t)b * ECAP + pos] = ((unsigned)src[e] << 6) | (unsigned)(d & 63);
        }
    }
}

// --------- counting-sort each bucket's edges by dst&63 -> per-node CSR + rp
__global__ __launch_bounds__(256) void bucket_sort(const unsigned* __restrict__ ebuf,
                                                   const int* __restrict__ bcnt,
                                                   const int* __restrict__ bstart,
                                                   int* __restrict__ csr,
                                                   int* __restrict__ rp) {
    __shared__ unsigned ent[ECAP];
    __shared__ int cnt[64], basea[64], fill[64];
    int b = blockIdx.x, tid = threadIdx.x;
    int start = bstart[b];
    int T = bcnt[b];
    const unsigned* eb = ebuf + (size_t)b * ECAP;
    if (tid < 64) cnt[tid] = 0;
    for (int i = tid; i < T; i += 256) ent[i] = eb[i];
    __syncthreads();
    for (int i = tid; i < T; i += 256) atomicAdd(&cnt[ent[i] & 63], 1);
    __syncthreads();
    if (tid < 64) {
        int v = cnt[tid], x = v;
#pragma unroll
        for (int off = 1; off < 64; off <<= 1) {
            int y = __shfl_up(x, off);
            if (tid >= off) x += y;
        }
        basea[tid] = x - v;
        fill[tid] = 0;
        rp[b * 64 + tid] = start + x - v;
    }
    __syncthreads();
    for (int i = tid; i < T; i += 256) {
        unsigned e = ent[i];
        int c = e & 63;
        int pos = basea[c] + atomicAdd(&fill[c], 1);
        csr[start + pos] = (int)(e >> 6);
    }
}

// -------------------------------------------- per-graph node counts (sorted)
__global__ __launch_bounds__(256) void count_graphs(const int* __restrict__ batch,
                                                    int* __restrict__ cntg) {
    int grp = blockIdx.x * 256 + threadIdx.x;
    if (grp >= N_NODES / 8) return;
    int n0 = grp * 8, run = 0, cur = batch[n0];
#pragma unroll
    for (int r = 0; r < 8; r++) {
        int b = batch[n0 + r];
        if (b != cur) { atomicAdd(&cntg[cur], run); run = 0; cur = b; }
        run++;
    }
    atomicAdd(&cntg[cur], run);
}

// -------- gather + prev-layer BN affine: z[i] = sc*(h[i]+sum h[j]) + (1+deg)*sh
__global__ __launch_bounds__(256) void gather_kernel(const float* __restrict__ h,
                                                     float* __restrict__ z,
                                                     const int* __restrict__ rp,
                                                     const int* __restrict__ csr,
                                                     const float* __restrict__ ss) {
    int node = blockIdx.x * 4 + (threadIdx.x >> 6);
    if (node >= N_NODES) return;
    int lane = threadIdx.x & 63;
    float acc = h[(size_t)node * DIM + lane];
    int e = rp[node], end = rp[node + 1];
    float degf = 1.f + (float)(end - e);
    for (; e + 8 <= end; e += 8) {
        int s0 = csr[e],     s1 = csr[e + 1], s2 = csr[e + 2], s3 = csr[e + 3];
        int s4 = csr[e + 4], s5 = csr[e + 5], s6 = csr[e + 6], s7 = csr[e + 7];
        float v0 = h[(size_t)s0 * DIM + lane];
        float v1 = h[(size_t)s1 * DIM + lane];
        float v2 = h[(size_t)s2 * DIM + lane];
        float v3 = h[(size_t)s3 * DIM + lane];
        float v4 = h[(size_t)s4 * DIM + lane];
        float v5 = h[(size_t)s5 * DIM + lane];
        float v6 = h[(size_t)s6 * DIM + lane];
        float v7 = h[(size_t)s7 * DIM + lane];
        acc += ((v0 + v1) + (v2 + v3)) + ((v4 + v5) + (v6 + v7));
    }
    for (; e < end; e++) acc += h[(size_t)csr[e] * DIM + lane];
    if (ss) acc = fmaf(acc, ss[lane], degf * ss[DIM + lane]);
    z[(size_t)node * DIM + lane] = acc;
}

// --------------- pack W1/W2 into MFMA B-operand fragments, split bf16 hi/lo
__global__ __launch_bounds__(256) void prep_weights(const float* __restrict__ W1,
                                                    const float* __restrict__ W2,
                                                    unsigned short* __restrict__ wf) {
    int idx = blockIdx.x * 256 + threadIdx.x;
    if (idx >= N_LAYERS * 2 * 4096) return;
    int j    = idx & 7;
    int lane = (idx >> 3) & 63;
    int ks   = (idx >> 9) & 1;
    int nt   = (idx >> 10) & 3;
    int gemm = (idx >> 12) & 1;
    int layer = idx >> 13;
    int n = nt * 16 + (lane & 15);
    int k = ks * 32 + (lane >> 4) * 8 + j;
    const float* W = (gemm ? W2 : W1) + (size_t)layer * DIM * DIM;
    float w = W[k * DIM + n];
    unsigned short hi = bf16_rn(w);
    unsigned short lo = bf16_rn(w - bf16_f(hi));
    size_t base = ((size_t)layer * 2 + gemm) * 8192;
    int f = nt * 2 + ks;
    wf[base + f * 512 + lane * 8 + j]        = hi;
    wf[base + 4096 + f * 512 + lane * 8 + j] = lo;
}

// ------- MFMA MLP: raw z' = relu(relu(zW1+B1)W2+B2) + BN partials + raw pool
#define HS_STRIDE 68
__global__ __launch_bounds__(256) void mlp_mfma(float* __restrict__ z,
    const unsigned short* __restrict__ wfL,
    const float* __restrict__ B1, const float* __restrict__ B2,
    float* __restrict__ sums_part, float* __restrict__ praw,
    const int* __restrict__ batch, int write_z) {
    __shared__ float sH[4][16 * HS_STRIDE];
    __shared__ float sSum[2 * DIM];
    __shared__ int   sBatch[64];

    int tid = threadIdx.x, wave = tid >> 6, lane = tid & 63;
    int blk0 = blockIdx.x * 64;
    if (tid < 2 * DIM) sSum[tid] = 0.f;
    if (tid < 64) sBatch[tid] = (blk0 + tid < N_NODES) ? batch[blk0 + tid] : -1;
    __syncthreads();

    int m = lane & 15, quad = lane >> 4;
    int row0 = blk0 + wave * 16;
    int grow = row0 + m;
    int ar = grow < N_NODES ? grow : N_NODES - 1;

    const float4* zr = (const float4*)(z + (size_t)ar * DIM);
    float4 a0 = zr[quad * 2],     a1 = zr[quad * 2 + 1];
    float4 a2 = zr[8 + quad * 2], a3 = zr[8 + quad * 2 + 1];
    short8 Ah0, Al0, Ah1, Al1;
    split8(a0, a1, &Ah0, &Al0);
    split8(a2, a3, &Ah1, &Al1);

    floatx4 acc[4];
#pragma unroll
    for (int nt = 0; nt < 4; nt++) acc[nt] = (floatx4){0.f, 0.f, 0.f, 0.f};
#pragma unroll
    for (int nt = 0; nt < 4; nt++) {
#pragma unroll
        for (int ks = 0; ks < 2; ks++) {
            const short8 Bh = *(const short8*)(wfL + (nt * 2 + ks) * 512 + lane * 8);
            const short8 Bl = *(const short8*)(wfL + 4096 + (nt * 2 + ks) * 512 + lane * 8);
            short8 Ahf = ks ? Ah1 : Ah0;
            short8 Alf = ks ? Al1 : Al0;
            acc[nt] = __builtin_amdgcn_mfma_f32_16x16x32_bf16(Ahf, Bh, acc[nt], 0, 0, 0);
            acc[nt] = __builtin_amdgcn_mfma_f32_16x16x32_bf16(Ahf, Bl, acc[nt], 0, 0, 0);
            acc[nt] = __builtin_amdgcn_mfma_f32_16x16x32_bf16(Alf, Bh, acc[nt], 0, 0, 0);
        }
    }

    float* Hs = sH[wave];
#pragma unroll
    for (int nt = 0; nt < 4; nt++) {
        int col = nt * 16 + m;
        float b = B1[col];
#pragma unroll
        for (int r = 0; r < 4; r++) {
            int lr = quad * 4 + r;
            Hs[lr * HS_STRIDE + col] = fmaxf(acc[nt][r] + b, 0.f);
        }
    }
    float4 h0 = *(const float4*)&Hs[m * HS_STRIDE + quad * 8];
    float4 h1 = *(const float4*)&Hs[m * HS_STRIDE + quad * 8 + 4];
    float4 h2 = *(const float4*)&Hs[m * HS_STRIDE + 32 + quad * 8];
    float4 h3 = *(const float4*)&Hs[m * HS_STRIDE + 32 + quad * 8 + 4];
    short8 Hh0, Hl0, Hh1, Hl1;
    split8(h0, h1, &Hh0, &Hl0);
    split8(h2, h3, &Hh1, &Hl1);

    floatx4 acc2[4];
#pragma unroll
    for (int nt = 0; nt < 4; nt++) acc2[nt] = (floatx4){0.f, 0.f, 0.f, 0.f};
    const unsigned short* wg2 = wfL + 8192;
#pragma unroll
    for (int nt = 0; nt < 4; nt++) {
#pragma unroll
        for (int ks = 0; ks < 2; ks++) {
            const short8 Bh = *(const short8*)(wg2 + (nt * 2 + ks) * 512 + lane * 8);
            const short8 Bl = *(const short8*)(wg2 + 4096 + (nt * 2 + ks) * 512 + lane * 8);
            short8 Ahf = ks ? Hh1 : Hh0;
            short8 Alf = ks ? Hl1 : Hl0;
            acc2[nt] = __builtin_amdgcn_mfma_f32_16x16x32_bf16(Ahf, Bh, acc2[nt], 0, 0, 0);
            acc2[nt] = __builtin_amdgcn_mfma_f32_16x16x32_bf16(Ahf, Bl, acc2[nt], 0, 0, 0);
            acc2[nt] = __builtin_amdgcn_mfma_f32_16x16x32_bf16(Alf, Bh, acc2[nt], 0, 0, 0);
        }
    }

    // ---- epilogue: raw z write + BN partials + per-graph raw pooling
    int widx = wave * 16;
    int gfirst = sBatch[widx], glast = sBatch[widx + 15];
    bool uni = (gfirst == glast) && (gfirst >= 0);
#pragma unroll
    for (int nt = 0; nt < 4; nt++) {
        int col = nt * 16 + m;
        float b = B2[col];
        float vv[4];
        float s = 0.f, s2 = 0.f;
#pragma unroll
        for (int r = 0; r < 4; r++) {
            int gr = row0 + quad * 4 + r;
            float v = fmaxf(acc2[nt][r] + b, 0.f);
            if (gr < N_NODES) {
                if (write_z) z[(size_t)gr * DIM + col] = v;
                s += v;
                s2 = fmaf(v, v, s2);
                vv[r] = v;
            } else {
                vv[r] = 0.f;
            }
        }
        float sf = s, s2f = s2;
        sf  += __shfl_xor(sf, 16);  sf  += __shfl_xor(sf, 32);
        s2f += __shfl_xor(s2f, 16); s2f += __shfl_xor(s2f, 32);
        if (quad == 0) {
            atomicAdd(&sSum[col], sf);
            atomicAdd(&sSum[DIM + col], s2f);
            if (uni) atomicAdd(&praw[(size_t)gfirst * DIM + col], sf);
        }
        if (!uni) {
            int cur = -1; float run = 0.f;
#pragma unroll
            for (int r = 0; r < 4; r++) {
                int g = sBatch[widx + quad * 4 + r];
                if (g != cur) {
                    if (cur >= 0 && run != 0.f)
                        atomicAdd(&praw[(size_t)cur * DIM + col], run);
                    run = 0.f; cur = g;
                }
                run += vv[r];
            }
            if (cur >= 0 && run != 0.f)
                atomicAdd(&praw[(size_t)cur * DIM + col], run);
        }
    }
    __syncthreads();
    if (tid < 2 * DIM)
        atomicAdd(&sums_part[(size_t)(blockIdx.x & (N_PART - 1)) * 2 * DIM + tid], sSum[tid]);
}

// --------------------------------------------- BN scale/shift from partials
__global__ void finalize_stats(const float* __restrict__ sp,
                               const float* __restrict__ gamma,
                               const float* __restrict__ beta,
                               float* __restrict__ ss) {
    int c = threadIdx.x;
    float s = 0.f, q = 0.f;
    for (int p = 0; p < N_PART; p++) {
        s += sp[p * 2 * DIM + c];
        q += sp[p * 2 * DIM + DIM + c];
    }
    const float inv_n = 1.0f / (float)N_NODES;
    float mu  = s * inv_n;
    float var = q * inv_n - mu * mu;
    float sc  = gamma[c] / sqrtf(var + BN_EPS);
    ss[c]       = sc;
    ss[DIM + c] = beta[c] - mu * sc;
}

// ------------------- pooled[g][L*64+c] = sc*praw + cnt_g*sh
__global__ __launch_bounds__(256) void assemble_pooled(const float* __restrict__ praw,
                                                       const float* __restrict__ ssAll,
                                                       const int* __restrict__ cntg,
                                                       float* __restrict__ pooled) {
    int idx = blockIdx.x * 256 + threadIdx.x;
    if (idx >= N_GRAPHS * D3) return;
    int g = idx / D3, j = idx - g * D3, L = j >> 6, c = j & 63;
    float sc = ssAll[L * 2 * DIM + c], sh = ssAll[L * 2 * DIM + DIM + c];
    pooled[idx] = fmaf(sc, praw[((size_t)L * N_GRAPHS + g) * DIM + c],
                       (float)cntg[g] * sh);
}

// ------------------------------------------------ final 2-layer MLP on pooled
__global__ __launch_bounds__(192) void final_mlp(const float* __restrict__ pooled,
    const float* __restrict__ PW1, const float* __restrict__ PB1,
    const float* __restrict__ PW2, const float* __restrict__ PB2,
    float* __restrict__ out) {
    __shared__ float row[D3];
    __shared__ float hid[D3];
    int g = blockIdx.x, j = threadIdx.x;
    row[j] = pooled[(size_t)g * D3 + j];
    __syncthreads();
    float acc = PB1[j];
    for (int k = 0; k < D3; k++) acc = fmaf(row[k], PW1[k * D3 + j], acc);
    hid[j] = fmaxf(acc, 0.f);
    __syncthreads();
    float acc2 = PB2[j];
    for (int k = 0; k < D3; k++) acc2 = fmaf(hid[k], PW2[k * D3 + j], acc2);
    out[(size_t)g * D3 + j] = acc2;
}

extern "C" void kernel_launch(void* const* d_in, const int* in_sizes, int n_in,
                              void* d_out, int out_size, void* d_ws, size_t ws_size,
                              hipStream_t stream) {
    const float* x     = (const float*)d_in[0];
    const int*   ei    = (const int*)d_in[1];
    const int*   batch = (const int*)d_in[2];
    const float* W1    = (const float*)d_in[3];
    const float* B1    = (const float*)d_in[4];
    const float* W2    = (const float*)d_in[5];
    const float* B2    = (const float*)d_in[6];
    const float* gamma = (const float*)d_in[7];
    const float* beta  = (const float*)d_in[8];
    const float* PW1   = (const float*)d_in[9];
    const float* PB1   = (const float*)d_in[10];
    const float* PW2   = (const float*)d_in[11];
    const float* PB2   = (const float*)d_in[12];
    float* out = (float*)d_out;

    // -------- workspace layout (ebuf aliases bufB: 782*2048 u32 = 6.4MB < 12.8MB)
    float*    bufA  = (float*)d_ws;                              // 3,200,000 f
    float*    bufB  = bufA + (size_t)N_NODES * DIM;              // 3,200,000 f
    unsigned* ebuf  = (unsigned*)bufB;                           // alias
    int*      csr   = (int*)(bufB + (size_t)N_NODES * DIM);      // 800,000 i
    int*      rp    = csr + N_EDGES;                             // 50,056 i
    int*      bstart = rp + 50056;                               // 784 i
    int*      bcnt  = bstart + 784;                              // 784 i (written fully)
    int*      counts = bcnt + 784;                               // 153,272 i (written fully)
    int*      offs   = counts + NBKT * NPB;                      // 153,272 i (written fully)
    unsigned short* wfrag = (unsigned short*)(offs + NBKT * NPB); // 49,152 u16
    float*    ssbuf = (float*)(wfrag + 49152);                   // 384 f
    float*    pooled = ssbuf + N_LAYERS * 2 * DIM;               // 49,152 f
    // ---- zeroed region
    int*      cntg  = (int*)(pooled + N_GRAPHS * D3);            // 256 i
    float*    sums_part = (float*)(cntg + N_GRAPHS);             // 24,576 f
    float*    praw  = sums_part + N_LAYERS * N_PART * 2 * DIM;   // 49,152 f

    const int* src = ei;
    const int* dst = ei + N_EDGES;

    const size_t zero_bytes =
        (size_t)N_GRAPHS * sizeof(int) +
        (size_t)(N_LAYERS * N_PART * 2 * DIM + N_LAYERS * N_GRAPHS * DIM) * sizeof(float);
    hipMemsetAsync(cntg, 0, zero_bytes, stream);

    // -------- CSR build: deterministic two-pass partition (no global atomics)
    pass1_hist<<<NPB, 256, 0, stream>>>(dst, counts);
    bucket_scan<<<NBKT, 256, 0, stream>>>(counts, offs, bcnt);
    scan_small<<<1, 1024, 0, stream>>>(bcnt, bstart);
    pass2_scatter<<<NPB, 256, 0, stream>>>(src, dst, offs, ebuf);
    bucket_sort<<<NBKT, 256, 0, stream>>>(ebuf, bcnt, bstart, csr, rp);
    prep_weights<<<(N_LAYERS * 2 * 4096 + 255) / 256, 256, 0, stream>>>(W1, W2, wfrag);
    count_graphs<<<(N_NODES / 8 + 255) / 256, 256, 0, stream>>>(batch, cntg);

    // -------- layers: gather(+affine) -> mlp(raw z + stats + raw pool)
    const float* P = x;
    float* Q = bufA;
    const float* ssPrev = nullptr;
    const int MB = (N_NODES + 63) / 64;   // 782
    for (int L = 0; L < N_LAYERS; ++L) {
        int write_z = (L < N_LAYERS - 1);
        gather_kernel<<<(N_NODES + 3) / 4, 256, 0, stream>>>(P, Q, rp, csr, ssPrev);
        mlp_mfma<<<MB, 256, 0, stream>>>(
            Q, wfrag + (size_t)L * 2 * 8192, B1 + (size_t)L * DIM, B2 + (size_t)L * DIM,
            sums_part + (size_t)L * N_PART * 2 * DIM,
            praw + (size_t)L * N_GRAPHS * DIM, batch, write_z);
        finalize_stats<<<1, DIM, 0, stream>>>(sums_part + (size_t)L * N_PART * 2 * DIM,
                                              gamma + (size_t)L * DIM,
                                              beta + (size_t)L * DIM,
                                              ssbuf + (size_t)L * 2 * DIM);
        ssPrev = ssbuf + (size_t)L * 2 * DIM;
        P = Q;
        Q = (Q == bufA) ? bufB : bufA;
    }

    assemble_pooled<<<(N_GRAPHS * D3 + 255) / 256, 256, 0, stream>>>(praw, ssbuf, cntg, pooled);
    final_mlp<<<N_GRAPHS, 192, 0, stream>>>(pooled, PW1, PB1, PW2, PB2, out);
}

// Round 10
// 303.325 us; speedup vs baseline: 1.5734x; 1.0143x over previous
//
#include <hip/hip_runtime.h>

#define N_NODES 50000
#define N_EDGES 800000
#define DIM 64
#define N_LAYERS 3
#define N_GRAPHS 256
#define BN_EPS 1e-5f
#define D3 (DIM * N_LAYERS)
#define N_PART 64
#define NBKT 782          // ceil(50000/64) destination buckets
#define NPB 196           // partition blocks (4096 edges each)
#define ECAP 2048         // fixed capacity per bucket (mean 1023, sigma ~32)

typedef __attribute__((ext_vector_type(8))) short short8;
typedef __attribute__((ext_vector_type(4))) float floatx4;

// ---------------------------------------------------------- bf16 split utils
__device__ inline unsigned short bf16_rn(float f) {
    unsigned u = __float_as_uint(f);
    u += 0x7FFF + ((u >> 16) & 1);
    return (unsigned short)(u >> 16);
}
__device__ inline float bf16_f(unsigned short b) {
    return __uint_as_float(((unsigned)b) << 16);
}
__device__ inline void split8(float4 a, float4 b, short8* hi, short8* lo) {
    float v[8] = {a.x, a.y, a.z, a.w, b.x, b.y, b.z, b.w};
#pragma unroll
    for (int i = 0; i < 8; i++) {
        unsigned short h = bf16_rn(v[i]);
        (*hi)[i] = (short)h;
        (*lo)[i] = (short)bf16_rn(v[i] - bf16_f(h));
    }
}

// -------- pass 1: per-block LDS hist over buckets -> counts[bucket][block]
__global__ __launch_bounds__(256) void pass1_hist(const int* __restrict__ dst,
                                                  int* __restrict__ counts) {
    __shared__ int hcnt[NBKT];
    for (int i = threadIdx.x; i < NBKT; i += 256) hcnt[i] = 0;
    __syncthreads();
    int base = blockIdx.x * 4096;
#pragma unroll
    for (int k = 0; k < 16; k++) {
        int e = base + k * 256 + threadIdx.x;
        if (e < N_EDGES) atomicAdd(&hcnt[dst[e] >> 6], 1);   // LDS atomic (native)
    }
    __syncthreads();
    for (int i = threadIdx.x; i < NBKT; i += 256)
        counts[i * NPB + blockIdx.x] = hcnt[i];
}

// -------- per-bucket exclusive scan over the 196 block counts -> offs, totals
__global__ __launch_bounds__(256) void bucket_scan(const int* __restrict__ counts,
                                                   int* __restrict__ offs,
                                                   int* __restrict__ bcnt) {
    __shared__ int s[256];
    int b = blockIdx.x, t = threadIdx.x;
    int v = (t < NPB) ? counts[b * NPB + t] : 0;
    s[t] = v;
    __syncthreads();
    for (int off = 1; off < 256; off <<= 1) {
        int u = (t >= off) ? s[t - off] : 0;
        __syncthreads();
        s[t] += u;
        __syncthreads();
    }
    if (t < NPB) offs[b * NPB + t] = s[t] - v;
    if (t == NPB - 1) bcnt[b] = s[t];
}

// ------------------------------- exclusive scan of 782 bucket totals
__global__ __launch_bounds__(1024) void scan_small(const int* __restrict__ bcnt,
                                                   int* __restrict__ bstart) {
    __shared__ int s[1024];
    int t = threadIdx.x;
    int v = (t < NBKT) ? bcnt[t] : 0;
    s[t] = v;
    __syncthreads();
    for (int off = 1; off < 1024; off <<= 1) {
        int u = (t >= off) ? s[t - off] : 0;
        __syncthreads();
        s[t] += u;
        __syncthreads();
    }
    if (t < NBKT) bstart[t] = s[t] - v;
    if (t == NBKT - 1) bstart[NBKT] = s[t];
}

// -------- pass 2: deterministic scatter via LDS position counters
__global__ __launch_bounds__(256) void pass2_scatter(const int* __restrict__ src,
                                                     const int* __restrict__ dst,
                                                     const int* __restrict__ offs,
                                                     unsigned* __restrict__ ebuf) {
    __shared__ int loff[NBKT];
    int blk = blockIdx.x;
    for (int i = threadIdx.x; i < NBKT; i += 256)
        loff[i] = offs[i * NPB + blk];
    __syncthreads();
    int base = blk * 4096;
#pragma unroll
    for (int k = 0; k < 16; k++) {
        int e = base + k * 256 + threadIdx.x;
        if (e < N_EDGES) {
            int d = dst[e];
            int b = d >> 6;
            int pos = atomicAdd(&loff[b], 1);     // LDS int atomic (native)
            ebuf[(size_t)b * ECAP + pos] = ((unsigned)src[e] << 6) | (unsigned)(d & 63);
        }
    }
}

// --------- counting-sort each bucket's edges by dst&63 -> per-node CSR + rp
__global__ __launch_bounds__(256) void bucket_sort(const unsigned* __restrict__ ebuf,
                                                   const int* __restrict__ bcnt,
                                                   const int* __restrict__ bstart,
                                                   int* __restrict__ csr,
                                                   int* __restrict__ rp) {
    __shared__ unsigned ent[ECAP];
    __shared__ int cnt[64], basea[64], fill[64];
    int b = blockIdx.x, tid = threadIdx.x;
    int start = bstart[b];
    int T = bcnt[b];
    const unsigned* eb = ebuf + (size_t)b * ECAP;
    if (tid < 64) cnt[tid] = 0;
    for (int i = tid; i < T; i += 256) ent[i] = eb[i];
    __syncthreads();
    for (int i = tid; i < T; i += 256) atomicAdd(&cnt[ent[i] & 63], 1);
    __syncthreads();
    if (tid < 64) {
        int v = cnt[tid], x = v;
#pragma unroll
        for (int off = 1; off < 64; off <<= 1) {
            int y = __shfl_up(x, off);
            if (tid >= off) x += y;
        }
        basea[tid] = x - v;
        fill[tid] = 0;
        rp[b * 64 + tid] = start + x - v;
    }
    __syncthreads();
    for (int i = tid; i < T; i += 256) {
        unsigned e = ent[i];
        int c = e & 63;
        int pos = basea[c] + atomicAdd(&fill[c], 1);
        csr[start + pos] = (int)(e >> 6);
    }
}

// -------------------------------------------- per-graph node counts (sorted)
__global__ __launch_bounds__(256) void count_graphs(const int* __restrict__ batch,
                                                    int* __restrict__ cntg) {
    int grp = blockIdx.x * 256 + threadIdx.x;
    if (grp >= N_NODES / 8) return;
    int n0 = grp * 8, run = 0, cur = batch[n0];
#pragma unroll
    for (int r = 0; r < 8; r++) {
        int b = batch[n0 + r];
        if (b != cur) { atomicAdd(&cntg[cur], run); run = 0; cur = b; }
        run++;
    }
    atomicAdd(&cntg[cur], run);
}

// -------- gather (f32 input, layer 0): z[i] = h[i] + sum_{j->i} h[j]
__global__ __launch_bounds__(256) void gather_f32(const float* __restrict__ h,
                                                  float* __restrict__ z,
                                                  const int* __restrict__ rp,
                                                  const int* __restrict__ csr) {
    int node = blockIdx.x * 4 + (threadIdx.x >> 6);
    if (node >= N_NODES) return;
    int lane = threadIdx.x & 63;
    float acc = h[(size_t)node * DIM + lane];
    int e = rp[node], end = rp[node + 1];
    for (; e + 8 <= end; e += 8) {
        int s0 = csr[e],     s1 = csr[e + 1], s2 = csr[e + 2], s3 = csr[e + 3];
        int s4 = csr[e + 4], s5 = csr[e + 5], s6 = csr[e + 6], s7 = csr[e + 7];
        float v0 = h[(size_t)s0 * DIM + lane];
        float v1 = h[(size_t)s1 * DIM + lane];
        float v2 = h[(size_t)s2 * DIM + lane];
        float v3 = h[(size_t)s3 * DIM + lane];
        float v4 = h[(size_t)s4 * DIM + lane];
        float v5 = h[(size_t)s5 * DIM + lane];
        float v6 = h[(size_t)s6 * DIM + lane];
        float v7 = h[(size_t)s7 * DIM + lane];
        acc += ((v0 + v1) + (v2 + v3)) + ((v4 + v5) + (v6 + v7));
    }
    for (; e < end; e++) acc += h[(size_t)csr[e] * DIM + lane];
    z[(size_t)node * DIM + lane] = acc;
}

// -------- gather (bf16 input, layers>=1) + prev-layer BN affine:
// z[i] = sc*(h[i]+sum h[j]) + (1+deg)*sh
__global__ __launch_bounds__(256) void gather_bf16(const unsigned short* __restrict__ hb,
                                                   float* __restrict__ z,
                                                   const int* __restrict__ rp,
                                                   const int* __restrict__ csr,
                                                   const float* __restrict__ ss) {
    int node = blockIdx.x * 4 + (threadIdx.x >> 6);
    if (node >= N_NODES) return;
    int lane = threadIdx.x & 63;
    float acc = bf16_f(hb[(size_t)node * DIM + lane]);
    int e = rp[node], end = rp[node + 1];
    float degf = 1.f + (float)(end - e);
    for (; e + 8 <= end; e += 8) {
        int s0 = csr[e],     s1 = csr[e + 1], s2 = csr[e + 2], s3 = csr[e + 3];
        int s4 = csr[e + 4], s5 = csr[e + 5], s6 = csr[e + 6], s7 = csr[e + 7];
        float v0 = bf16_f(hb[(size_t)s0 * DIM + lane]);
        float v1 = bf16_f(hb[(size_t)s1 * DIM + lane]);
        float v2 = bf16_f(hb[(size_t)s2 * DIM + lane]);
        float v3 = bf16_f(hb[(size_t)s3 * DIM + lane]);
        float v4 = bf16_f(hb[(size_t)s4 * DIM + lane]);
        float v5 = bf16_f(hb[(size_t)s5 * DIM + lane]);
        float v6 = bf16_f(hb[(size_t)s6 * DIM + lane]);
        float v7 = bf16_f(hb[(size_t)s7 * DIM + lane]);
        acc += ((v0 + v1) + (v2 + v3)) + ((v4 + v5) + (v6 + v7));
    }
    for (; e < end; e++) acc += bf16_f(hb[(size_t)csr[e] * DIM + lane]);
    acc = fmaf(acc, ss[lane], degf * ss[DIM + lane]);
    z[(size_t)node * DIM + lane] = acc;
}

// --------------- pack W1/W2 into MFMA B-operand fragments, split bf16 hi/lo
__global__ __launch_bounds__(256) void prep_weights(const float* __restrict__ W1,
                                                    const float* __restrict__ W2,
                                                    unsigned short* __restrict__ wf) {
    int idx = blockIdx.x * 256 + threadIdx.x;
    if (idx >= N_LAYERS * 2 * 4096) return;
    int j    = idx & 7;
    int lane = (idx >> 3) & 63;
    int ks   = (idx >> 9) & 1;
    int nt   = (idx >> 10) & 3;
    int gemm = (idx >> 12) & 1;
    int layer = idx >> 13;
    int n = nt * 16 + (lane & 15);
    int k = ks * 32 + (lane >> 4) * 8 + j;
    const float* W = (gemm ? W2 : W1) + (size_t)layer * DIM * DIM;
    float w = W[k * DIM + n];
    unsigned short hi = bf16_rn(w);
    unsigned short lo = bf16_rn(w - bf16_f(hi));
    size_t base = ((size_t)layer * 2 + gemm) * 8192;
    int f = nt * 2 + ks;
    wf[base + f * 512 + lane * 8 + j]        = hi;
    wf[base + 4096 + f * 512 + lane * 8 + j] = lo;
}

// ------- MFMA MLP: bf16 z' = relu(relu(zW1+B1)W2+B2) + BN partials + raw pool
#define HS_STRIDE 68
__global__ __launch_bounds__(256) void mlp_mfma(const float* __restrict__ z,
    unsigned short* __restrict__ zb,
    const unsigned short* __restrict__ wfL,
    const float* __restrict__ B1, const float* __restrict__ B2,
    float* __restrict__ sums_part, float* __restrict__ praw,
    const int* __restrict__ batch, int write_z) {
    __shared__ float sH[4][16 * HS_STRIDE];
    __shared__ float sSum[2 * DIM];
    __shared__ int   sBatch[64];

    int tid = threadIdx.x, wave = tid >> 6, lane = tid & 63;
    int blk0 = blockIdx.x * 64;
    if (tid < 2 * DIM) sSum[tid] = 0.f;
    if (tid < 64) sBatch[tid] = (blk0 + tid < N_NODES) ? batch[blk0 + tid] : -1;
    __syncthreads();

    int m = lane & 15, quad = lane >> 4;
    int row0 = blk0 + wave * 16;
    int grow = row0 + m;
    int ar = grow < N_NODES ? grow : N_NODES - 1;

    const float4* zr = (const float4*)(z + (size_t)ar * DIM);
    float4 a0 = zr[quad * 2],     a1 = zr[quad * 2 + 1];
    float4 a2 = zr[8 + quad * 2], a3 = zr[8 + quad * 2 + 1];
    short8 Ah0, Al0, Ah1, Al1;
    split8(a0, a1, &Ah0, &Al0);
    split8(a2, a3, &Ah1, &Al1);

    floatx4 acc[4];
#pragma unroll
    for (int nt = 0; nt < 4; nt++) acc[nt] = (floatx4){0.f, 0.f, 0.f, 0.f};
#pragma unroll
    for (int nt = 0; nt < 4; nt++) {
#pragma unroll
        for (int ks = 0; ks < 2; ks++) {
            const short8 Bh = *(const short8*)(wfL + (nt * 2 + ks) * 512 + lane * 8);
            const short8 Bl = *(const short8*)(wfL + 4096 + (nt * 2 + ks) * 512 + lane * 8);
            short8 Ahf = ks ? Ah1 : Ah0;
            short8 Alf = ks ? Al1 : Al0;
            acc[nt] = __builtin_amdgcn_mfma_f32_16x16x32_bf16(Ahf, Bh, acc[nt], 0, 0, 0);
            acc[nt] = __builtin_amdgcn_mfma_f32_16x16x32_bf16(Ahf, Bl, acc[nt], 0, 0, 0);
            acc[nt] = __builtin_amdgcn_mfma_f32_16x16x32_bf16(Alf, Bh, acc[nt], 0, 0, 0);
        }
    }

    float* Hs = sH[wave];
#pragma unroll
    for (int nt = 0; nt < 4; nt++) {
        int col = nt * 16 + m;
        float b = B1[col];
#pragma unroll
        for (int r = 0; r < 4; r++) {
            int lr = quad * 4 + r;
            Hs[lr * HS_STRIDE + col] = fmaxf(acc[nt][r] + b, 0.f);
        }
    }
    float4 h0 = *(const float4*)&Hs[m * HS_STRIDE + quad * 8];
    float4 h1 = *(const float4*)&Hs[m * HS_STRIDE + quad * 8 + 4];
    float4 h2 = *(const float4*)&Hs[m * HS_STRIDE + 32 + quad * 8];
    float4 h3 = *(const float4*)&Hs[m * HS_STRIDE + 32 + quad * 8 + 4];
    short8 Hh0, Hl0, Hh1, Hl1;
    split8(h0, h1, &Hh0, &Hl0);
    split8(h2, h3, &Hh1, &Hl1);

    floatx4 acc2[4];
#pragma unroll
    for (int nt = 0; nt < 4; nt++) acc2[nt] = (floatx4){0.f, 0.f, 0.f, 0.f};
    const unsigned short* wg2 = wfL + 8192;
#pragma unroll
    for (int nt = 0; nt < 4; nt++) {
#pragma unroll
        for (int ks = 0; ks < 2; ks++) {
            const short8 Bh = *(const short8*)(wg2 + (nt * 2 + ks) * 512 + lane * 8);
            const short8 Bl = *(const short8*)(wg2 + 4096 + (nt * 2 + ks) * 512 + lane * 8);
            short8 Ahf = ks ? Hh1 : Hh0;
            short8 Alf = ks ? Hl1 : Hl0;
            acc2[nt] = __builtin_amdgcn_mfma_f32_16x16x32_bf16(Ahf, Bh, acc2[nt], 0, 0, 0);
            acc2[nt] = __builtin_amdgcn_mfma_f32_16x16x32_bf16(Ahf, Bl, acc2[nt], 0, 0, 0);
            acc2[nt] = __builtin_amdgcn_mfma_f32_16x16x32_bf16(Alf, Bh, acc2[nt], 0, 0, 0);
        }
    }

    // ---- epilogue: bf16 z write + BN partials + per-graph raw pooling
    int widx = wave * 16;
    int gfirst = sBatch[widx], glast = sBatch[widx + 15];
    bool uni = (gfirst == glast) && (gfirst >= 0);
#pragma unroll
    for (int nt = 0; nt < 4; nt++) {
        int col = nt * 16 + m;
        float b = B2[col];
        float vv[4];
        float s = 0.f, s2 = 0.f;
#pragma unroll
        for (int r = 0; r < 4; r++) {
            int gr = row0 + quad * 4 + r;
            float v = fmaxf(acc2[nt][r] + b, 0.f);
            if (gr < N_NODES) {
                if (write_z) zb[(size_t)gr * DIM + col] = bf16_rn(v);
                s += v;
                s2 = fmaf(v, v, s2);
                vv[r] = v;
            } else {
                vv[r] = 0.f;
            }
        }
        float sf = s, s2f = s2;
        sf  += __shfl_xor(sf, 16);  sf  += __shfl_xor(sf, 32);
        s2f += __shfl_xor(s2f, 16); s2f += __shfl_xor(s2f, 32);
        if (quad == 0) {
            atomicAdd(&sSum[col], sf);
            atomicAdd(&sSum[DIM + col], s2f);
            if (uni) atomicAdd(&praw[(size_t)gfirst * DIM + col], sf);
        }
        if (!uni) {
            int cur = -1; float run = 0.f;
#pragma unroll
            for (int r = 0; r < 4; r++) {
                int g = sBatch[widx + quad * 4 + r];
                if (g != cur) {
                    if (cur >= 0 && run != 0.f)
                        atomicAdd(&praw[(size_t)cur * DIM + col], run);
                    run = 0.f; cur = g;
                }
                run += vv[r];
            }
            if (cur >= 0 && run != 0.f)
                atomicAdd(&praw[(size_t)cur * DIM + col], run);
        }
    }
    __syncthreads();
    if (tid < 2 * DIM)
        atomicAdd(&sums_part[(size_t)(blockIdx.x & (N_PART - 1)) * 2 * DIM + tid], sSum[tid]);
}

// --------------------------------------------- BN scale/shift from partials
__global__ void finalize_stats(const float* __restrict__ sp,
                               const float* __restrict__ gamma,
                               const float* __restrict__ beta,
                               float* __restrict__ ss) {
    int c = threadIdx.x;
    float s = 0.f, q = 0.f;
    for (int p = 0; p < N_PART; p++) {
        s += sp[p * 2 * DIM + c];
        q += sp[p * 2 * DIM + DIM + c];
    }
    const float inv_n = 1.0f / (float)N_NODES;
    float mu  = s * inv_n;
    float var = q * inv_n - mu * mu;
    float sc  = gamma[c] / sqrtf(var + BN_EPS);
    ss[c]       = sc;
    ss[DIM + c] = beta[c] - mu * sc;
}

// ------------------- pooled[g][L*64+c] = sc*praw + cnt_g*sh
__global__ __launch_bounds__(256) void assemble_pooled(const float* __restrict__ praw,
                                                       const float* __restrict__ ssAll,
                                                       const int* __restrict__ cntg,
                                                       float* __restrict__ pooled) {
    int idx = blockIdx.x * 256 + threadIdx.x;
    if (idx >= N_GRAPHS * D3) return;
    int g = idx / D3, j = idx - g * D3, L = j >> 6, c = j & 63;
    float sc = ssAll[L * 2 * DIM + c], sh = ssAll[L * 2 * DIM + DIM + c];
    pooled[idx] = fmaf(sc, praw[((size_t)L * N_GRAPHS + g) * DIM + c],
                       (float)cntg[g] * sh);
}

// ------------------------------------------------ final 2-layer MLP on pooled
__global__ __launch_bounds__(192) void final_mlp(const float* __restrict__ pooled,
    const float* __restrict__ PW1, const float* __restrict__ PB1,
    const float* __restrict__ PW2, const float* __restrict__ PB2,
    float* __restrict__ out) {
    __shared__ float row[D3];
    __shared__ float hid[D3];
    int g = blockIdx.x, j = threadIdx.x;
    row[j] = pooled[(size_t)g * D3 + j];
    __syncthreads();
    float acc = PB1[j];
    for (int k = 0; k < D3; k++) acc = fmaf(row[k], PW1[k * D3 + j], acc);
    hid[j] = fmaxf(acc, 0.f);
    __syncthreads();
    float acc2 = PB2[j];
    for (int k = 0; k < D3; k++) acc2 = fmaf(hid[k], PW2[k * D3 + j], acc2);
    out[(size_t)g * D3 + j] = acc2;
}

extern "C" void kernel_launch(void* const* d_in, const int* in_sizes, int n_in,
                              void* d_out, int out_size, void* d_ws, size_t ws_size,
                              hipStream_t stream) {
    const float* x     = (const float*)d_in[0];
    const int*   ei    = (const int*)d_in[1];
    const int*   batch = (const int*)d_in[2];
    const float* W1    = (const float*)d_in[3];
    const float* B1    = (const float*)d_in[4];
    const float* W2    = (const float*)d_in[5];
    const float* B2    = (const float*)d_in[6];
    const float* gamma = (const float*)d_in[7];
    const float* beta  = (const float*)d_in[8];
    const float* PW1   = (const float*)d_in[9];
    const float* PB1   = (const float*)d_in[10];
    const float* PW2   = (const float*)d_in[11];
    const float* PB2   = (const float*)d_in[12];
    float* out = (float*)d_out;

    // -------- workspace layout (no aliasing; ~36 MB of 256 MB)
    float*    bufA  = (float*)d_ws;                              // 3,200,000 f (gather out)
    unsigned short* zb = (unsigned short*)(bufA + (size_t)N_NODES * DIM); // 3,200,000 u16
    unsigned* ebuf  = (unsigned*)(zb + (size_t)N_NODES * DIM);   // 782*2048 u32
    int*      csr   = (int*)(ebuf + (size_t)NBKT * ECAP);        // 800,000 i
    int*      rp    = csr + N_EDGES;                             // 50,056 i
    int*      bstart = rp + 50056;                               // 784 i
    int*      bcnt  = bstart + 784;                              // 784 i (written fully)
    int*      counts = bcnt + 784;                               // 153,272 i (written fully)
    int*      offs   = counts + NBKT * NPB;                      // 153,272 i (written fully)
    unsigned short* wfrag = (unsigned short*)(offs + NBKT * NPB); // 49,152 u16
    float*    ssbuf = (float*)(wfrag + 49152);                   // 384 f
    float*    pooled = ssbuf + N_LAYERS * 2 * DIM;               // 49,152 f
    // ---- zeroed region
    int*      cntg  = (int*)(pooled + N_GRAPHS * D3);            // 256 i
    float*    sums_part = (float*)(cntg + N_GRAPHS);             // 24,576 f
    float*    praw  = sums_part + N_LAYERS * N_PART * 2 * DIM;   // 49,152 f

    const int* src = ei;
    const int* dst = ei + N_EDGES;

    const size_t zero_bytes =
        (size_t)N_GRAPHS * sizeof(int) +
        (size_t)(N_LAYERS * N_PART * 2 * DIM + N_LAYERS * N_GRAPHS * DIM) * sizeof(float);
    hipMemsetAsync(cntg, 0, zero_bytes, stream);

    // -------- CSR build: deterministic two-pass partition (no global atomics)
    pass1_hist<<<NPB, 256, 0, stream>>>(dst, counts);
    bucket_scan<<<NBKT, 256, 0, stream>>>(counts, offs, bcnt);
    scan_small<<<1, 1024, 0, stream>>>(bcnt, bstart);
    pass2_scatter<<<NPB, 256, 0, stream>>>(src, dst, offs, ebuf);
    bucket_sort<<<NBKT, 256, 0, stream>>>(ebuf, bcnt, bstart, csr, rp);
    prep_weights<<<(N_LAYERS * 2 * 4096 + 255) / 256, 256, 0, stream>>>(W1, W2, wfrag);
    count_graphs<<<(N_NODES / 8 + 255) / 256, 256, 0, stream>>>(batch, cntg);

    // -------- layers: gather(+affine) -> mlp(bf16 z + stats + raw pool)
    const int GB = (N_NODES + 3) / 4;     // 12500
    const int MB = (N_NODES + 63) / 64;   // 782
    for (int L = 0; L < N_LAYERS; ++L) {
        int write_z = (L < N_LAYERS - 1);
        if (L == 0)
            gather_f32<<<GB, 256, 0, stream>>>(x, bufA, rp, csr);
        else
            gather_bf16<<<GB, 256, 0, stream>>>(zb, bufA, rp, csr,
                                                ssbuf + (size_t)(L - 1) * 2 * DIM);
        mlp_mfma<<<MB, 256, 0, stream>>>(
            bufA, zb,
            wfrag + (size_t)L * 2 * 8192, B1 + (size_t)L * DIM, B2 + (size_t)L * DIM,
            sums_part + (size_t)L * N_PART * 2 * DIM,
            praw + (size_t)L * N_GRAPHS * DIM, batch, write_z);
        finalize_stats<<<1, DIM, 0, stream>>>(sums_part + (size_t)L * N_PART * 2 * DIM,
                                              gamma + (size_t)L * DIM,
                                              beta + (size_t)L * DIM,
                                              ssbuf + (size_t)L * 2 * DIM);
    }

    assemble_pooled<<<(N_GRAPHS * D3 + 255) / 256, 256, 0, stream>>>(praw, ssbuf, cntg, pooled);
    final_mlp<<<N_GRAPHS, 192, 0, stream>>>(pooled, PW1, PB1, PW2, PB2, out);
}

// Round 11
// 284.159 us; speedup vs baseline: 1.6795x; 1.0674x over previous
//
#include <hip/hip_runtime.h>

#define N_NODES 50000
#define N_EDGES 800000
#define DIM 64
#define N_LAYERS 3
#define N_GRAPHS 256
#define BN_EPS 1e-5f
#define D3 (DIM * N_LAYERS)
#define N_PART 64
#define NBKT 782          // ceil(50000/64) destination buckets
#define NPB 196           // partition blocks (4096 edges each)
#define ECAP 2048         // fixed capacity per bucket (mean 1023, sigma ~32)

typedef __attribute__((ext_vector_type(8))) short short8;
typedef __attribute__((ext_vector_type(4))) float floatx4;

// ---------------------------------------------------------- bf16 split utils
__device__ inline unsigned short bf16_rn(float f) {
    unsigned u = __float_as_uint(f);
    u += 0x7FFF + ((u >> 16) & 1);
    return (unsigned short)(u >> 16);
}
__device__ inline float bf16_f(unsigned short b) {
    return __uint_as_float(((unsigned)b) << 16);
}
__device__ inline void split8(float4 a, float4 b, short8* hi, short8* lo) {
    float v[8] = {a.x, a.y, a.z, a.w, b.x, b.y, b.z, b.w};
#pragma unroll
    for (int i = 0; i < 8; i++) {
        unsigned short h = bf16_rn(v[i]);
        (*hi)[i] = (short)h;
        (*lo)[i] = (short)bf16_rn(v[i] - bf16_f(h));
    }
}

// -------- pass 1: per-block LDS hist over buckets -> counts[bucket][block]
__global__ __launch_bounds__(256) void pass1_hist(const int* __restrict__ dst,
                                                  int* __restrict__ counts) {
    __shared__ int hcnt[NBKT];
    for (int i = threadIdx.x; i < NBKT; i += 256) hcnt[i] = 0;
    __syncthreads();
    int base = blockIdx.x * 4096;
#pragma unroll
    for (int k = 0; k < 16; k++) {
        int e = base + k * 256 + threadIdx.x;
        if (e < N_EDGES) atomicAdd(&hcnt[dst[e] >> 6], 1);   // LDS atomic (native)
    }
    __syncthreads();
    for (int i = threadIdx.x; i < NBKT; i += 256)
        counts[i * NPB + blockIdx.x] = hcnt[i];
}

// -------- per-bucket exclusive scan over the 196 block counts -> offs, totals
__global__ __launch_bounds__(256) void bucket_scan(const int* __restrict__ counts,
                                                   int* __restrict__ offs,
                                                   int* __restrict__ bcnt) {
    __shared__ int s[256];
    int b = blockIdx.x, t = threadIdx.x;
    int v = (t < NPB) ? counts[b * NPB + t] : 0;
    s[t] = v;
    __syncthreads();
    for (int off = 1; off < 256; off <<= 1) {
        int u = (t >= off) ? s[t - off] : 0;
        __syncthreads();
        s[t] += u;
        __syncthreads();
    }
    if (t < NPB) offs[b * NPB + t] = s[t] - v;
    if (t == NPB - 1) bcnt[b] = s[t];
}

// ------------------------------- exclusive scan of 782 bucket totals
__global__ __launch_bounds__(1024) void scan_small(const int* __restrict__ bcnt,
                                                   int* __restrict__ bstart) {
    __shared__ int s[1024];
    int t = threadIdx.x;
    int v = (t < NBKT) ? bcnt[t] : 0;
    s[t] = v;
    __syncthreads();
    for (int off = 1; off < 1024; off <<= 1) {
        int u = (t >= off) ? s[t - off] : 0;
        __syncthreads();
        s[t] += u;
        __syncthreads();
    }
    if (t < NBKT) bstart[t] = s[t] - v;
    if (t == NBKT - 1) bstart[NBKT] = s[t];
}

// -------- pass 2: deterministic scatter via LDS position counters
__global__ __launch_bounds__(256) void pass2_scatter(const int* __restrict__ src,
                                                     const int* __restrict__ dst,
                                                     const int* __restrict__ offs,
                                                     unsigned* __restrict__ ebuf) {
    __shared__ int loff[NBKT];
    int blk = blockIdx.x;
    for (int i = threadIdx.x; i < NBKT; i += 256)
        loff[i] = offs[i * NPB + blk];
    __syncthreads();
    int base = blk * 4096;
#pragma unroll
    for (int k = 0; k < 16; k++) {
        int e = base + k * 256 + threadIdx.x;
        if (e < N_EDGES) {
            int d = dst[e];
            int b = d >> 6;
            int pos = atomicAdd(&loff[b], 1);     // LDS int atomic (native)
            ebuf[(size_t)b * ECAP + pos] = ((unsigned)src[e] << 6) | (unsigned)(d & 63);
        }
    }
}

// --------- counting-sort each bucket's edges by dst&63 -> per-node CSR + rp
__global__ __launch_bounds__(256) void bucket_sort(const unsigned* __restrict__ ebuf,
                                                   const int* __restrict__ bcnt,
                                                   const int* __restrict__ bstart,
                                                   int* __restrict__ csr,
                                                   int* __restrict__ rp) {
    __shared__ unsigned ent[ECAP];
    __shared__ int cnt[64], basea[64], fill[64];
    int b = blockIdx.x, tid = threadIdx.x;
    int start = bstart[b];
    int T = bcnt[b];
    const unsigned* eb = ebuf + (size_t)b * ECAP;
    if (tid < 64) cnt[tid] = 0;
    for (int i = tid; i < T; i += 256) ent[i] = eb[i];
    __syncthreads();
    for (int i = tid; i < T; i += 256) atomicAdd(&cnt[ent[i] & 63], 1);
    __syncthreads();
    if (tid < 64) {
        int v = cnt[tid], x = v;
#pragma unroll
        for (int off = 1; off < 64; off <<= 1) {
            int y = __shfl_up(x, off);
            if (tid >= off) x += y;
        }
        basea[tid] = x - v;
        fill[tid] = 0;
        rp[b * 64 + tid] = start + x - v;
    }
    __syncthreads();
    for (int i = tid; i < T; i += 256) {
        unsigned e = ent[i];
        int c = e & 63;
        int pos = basea[c] + atomicAdd(&fill[c], 1);
        csr[start + pos] = (int)(e >> 6);
    }
}

// -------------------------------------------- per-graph node counts (sorted)
__global__ __launch_bounds__(256) void count_graphs(const int* __restrict__ batch,
                                                    int* __restrict__ cntg) {
    int grp = blockIdx.x * 256 + threadIdx.x;
    if (grp >= N_NODES / 8) return;
    int n0 = grp * 8, run = 0, cur = batch[n0];
#pragma unroll
    for (int r = 0; r < 8; r++) {
        int b = batch[n0 + r];
        if (b != cur) { atomicAdd(&cntg[cur], run); run = 0; cur = b; }
        run++;
    }
    atomicAdd(&cntg[cur], run);
}

// -------- gather (f32 input, layer 0): z[i] = h[i] + sum_{j->i} h[j]
// 16 lanes per row (lane&15 = channel quad, lane>>4 = edge slot):
// one wave-wide load instruction fetches 4 neighbor rows.
__global__ __launch_bounds__(256) void gather_f32(const float* __restrict__ h,
                                                  float* __restrict__ z,
                                                  const int* __restrict__ rp,
                                                  const int* __restrict__ csr) {
    int node = blockIdx.x * 4 + (threadIdx.x >> 6);
    if (node >= N_NODES) return;
    int lane = threadIdx.x & 63;
    int c4 = lane & 15, sub = lane >> 4;
    int e = rp[node], end = rp[node + 1];
    float a0 = 0.f, a1 = 0.f, a2 = 0.f, a3 = 0.f;
    if (sub == 0) {
        float4 sv = *(const float4*)&h[(size_t)node * DIM + c4 * 4];
        a0 = sv.x; a1 = sv.y; a2 = sv.z; a3 = sv.w;
    }
    for (; e + 16 <= end; e += 16) {
        int i0 = csr[e + sub], i1 = csr[e + 4 + sub];
        int i2 = csr[e + 8 + sub], i3 = csr[e + 12 + sub];
        float4 r0 = *(const float4*)&h[(size_t)i0 * DIM + c4 * 4];
        float4 r1 = *(const float4*)&h[(size_t)i1 * DIM + c4 * 4];
        float4 r2 = *(const float4*)&h[(size_t)i2 * DIM + c4 * 4];
        float4 r3 = *(const float4*)&h[(size_t)i3 * DIM + c4 * 4];
        a0 += (r0.x + r1.x) + (r2.x + r3.x);
        a1 += (r0.y + r1.y) + (r2.y + r3.y);
        a2 += (r0.z + r1.z) + (r2.z + r3.z);
        a3 += (r0.w + r1.w) + (r2.w + r3.w);
    }
    for (; e < end; e += 4) {
        int idx = e + sub;
        if (idx < end) {
            float4 r = *(const float4*)&h[(size_t)csr[idx] * DIM + c4 * 4];
            a0 += r.x; a1 += r.y; a2 += r.z; a3 += r.w;
        }
    }
    a0 += __shfl_xor(a0, 16); a0 += __shfl_xor(a0, 32);
    a1 += __shfl_xor(a1, 16); a1 += __shfl_xor(a1, 32);
    a2 += __shfl_xor(a2, 16); a2 += __shfl_xor(a2, 32);
    a3 += __shfl_xor(a3, 16); a3 += __shfl_xor(a3, 32);
    if (sub == 0) {
        float4 o = {a0, a1, a2, a3};
        *(float4*)&z[(size_t)node * DIM + c4 * 4] = o;
    }
}

// -------- gather (bf16 input, layers>=1) + prev-layer BN affine:
// z[i] = sc*(h[i]+sum h[j]) + (1+deg)*sh ; 16 lanes/row, 4 rows/instruction
__global__ __launch_bounds__(256) void gather_bf16(const unsigned short* __restrict__ hb,
                                                   float* __restrict__ z,
                                                   const int* __restrict__ rp,
                                                   const int* __restrict__ csr,
                                                   const float* __restrict__ ss) {
    int node = blockIdx.x * 4 + (threadIdx.x >> 6);
    if (node >= N_NODES) return;
    int lane = threadIdx.x & 63;
    int c4 = lane & 15, sub = lane >> 4;
    int e = rp[node], end = rp[node + 1];
    float degf = 1.f + (float)(end - e);
    float a0 = 0.f, a1 = 0.f, a2 = 0.f, a3 = 0.f;
    if (sub == 0) {
        ushort4 sv = *(const ushort4*)&hb[(size_t)node * DIM + c4 * 4];
        a0 = bf16_f(sv.x); a1 = bf16_f(sv.y); a2 = bf16_f(sv.z); a3 = bf16_f(sv.w);
    }
    for (; e + 16 <= end; e += 16) {
        int i0 = csr[e + sub], i1 = csr[e + 4 + sub];
        int i2 = csr[e + 8 + sub], i3 = csr[e + 12 + sub];
        ushort4 r0 = *(const ushort4*)&hb[(size_t)i0 * DIM + c4 * 4];
        ushort4 r1 = *(const ushort4*)&hb[(size_t)i1 * DIM + c4 * 4];
        ushort4 r2 = *(const ushort4*)&hb[(size_t)i2 * DIM + c4 * 4];
        ushort4 r3 = *(const ushort4*)&hb[(size_t)i3 * DIM + c4 * 4];
        a0 += (bf16_f(r0.x) + bf16_f(r1.x)) + (bf16_f(r2.x) + bf16_f(r3.x));
        a1 += (bf16_f(r0.y) + bf16_f(r1.y)) + (bf16_f(r2.y) + bf16_f(r3.y));
        a2 += (bf16_f(r0.z) + bf16_f(r1.z)) + (bf16_f(r2.z) + bf16_f(r3.z));
        a3 += (bf16_f(r0.w) + bf16_f(r1.w)) + (bf16_f(r2.w) + bf16_f(r3.w));
    }
    for (; e < end; e += 4) {
        int idx = e + sub;
        if (idx < end) {
            ushort4 r = *(const ushort4*)&hb[(size_t)csr[idx] * DIM + c4 * 4];
            a0 += bf16_f(r.x); a1 += bf16_f(r.y); a2 += bf16_f(r.z); a3 += bf16_f(r.w);
        }
    }
    a0 += __shfl_xor(a0, 16); a0 += __shfl_xor(a0, 32);
    a1 += __shfl_xor(a1, 16); a1 += __shfl_xor(a1, 32);
    a2 += __shfl_xor(a2, 16); a2 += __shfl_xor(a2, 32);
    a3 += __shfl_xor(a3, 16); a3 += __shfl_xor(a3, 32);
    if (sub == 0) {
        int ch = c4 * 4;
        float4 o;
        o.x = fmaf(a0, ss[ch + 0], degf * ss[DIM + ch + 0]);
        o.y = fmaf(a1, ss[ch + 1], degf * ss[DIM + ch + 1]);
        o.z = fmaf(a2, ss[ch + 2], degf * ss[DIM + ch + 2]);
        o.w = fmaf(a3, ss[ch + 3], degf * ss[DIM + ch + 3]);
        *(float4*)&z[(size_t)node * DIM + ch] = o;
    }
}

// --------------- pack W1/W2 into MFMA B-operand fragments, split bf16 hi/lo
__global__ __launch_bounds__(256) void prep_weights(const float* __restrict__ W1,
                                                    const float* __restrict__ W2,
                                                    unsigned short* __restrict__ wf) {
    int idx = blockIdx.x * 256 + threadIdx.x;
    if (idx >= N_LAYERS * 2 * 4096) return;
    int j    = idx & 7;
    int lane = (idx >> 3) & 63;
    int ks   = (idx >> 9) & 1;
    int nt   = (idx >> 10) & 3;
    int gemm = (idx >> 12) & 1;
    int layer = idx >> 13;
    int n = nt * 16 + (lane & 15);
    int k = ks * 32 + (lane >> 4) * 8 + j;
    const float* W = (gemm ? W2 : W1) + (size_t)layer * DIM * DIM;
    float w = W[k * DIM + n];
    unsigned short hi = bf16_rn(w);
    unsigned short lo = bf16_rn(w - bf16_f(hi));
    size_t base = ((size_t)layer * 2 + gemm) * 8192;
    int f = nt * 2 + ks;
    wf[base + f * 512 + lane * 8 + j]        = hi;
    wf[base + 4096 + f * 512 + lane * 8 + j] = lo;
}

// ------- MFMA MLP: bf16 z' = relu(relu(zW1+B1)W2+B2) + BN partials + raw pool
#define HS_STRIDE 68
__global__ __launch_bounds__(256) void mlp_mfma(const float* __restrict__ z,
    unsigned short* __restrict__ zb,
    const unsigned short* __restrict__ wfL,
    const float* __restrict__ B1, const float* __restrict__ B2,
    float* __restrict__ sums_part, float* __restrict__ praw,
    const int* __restrict__ batch, int write_z) {
    __shared__ float sH[4][16 * HS_STRIDE];
    __shared__ float sSum[2 * DIM];
    __shared__ int   sBatch[64];

    int tid = threadIdx.x, wave = tid >> 6, lane = tid & 63;
    int blk0 = blockIdx.x * 64;
    if (tid < 2 * DIM) sSum[tid] = 0.f;
    if (tid < 64) sBatch[tid] = (blk0 + tid < N_NODES) ? batch[blk0 + tid] : -1;
    __syncthreads();

    int m = lane & 15, quad = lane >> 4;
    int row0 = blk0 + wave * 16;
    int grow = row0 + m;
    int ar = grow < N_NODES ? grow : N_NODES - 1;

    const float4* zr = (const float4*)(z + (size_t)ar * DIM);
    float4 a0 = zr[quad * 2],     a1 = zr[quad * 2 + 1];
    float4 a2 = zr[8 + quad * 2], a3 = zr[8 + quad * 2 + 1];
    short8 Ah0, Al0, Ah1, Al1;
    split8(a0, a1, &Ah0, &Al0);
    split8(a2, a3, &Ah1, &Al1);

    floatx4 acc[4];
#pragma unroll
    for (int nt = 0; nt < 4; nt++) acc[nt] = (floatx4){0.f, 0.f, 0.f, 0.f};
#pragma unroll
    for (int nt = 0; nt < 4; nt++) {
#pragma unroll
        for (int ks = 0; ks < 2; ks++) {
            const short8 Bh = *(const short8*)(wfL + (nt * 2 + ks) * 512 + lane * 8);
            const short8 Bl = *(const short8*)(wfL + 4096 + (nt * 2 + ks) * 512 + lane * 8);
            short8 Ahf = ks ? Ah1 : Ah0;
            short8 Alf = ks ? Al1 : Al0;
            acc[nt] = __builtin_amdgcn_mfma_f32_16x16x32_bf16(Ahf, Bh, acc[nt], 0, 0, 0);
            acc[nt] = __builtin_amdgcn_mfma_f32_16x16x32_bf16(Ahf, Bl, acc[nt], 0, 0, 0);
            acc[nt] = __builtin_amdgcn_mfma_f32_16x16x32_bf16(Alf, Bh, acc[nt], 0, 0, 0);
        }
    }

    float* Hs = sH[wave];
#pragma unroll
    for (int nt = 0; nt < 4; nt++) {
        int col = nt * 16 + m;
        float b = B1[col];
#pragma unroll
        for (int r = 0; r < 4; r++) {
            int lr = quad * 4 + r;
            Hs[lr * HS_STRIDE + col] = fmaxf(acc[nt][r] + b, 0.f);
        }
    }
    float4 h0 = *(const float4*)&Hs[m * HS_STRIDE + quad * 8];
    float4 h1 = *(const float4*)&Hs[m * HS_STRIDE + quad * 8 + 4];
    float4 h2 = *(const float4*)&Hs[m * HS_STRIDE + 32 + quad * 8];
    float4 h3 = *(const float4*)&Hs[m * HS_STRIDE + 32 + quad * 8 + 4];
    short8 Hh0, Hl0, Hh1, Hl1;
    split8(h0, h1, &Hh0, &Hl0);
    split8(h2, h3, &Hh1, &Hl1);

    floatx4 acc2[4];
#pragma unroll
    for (int nt = 0; nt < 4; nt++) acc2[nt] = (floatx4){0.f, 0.f, 0.f, 0.f};
    const unsigned short* wg2 = wfL + 8192;
#pragma unroll
    for (int nt = 0; nt < 4; nt++) {
#pragma unroll
        for (int ks = 0; ks < 2; ks++) {
            const short8 Bh = *(const short8*)(wg2 + (nt * 2 + ks) * 512 + lane * 8);
            const short8 Bl = *(const short8*)(wg2 + 4096 + (nt * 2 + ks) * 512 + lane * 8);
            short8 Ahf = ks ? Hh1 : Hh0;
            short8 Alf = ks ? Hl1 : Hl0;
            acc2[nt] = __builtin_amdgcn_mfma_f32_16x16x32_bf16(Ahf, Bh, acc2[nt], 0, 0, 0);
            acc2[nt] = __builtin_amdgcn_mfma_f32_16x16x32_bf16(Ahf, Bl, acc2[nt], 0, 0, 0);
            acc2[nt] = __builtin_amdgcn_mfma_f32_16x16x32_bf16(Alf, Bh, acc2[nt], 0, 0, 0);
        }
    }

    // ---- epilogue: bf16 z write + BN partials + per-graph raw pooling
    int widx = wave * 16;
    int gfirst = sBatch[widx], glast = sBatch[widx + 15];
    bool uni = (gfirst == glast) && (gfirst >= 0);
#pragma unroll
    for (int nt = 0; nt < 4; nt++) {
        int col = nt * 16 + m;
        float b = B2[col];
        float vv[4];
        float s = 0.f, s2 = 0.f;
#pragma unroll
        for (int r = 0; r < 4; r++) {
            int gr = row0 + quad * 4 + r;
            float v = fmaxf(acc2[nt][r] + b, 0.f);
            if (gr < N_NODES) {
                if (write_z) zb[(size_t)gr * DIM + col] = bf16_rn(v);
                s += v;
                s2 = fmaf(v, v, s2);
                vv[r] = v;
            } else {
                vv[r] = 0.f;
            }
        }
        float sf = s, s2f = s2;
        sf  += __shfl_xor(sf, 16);  sf  += __shfl_xor(sf, 32);
        s2f += __shfl_xor(s2f, 16); s2f += __shfl_xor(s2f, 32);
        if (quad == 0) {
            atomicAdd(&sSum[col], sf);
            atomicAdd(&sSum[DIM + col], s2f);
            if (uni) atomicAdd(&praw[(size_t)gfirst * DIM + col], sf);
        }
        if (!uni) {
            int cur = -1; float run = 0.f;
#pragma unroll
            for (int r = 0; r < 4; r++) {
                int g = sBatch[widx + quad * 4 + r];
                if (g != cur) {
                    if (cur >= 0 && run != 0.f)
                        atomicAdd(&praw[(size_t)cur * DIM + col], run);
                    run = 0.f; cur = g;
                }
                run += vv[r];
            }
            if (cur >= 0 && run != 0.f)
                atomicAdd(&praw[(size_t)cur * DIM + col], run);
        }
    }
    __syncthreads();
    if (tid < 2 * DIM)
        atomicAdd(&sums_part[(size_t)(blockIdx.x & (N_PART - 1)) * 2 * DIM + tid], sSum[tid]);
}

// --------------------------------------------- BN scale/shift from partials
__global__ void finalize_stats(const float* __restrict__ sp,
                               const float* __restrict__ gamma,
                               const float* __restrict__ beta,
                               float* __restrict__ ss) {
    int c = threadIdx.x;
    float s = 0.f, q = 0.f;
    for (int p = 0; p < N_PART; p++) {
        s += sp[p * 2 * DIM + c];
        q += sp[p * 2 * DIM + DIM + c];
    }
    const float inv_n = 1.0f / (float)N_NODES;
    float mu  = s * inv_n;
    float var = q * inv_n - mu * mu;
    float sc  = gamma[c] / sqrtf(var + BN_EPS);
    ss[c]       = sc;
    ss[DIM + c] = beta[c] - mu * sc;
}

// ------------------- pooled[g][L*64+c] = sc*praw + cnt_g*sh
__global__ __launch_bounds__(256) void assemble_pooled(const float* __restrict__ praw,
                                                       const float* __restrict__ ssAll,
                                                       const int* __restrict__ cntg,
                                                       float* __restrict__ pooled) {
    int idx = blockIdx.x * 256 + threadIdx.x;
    if (idx >= N_GRAPHS * D3) return;
    int g = idx / D3, j = idx - g * D3, L = j >> 6, c = j & 63;
    float sc = ssAll[L * 2 * DIM + c], sh = ssAll[L * 2 * DIM + DIM + c];
    pooled[idx] = fmaf(sc, praw[((size_t)L * N_GRAPHS + g) * DIM + c],
                       (float)cntg[g] * sh);
}

// ------------------------------------------------ final 2-layer MLP on pooled
__global__ __launch_bounds__(192) void final_mlp(const float* __restrict__ pooled,
    const float* __restrict__ PW1, const float* __restrict__ PB1,
    const float* __restrict__ PW2, const float* __restrict__ PB2,
    float* __restrict__ out) {
    __shared__ float row[D3];
    __shared__ float hid[D3];
    int g = blockIdx.x, j = threadIdx.x;
    row[j] = pooled[(size_t)g * D3 + j];
    __syncthreads();
    float acc = PB1[j];
    for (int k = 0; k < D3; k++) acc = fmaf(row[k], PW1[k * D3 + j], acc);
    hid[j] = fmaxf(acc, 0.f);
    __syncthreads();
    float acc2 = PB2[j];
    for (int k = 0; k < D3; k++) acc2 = fmaf(hid[k], PW2[k * D3 + j], acc2);
    out[(size_t)g * D3 + j] = acc2;
}

extern "C" void kernel_launch(void* const* d_in, const int* in_sizes, int n_in,
                              void* d_out, int out_size, void* d_ws, size_t ws_size,
                              hipStream_t stream) {
    const float* x     = (const float*)d_in[0];
    const int*   ei    = (const int*)d_in[1];
    const int*   batch = (const int*)d_in[2];
    const float* W1    = (const float*)d_in[3];
    const float* B1    = (const float*)d_in[4];
    const float* W2    = (const float*)d_in[5];
    const float* B2    = (const float*)d_in[6];
    const float* gamma = (const float*)d_in[7];
    const float* beta  = (const float*)d_in[8];
    const float* PW1   = (const float*)d_in[9];
    const float* PB1   = (const float*)d_in[10];
    const float* PW2   = (const float*)d_in[11];
    const float* PB2   = (const float*)d_in[12];
    float* out = (float*)d_out;

    // -------- workspace layout (no aliasing; ~36 MB of 256 MB)
    float*    bufA  = (float*)d_ws;                              // 3,200,000 f (gather out)
    unsigned short* zb = (unsigned short*)(bufA + (size_t)N_NODES * DIM); // 3,200,000 u16
    unsigned* ebuf  = (unsigned*)(zb + (size_t)N_NODES * DIM);   // 782*2048 u32
    int*      csr   = (int*)(ebuf + (size_t)NBKT * ECAP);        // 800,000 i
    int*      rp    = csr + N_EDGES;                             // 50,056 i
    int*      bstart = rp + 50056;                               // 784 i
    int*      bcnt  = bstart + 784;                              // 784 i (written fully)
    int*      counts = bcnt + 784;                               // 153,272 i (written fully)
    int*      offs   = counts + NBKT * NPB;                      // 153,272 i (written fully)
    unsigned short* wfrag = (unsigned short*)(offs + NBKT * NPB); // 49,152 u16
    float*    ssbuf = (float*)(wfrag + 49152);                   // 384 f
    float*    pooled = ssbuf + N_LAYERS * 2 * DIM;               // 49,152 f
    // ---- zeroed region
    int*      cntg  = (int*)(pooled + N_GRAPHS * D3);            // 256 i
    float*    sums_part = (float*)(cntg + N_GRAPHS);             // 24,576 f
    float*    praw  = sums_part + N_LAYERS * N_PART * 2 * DIM;   // 49,152 f

    const int* src = ei;
    const int* dst = ei + N_EDGES;

    const size_t zero_bytes =
        (size_t)N_GRAPHS * sizeof(int) +
        (size_t)(N_LAYERS * N_PART * 2 * DIM + N_LAYERS * N_GRAPHS * DIM) * sizeof(float);
    hipMemsetAsync(cntg, 0, zero_bytes, stream);

    // -------- CSR build: deterministic two-pass partition (no global atomics)
    pass1_hist<<<NPB, 256, 0, stream>>>(dst, counts);
    bucket_scan<<<NBKT, 256, 0, stream>>>(counts, offs, bcnt);
    scan_small<<<1, 1024, 0, stream>>>(bcnt, bstart);
    pass2_scatter<<<NPB, 256, 0, stream>>>(src, dst, offs, ebuf);
    bucket_sort<<<NBKT, 256, 0, stream>>>(ebuf, bcnt, bstart, csr, rp);
    prep_weights<<<(N_LAYERS * 2 * 4096 + 255) / 256, 256, 0, stream>>>(W1, W2, wfrag);
    count_graphs<<<(N_NODES / 8 + 255) / 256, 256, 0, stream>>>(batch, cntg);

    // -------- layers: gather(+affine) -> mlp(bf16 z + stats + raw pool)
    const int GB = (N_NODES + 3) / 4;     // 12500
    const int MB = (N_NODES + 63) / 64;   // 782
    for (int L = 0; L < N_LAYERS; ++L) {
        int write_z = (L < N_LAYERS - 1);
        if (L == 0)
            gather_f32<<<GB, 256, 0, stream>>>(x, bufA, rp, csr);
        else
            gather_bf16<<<GB, 256, 0, stream>>>(zb, bufA, rp, csr,
                                                ssbuf + (size_t)(L - 1) * 2 * DIM);
        mlp_mfma<<<MB, 256, 0, stream>>>(
            bufA, zb,
            wfrag + (size_t)L * 2 * 8192, B1 + (size_t)L * DIM, B2 + (size_t)L * DIM,
            sums_part + (size_t)L * N_PART * 2 * DIM,
            praw + (size_t)L * N_GRAPHS * DIM, batch, write_z);
        finalize_stats<<<1, DIM, 0, stream>>>(sums_part + (size_t)L * N_PART * 2 * DIM,
                                              gamma + (size_t)L * DIM,
                                              beta + (size_t)L * DIM,
                                              ssbuf + (size_t)L * 2 * DIM);
    }

    assemble_pooled<<<(N_GRAPHS * D3 + 255) / 256, 256, 0, stream>>>(praw, ssbuf, cntg, pooled);
    final_mlp<<<N_GRAPHS, 192, 0, stream>>>(pooled, PW1, PB1, PW2, PB2, out);
}

// Round 12
// 276.017 us; speedup vs baseline: 1.7290x; 1.0295x over previous
//
#include <hip/hip_runtime.h>

#define N_NODES 50000
#define N_EDGES 800000
#define DIM 64
#define N_LAYERS 3
#define N_GRAPHS 256
#define BN_EPS 1e-5f
#define D3 (DIM * N_LAYERS)
#define N_PART 64
#define NBKT 782          // ceil(50000/64) destination buckets
#define NPB 196           // partition blocks (4096 edges each)
#define ECAP 2048         // fixed capacity per bucket (mean 1023, sigma ~32)

typedef __attribute__((ext_vector_type(8))) short short8;
typedef __attribute__((ext_vector_type(4))) float floatx4;

// ---------------------------------------------------------- bf16 split utils
__device__ inline unsigned short bf16_rn(float f) {
    unsigned u = __float_as_uint(f);
    u += 0x7FFF + ((u >> 16) & 1);
    return (unsigned short)(u >> 16);
}
__device__ inline float bf16_f(unsigned short b) {
    return __uint_as_float(((unsigned)b) << 16);
}
__device__ inline void split8(float4 a, float4 b, short8* hi, short8* lo) {
    float v[8] = {a.x, a.y, a.z, a.w, b.x, b.y, b.z, b.w};
#pragma unroll
    for (int i = 0; i < 8; i++) {
        unsigned short h = bf16_rn(v[i]);
        (*hi)[i] = (short)h;
        (*lo)[i] = (short)bf16_rn(v[i] - bf16_f(h));
    }
}

// --------------------------------------- x (f32) -> xb (bf16), elementwise
__global__ __launch_bounds__(256) void convert_x(const float* __restrict__ x,
                                                 unsigned short* __restrict__ xb) {
    int i = blockIdx.x * 256 + threadIdx.x;     // one float4 per thread
    if (i >= N_NODES * DIM / 4) return;
    float4 v = ((const float4*)x)[i];
    ushort4 o;
    o.x = bf16_rn(v.x); o.y = bf16_rn(v.y);
    o.z = bf16_rn(v.z); o.w = bf16_rn(v.w);
    ((ushort4*)xb)[i] = o;
}

// -------- pass 1: per-block LDS hist over buckets -> counts[bucket][block]
__global__ __launch_bounds__(256) void pass1_hist(const int* __restrict__ dst,
                                                  int* __restrict__ counts) {
    __shared__ int hcnt[NBKT];
    for (int i = threadIdx.x; i < NBKT; i += 256) hcnt[i] = 0;
    __syncthreads();
    int base = blockIdx.x * 4096;
#pragma unroll
    for (int k = 0; k < 16; k++) {
        int e = base + k * 256 + threadIdx.x;
        if (e < N_EDGES) atomicAdd(&hcnt[dst[e] >> 6], 1);   // LDS atomic (native)
    }
    __syncthreads();
    for (int i = threadIdx.x; i < NBKT; i += 256)
        counts[i * NPB + blockIdx.x] = hcnt[i];
}

// -------- per-bucket exclusive scan over the 196 block counts -> offs, totals
__global__ __launch_bounds__(256) void bucket_scan(const int* __restrict__ counts,
                                                   int* __restrict__ offs,
                                                   int* __restrict__ bcnt) {
    __shared__ int s[256];
    int b = blockIdx.x, t = threadIdx.x;
    int v = (t < NPB) ? counts[b * NPB + t] : 0;
    s[t] = v;
    __syncthreads();
    for (int off = 1; off < 256; off <<= 1) {
        int u = (t >= off) ? s[t - off] : 0;
        __syncthreads();
        s[t] += u;
        __syncthreads();
    }
    if (t < NPB) offs[b * NPB + t] = s[t] - v;
    if (t == NPB - 1) bcnt[b] = s[t];
}

// ------------------------------- exclusive scan of 782 bucket totals
__global__ __launch_bounds__(1024) void scan_small(const int* __restrict__ bcnt,
                                                   int* __restrict__ bstart) {
    __shared__ int s[1024];
    int t = threadIdx.x;
    int v = (t < NBKT) ? bcnt[t] : 0;
    s[t] = v;
    __syncthreads();
    for (int off = 1; off < 1024; off <<= 1) {
        int u = (t >= off) ? s[t - off] : 0;
        __syncthreads();
        s[t] += u;
        __syncthreads();
    }
    if (t < NBKT) bstart[t] = s[t] - v;
    if (t == NBKT - 1) bstart[NBKT] = s[t];
}

// -------- pass 2: deterministic scatter via LDS position counters
__global__ __launch_bounds__(256) void pass2_scatter(const int* __restrict__ src,
                                                     const int* __restrict__ dst,
                                                     const int* __restrict__ offs,
                                                     unsigned* __restrict__ ebuf) {
    __shared__ int loff[NBKT];
    int blk = blockIdx.x;
    for (int i = threadIdx.x; i < NBKT; i += 256)
        loff[i] = offs[i * NPB + blk];
    __syncthreads();
    int base = blk * 4096;
#pragma unroll
    for (int k = 0; k < 16; k++) {
        int e = base + k * 256 + threadIdx.x;
        if (e < N_EDGES) {
            int d = dst[e];
            int b = d >> 6;
            int pos = atomicAdd(&loff[b], 1);     // LDS int atomic (native)
            ebuf[(size_t)b * ECAP + pos] = ((unsigned)src[e] << 6) | (unsigned)(d & 63);
        }
    }
}

// --------- counting-sort each bucket's edges by dst&63 -> per-node CSR + rp
__global__ __launch_bounds__(256) void bucket_sort(const unsigned* __restrict__ ebuf,
                                                   const int* __restrict__ bcnt,
                                                   const int* __restrict__ bstart,
                                                   int* __restrict__ csr,
                                                   int* __restrict__ rp) {
    __shared__ unsigned ent[ECAP];
    __shared__ int cnt[64], basea[64], fill[64];
    int b = blockIdx.x, tid = threadIdx.x;
    int start = bstart[b];
    int T = bcnt[b];
    const unsigned* eb = ebuf + (size_t)b * ECAP;
    if (tid < 64) cnt[tid] = 0;
    for (int i = tid; i < T; i += 256) ent[i] = eb[i];
    __syncthreads();
    for (int i = tid; i < T; i += 256) atomicAdd(&cnt[ent[i] & 63], 1);
    __syncthreads();
    if (tid < 64) {
        int v = cnt[tid], x = v;
#pragma unroll
        for (int off = 1; off < 64; off <<= 1) {
            int y = __shfl_up(x, off);
            if (tid >= off) x += y;
        }
        basea[tid] = x - v;
        fill[tid] = 0;
        rp[b * 64 + tid] = start + x - v;
    }
    __syncthreads();
    for (int i = tid; i < T; i += 256) {
        unsigned e = ent[i];
        int c = e & 63;
        int pos = basea[c] + atomicAdd(&fill[c], 1);
        csr[start + pos] = (int)(e >> 6);
    }
}

// -------------------------------------------- per-graph node counts (sorted)
__global__ __launch_bounds__(256) void count_graphs(const int* __restrict__ batch,
                                                    int* __restrict__ cntg) {
    int grp = blockIdx.x * 256 + threadIdx.x;
    if (grp >= N_NODES / 8) return;
    int n0 = grp * 8, run = 0, cur = batch[n0];
#pragma unroll
    for (int r = 0; r < 8; r++) {
        int b = batch[n0 + r];
        if (b != cur) { atomicAdd(&cntg[cur], run); run = 0; cur = b; }
        run++;
    }
    atomicAdd(&cntg[cur], run);
}

// -------- gather (bf16 rows) + optional prev-layer BN affine
// 8 lanes per row (lane&7 = channel octet, lane>>3 = edge slot):
// one wave-wide ushort8 load fetches 8 neighbor rows.
// z[i] = sc*(h[i]+sum h[j]) + (1+deg)*sh   (ss==null -> identity)
__global__ __launch_bounds__(256) void gather_bf16(const unsigned short* __restrict__ hb,
                                                   float* __restrict__ z,
                                                   const int* __restrict__ rp,
                                                   const int* __restrict__ csr,
                                                   const float* __restrict__ ss) {
    int node = blockIdx.x * 4 + (threadIdx.x >> 6);
    if (node >= N_NODES) return;
    int lane = threadIdx.x & 63;
    int c8 = lane & 7, sub = lane >> 3;
    int e = rp[node], end = rp[node + 1];
    float degf = 1.f + (float)(end - e);
    float a[8];
#pragma unroll
    for (int i = 0; i < 8; i++) a[i] = 0.f;
    if (sub == 0) {
        short8 sv = *(const short8*)&hb[(size_t)node * DIM + c8 * 8];
#pragma unroll
        for (int i = 0; i < 8; i++) a[i] = bf16_f((unsigned short)sv[i]);
    }
    for (; e + 16 <= end; e += 16) {
        int i0 = csr[e + sub];
        int i1 = csr[e + 8 + sub];
        short8 r0 = *(const short8*)&hb[(size_t)i0 * DIM + c8 * 8];
        short8 r1 = *(const short8*)&hb[(size_t)i1 * DIM + c8 * 8];
#pragma unroll
        for (int i = 0; i < 8; i++)
            a[i] += bf16_f((unsigned short)r0[i]) + bf16_f((unsigned short)r1[i]);
    }
    for (; e + 8 <= end; e += 8) {
        int i0 = csr[e + sub];
        short8 r0 = *(const short8*)&hb[(size_t)i0 * DIM + c8 * 8];
#pragma unroll
        for (int i = 0; i < 8; i++) a[i] += bf16_f((unsigned short)r0[i]);
    }
    int rem = end - e;
    if (sub < rem) {
        short8 r0 = *(const short8*)&hb[(size_t)csr[e + sub] * DIM + c8 * 8];
#pragma unroll
        for (int i = 0; i < 8; i++) a[i] += bf16_f((unsigned short)r0[i]);
    }
#pragma unroll
    for (int i = 0; i < 8; i++) {
        a[i] += __shfl_xor(a[i], 8);
        a[i] += __shfl_xor(a[i], 16);
        a[i] += __shfl_xor(a[i], 32);
    }
    if (sub == 0) {
        int ch = c8 * 8;
        float4 o1, o2;
        if (ss) {
            o1.x = fmaf(a[0], ss[ch + 0], degf * ss[DIM + ch + 0]);
            o1.y = fmaf(a[1], ss[ch + 1], degf * ss[DIM + ch + 1]);
            o1.z = fmaf(a[2], ss[ch + 2], degf * ss[DIM + ch + 2]);
            o1.w = fmaf(a[3], ss[ch + 3], degf * ss[DIM + ch + 3]);
            o2.x = fmaf(a[4], ss[ch + 4], degf * ss[DIM + ch + 4]);
            o2.y = fmaf(a[5], ss[ch + 5], degf * ss[DIM + ch + 5]);
            o2.z = fmaf(a[6], ss[ch + 6], degf * ss[DIM + ch + 6]);
            o2.w = fmaf(a[7], ss[ch + 7], degf * ss[DIM + ch + 7]);
        } else {
            o1.x = a[0]; o1.y = a[1]; o1.z = a[2]; o1.w = a[3];
            o2.x = a[4]; o2.y = a[5]; o2.z = a[6]; o2.w = a[7];
        }
        *(float4*)&z[(size_t)node * DIM + ch] = o1;
        *(float4*)&z[(size_t)node * DIM + ch + 4] = o2;
    }
}

// --------------- pack W1/W2 into MFMA B-operand fragments, split bf16 hi/lo
__global__ __launch_bounds__(256) void prep_weights(const float* __restrict__ W1,
                                                    const float* __restrict__ W2,
                                                    unsigned short* __restrict__ wf) {
    int idx = blockIdx.x * 256 + threadIdx.x;
    if (idx >= N_LAYERS * 2 * 4096) return;
    int j    = idx & 7;
    int lane = (idx >> 3) & 63;
    int ks   = (idx >> 9) & 1;
    int nt   = (idx >> 10) & 3;
    int gemm = (idx >> 12) & 1;
    int layer = idx >> 13;
    int n = nt * 16 + (lane & 15);
    int k = ks * 32 + (lane >> 4) * 8 + j;
    const float* W = (gemm ? W2 : W1) + (size_t)layer * DIM * DIM;
    float w = W[k * DIM + n];
    unsigned short hi = bf16_rn(w);
    unsigned short lo = bf16_rn(w - bf16_f(hi));
    size_t base = ((size_t)layer * 2 + gemm) * 8192;
    int f = nt * 2 + ks;
    wf[base + f * 512 + lane * 8 + j]        = hi;
    wf[base + 4096 + f * 512 + lane * 8 + j] = lo;
}

// ------- MFMA MLP: bf16 z' = relu(relu(zW1+B1)W2+B2) + BN partials + raw pool
#define HS_STRIDE 68
__global__ __launch_bounds__(256) void mlp_mfma(const float* __restrict__ z,
    unsigned short* __restrict__ zb,
    const unsigned short* __restrict__ wfL,
    const float* __restrict__ B1, const float* __restrict__ B2,
    float* __restrict__ sums_part, float* __restrict__ praw,
    const int* __restrict__ batch, int write_z) {
    __shared__ float sH[4][16 * HS_STRIDE];
    __shared__ float sSum[2 * DIM];
    __shared__ int   sBatch[64];

    int tid = threadIdx.x, wave = tid >> 6, lane = tid & 63;
    int blk0 = blockIdx.x * 64;
    if (tid < 2 * DIM) sSum[tid] = 0.f;
    if (tid < 64) sBatch[tid] = (blk0 + tid < N_NODES) ? batch[blk0 + tid] : -1;
    __syncthreads();

    int m = lane & 15, quad = lane >> 4;
    int row0 = blk0 + wave * 16;
    int grow = row0 + m;
    int ar = grow < N_NODES ? grow : N_NODES - 1;

    const float4* zr = (const float4*)(z + (size_t)ar * DIM);
    float4 a0 = zr[quad * 2],     a1 = zr[quad * 2 + 1];
    float4 a2 = zr[8 + quad * 2], a3 = zr[8 + quad * 2 + 1];
    short8 Ah0, Al0, Ah1, Al1;
    split8(a0, a1, &Ah0, &Al0);
    split8(a2, a3, &Ah1, &Al1);

    floatx4 acc[4];
#pragma unroll
    for (int nt = 0; nt < 4; nt++) acc[nt] = (floatx4){0.f, 0.f, 0.f, 0.f};
#pragma unroll
    for (int nt = 0; nt < 4; nt++) {
#pragma unroll
        for (int ks = 0; ks < 2; ks++) {
            const short8 Bh = *(const short8*)(wfL + (nt * 2 + ks) * 512 + lane * 8);
            const short8 Bl = *(const short8*)(wfL + 4096 + (nt * 2 + ks) * 512 + lane * 8);
            short8 Ahf = ks ? Ah1 : Ah0;
            short8 Alf = ks ? Al1 : Al0;
            acc[nt] = __builtin_amdgcn_mfma_f32_16x16x32_bf16(Ahf, Bh, acc[nt], 0, 0, 0);
            acc[nt] = __builtin_amdgcn_mfma_f32_16x16x32_bf16(Ahf, Bl, acc[nt], 0, 0, 0);
            acc[nt] = __builtin_amdgcn_mfma_f32_16x16x32_bf16(Alf, Bh, acc[nt], 0, 0, 0);
        }
    }

    float* Hs = sH[wave];
#pragma unroll
    for (int nt = 0; nt < 4; nt++) {
        int col = nt * 16 + m;
        float b = B1[col];
#pragma unroll
        for (int r = 0; r < 4; r++) {
            int lr = quad * 4 + r;
            Hs[lr * HS_STRIDE + col] = fmaxf(acc[nt][r] + b, 0.f);
        }
    }
    float4 h0 = *(const float4*)&Hs[m * HS_STRIDE + quad * 8];
    float4 h1 = *(const float4*)&Hs[m * HS_STRIDE + quad * 8 + 4];
    float4 h2 = *(const float4*)&Hs[m * HS_STRIDE + 32 + quad * 8];
    float4 h3 = *(const float4*)&Hs[m * HS_STRIDE + 32 + quad * 8 + 4];
    short8 Hh0, Hl0, Hh1, Hl1;
    split8(h0, h1, &Hh0, &Hl0);
    split8(h2, h3, &Hh1, &Hl1);

    floatx4 acc2[4];
#pragma unroll
    for (int nt = 0; nt < 4; nt++) acc2[nt] = (floatx4){0.f, 0.f, 0.f, 0.f};
    const unsigned short* wg2 = wfL + 8192;
#pragma unroll
    for (int nt = 0; nt < 4; nt++) {
#pragma unroll
        for (int ks = 0; ks < 2; ks++) {
            const short8 Bh = *(const short8*)(wg2 + (nt * 2 + ks) * 512 + lane * 8);
            const short8 Bl = *(const short8*)(wg2 + 4096 + (nt * 2 + ks) * 512 + lane * 8);
            short8 Ahf = ks ? Hh1 : Hh0;
            short8 Alf = ks ? Hl1 : Hl0;
            acc2[nt] = __builtin_amdgcn_mfma_f32_16x16x32_bf16(Ahf, Bh, acc2[nt], 0, 0, 0);
            acc2[nt] = __builtin_amdgcn_mfma_f32_16x16x32_bf16(Ahf, Bl, acc2[nt], 0, 0, 0);
            acc2[nt] = __builtin_amdgcn_mfma_f32_16x16x32_bf16(Alf, Bh, acc2[nt], 0, 0, 0);
        }
    }

    // ---- epilogue: bf16 z write + BN partials + per-graph raw pooling
    int widx = wave * 16;
    int gfirst = sBatch[widx], glast = sBatch[widx + 15];
    bool uni = (gfirst == glast) && (gfirst >= 0);
#pragma unroll
    for (int nt = 0; nt < 4; nt++) {
        int col = nt * 16 + m;
        float b = B2[col];
        float vv[4];
        float s = 0.f, s2 = 0.f;
#pragma unroll
        for (int r = 0; r < 4; r++) {
            int gr = row0 + quad * 4 + r;
            float v = fmaxf(acc2[nt][r] + b, 0.f);
            if (gr < N_NODES) {
                if (write_z) zb[(size_t)gr * DIM + col] = bf16_rn(v);
                s += v;
                s2 = fmaf(v, v, s2);
                vv[r] = v;
            } else {
                vv[r] = 0.f;
            }
        }
        float sf = s, s2f = s2;
        sf  += __shfl_xor(sf, 16);  sf  += __shfl_xor(sf, 32);
        s2f += __shfl_xor(s2f, 16); s2f += __shfl_xor(s2f, 32);
        if (quad == 0) {
            atomicAdd(&sSum[col], sf);
            atomicAdd(&sSum[DIM + col], s2f);
            if (uni) atomicAdd(&praw[(size_t)gfirst * DIM + col], sf);
        }
        if (!uni) {
            int cur = -1; float run = 0.f;
#pragma unroll
            for (int r = 0; r < 4; r++) {
                int g = sBatch[widx + quad * 4 + r];
                if (g != cur) {
                    if (cur >= 0 && run != 0.f)
                        atomicAdd(&praw[(size_t)cur * DIM + col], run);
                    run = 0.f; cur = g;
                }
                run += vv[r];
            }
            if (cur >= 0 && run != 0.f)
                atomicAdd(&praw[(size_t)cur * DIM + col], run);
        }
    }
    __syncthreads();
    if (tid < 2 * DIM)
        atomicAdd(&sums_part[(size_t)(blockIdx.x & (N_PART - 1)) * 2 * DIM + tid], sSum[tid]);
}

// --------------------------------------------- BN scale/shift from partials
__global__ void finalize_stats(const float* __restrict__ sp,
                               const float* __restrict__ gamma,
                               const float* __restrict__ beta,
                               float* __restrict__ ss) {
    int c = threadIdx.x;
    float s = 0.f, q = 0.f;
    for (int p = 0; p < N_PART; p++) {
        s += sp[p * 2 * DIM + c];
        q += sp[p * 2 * DIM + DIM + c];
    }
    const float inv_n = 1.0f / (float)N_NODES;
    float mu  = s * inv_n;
    float var = q * inv_n - mu * mu;
    float sc  = gamma[c] / sqrtf(var + BN_EPS);
    ss[c]       = sc;
    ss[DIM + c] = beta[c] - mu * sc;
}

// ------------------- pooled[g][L*64+c] = sc*praw + cnt_g*sh
__global__ __launch_bounds__(256) void assemble_pooled(const float* __restrict__ praw,
                                                       const float* __restrict__ ssAll,
                                                       const int* __restrict__ cntg,
                                                       float* __restrict__ pooled) {
    int idx = blockIdx.x * 256 + threadIdx.x;
    if (idx >= N_GRAPHS * D3) return;
    int g = idx / D3, j = idx - g * D3, L = j >> 6, c = j & 63;
    float sc = ssAll[L * 2 * DIM + c], sh = ssAll[L * 2 * DIM + DIM + c];
    pooled[idx] = fmaf(sc, praw[((size_t)L * N_GRAPHS + g) * DIM + c],
                       (float)cntg[g] * sh);
}

// ------------------------------------------------ final 2-layer MLP on pooled
__global__ __launch_bounds__(192) void final_mlp(const float* __restrict__ pooled,
    const float* __restrict__ PW1, const float* __restrict__ PB1,
    const float* __restrict__ PW2, const float* __restrict__ PB2,
    float* __restrict__ out) {
    __shared__ float row[D3];
    __shared__ float hid[D3];
    int g = blockIdx.x, j = threadIdx.x;
    row[j] = pooled[(size_t)g * D3 + j];
    __syncthreads();
    float acc = PB1[j];
    for (int k = 0; k < D3; k++) acc = fmaf(row[k], PW1[k * D3 + j], acc);
    hid[j] = fmaxf(acc, 0.f);
    __syncthreads();
    float acc2 = PB2[j];
    for (int k = 0; k < D3; k++) acc2 = fmaf(hid[k], PW2[k * D3 + j], acc2);
    out[(size_t)g * D3 + j] = acc2;
}

extern "C" void kernel_launch(void* const* d_in, const int* in_sizes, int n_in,
                              void* d_out, int out_size, void* d_ws, size_t ws_size,
                              hipStream_t stream) {
    const float* x     = (const float*)d_in[0];
    const int*   ei    = (const int*)d_in[1];
    const int*   batch = (const int*)d_in[2];
    const float* W1    = (const float*)d_in[3];
    const float* B1    = (const float*)d_in[4];
    const float* W2    = (const float*)d_in[5];
    const float* B2    = (const float*)d_in[6];
    const float* gamma = (const float*)d_in[7];
    const float* beta  = (const float*)d_in[8];
    const float* PW1   = (const float*)d_in[9];
    const float* PB1   = (const float*)d_in[10];
    const float* PW2   = (const float*)d_in[11];
    const float* PB2   = (const float*)d_in[12];
    float* out = (float*)d_out;

    // -------- workspace layout (~43 MB of 256 MB)
    float*    bufA  = (float*)d_ws;                              // 3,200,000 f (gather out)
    unsigned short* zb = (unsigned short*)(bufA + (size_t)N_NODES * DIM); // 3,200,000 u16
    unsigned short* xb = zb + (size_t)N_NODES * DIM;             // 3,200,000 u16
    unsigned* ebuf  = (unsigned*)(xb + (size_t)N_NODES * DIM);   // 782*2048 u32
    int*      csr   = (int*)(ebuf + (size_t)NBKT * ECAP);        // 800,000 i
    int*      rp    = csr + N_EDGES;                             // 50,056 i
    int*      bstart = rp + 50056;                               // 784 i
    int*      bcnt  = bstart + 784;                              // 784 i (written fully)
    int*      counts = bcnt + 784;                               // 153,272 i (written fully)
    int*      offs   = counts + NBKT * NPB;                      // 153,272 i (written fully)
    unsigned short* wfrag = (unsigned short*)(offs + NBKT * NPB); // 49,152 u16
    float*    ssbuf = (float*)(wfrag + 49152);                   // 384 f
    float*    pooled = ssbuf + N_LAYERS * 2 * DIM;               // 49,152 f
    // ---- zeroed region
    int*      cntg  = (int*)(pooled + N_GRAPHS * D3);            // 256 i
    float*    sums_part = (float*)(cntg + N_GRAPHS);             // 24,576 f
    float*    praw  = sums_part + N_LAYERS * N_PART * 2 * DIM;   // 49,152 f

    const int* src = ei;
    const int* dst = ei + N_EDGES;

    const size_t zero_bytes =
        (size_t)N_GRAPHS * sizeof(int) +
        (size_t)(N_LAYERS * N_PART * 2 * DIM + N_LAYERS * N_GRAPHS * DIM) * sizeof(float);
    hipMemsetAsync(cntg, 0, zero_bytes, stream);

    // -------- CSR build: deterministic two-pass partition (no global atomics)
    pass1_hist<<<NPB, 256, 0, stream>>>(dst, counts);
    bucket_scan<<<NBKT, 256, 0, stream>>>(counts, offs, bcnt);
    scan_small<<<1, 1024, 0, stream>>>(bcnt, bstart);
    pass2_scatter<<<NPB, 256, 0, stream>>>(src, dst, offs, ebuf);
    bucket_sort<<<NBKT, 256, 0, stream>>>(ebuf, bcnt, bstart, csr, rp);
    convert_x<<<(N_NODES * DIM / 4 + 255) / 256, 256, 0, stream>>>(x, xb);
    prep_weights<<<(N_LAYERS * 2 * 4096 + 255) / 256, 256, 0, stream>>>(W1, W2, wfrag);
    count_graphs<<<(N_NODES / 8 + 255) / 256, 256, 0, stream>>>(batch, cntg);

    // -------- layers: gather(+affine) -> mlp(bf16 z + stats + raw pool)
    const int GB = (N_NODES + 3) / 4;     // 12500
    const int MB = (N_NODES + 63) / 64;   // 782
    for (int L = 0; L < N_LAYERS; ++L) {
        int write_z = (L < N_LAYERS - 1);
        gather_bf16<<<GB, 256, 0, stream>>>(
            (L == 0) ? xb : zb, bufA, rp, csr,
            (L == 0) ? (const float*)nullptr : ssbuf + (size_t)(L - 1) * 2 * DIM);
        mlp_mfma<<<MB, 256, 0, stream>>>(
            bufA, zb,
            wfrag + (size_t)L * 2 * 8192, B1 + (size_t)L * DIM, B2 + (size_t)L * DIM,
            sums_part + (size_t)L * N_PART * 2 * DIM,
            praw + (size_t)L * N_GRAPHS * DIM, batch, write_z);
        finalize_stats<<<1, DIM, 0, stream>>>(sums_part + (size_t)L * N_PART * 2 * DIM,
                                              gamma + (size_t)L * DIM,
                                              beta + (size_t)L * DIM,
                                              ssbuf + (size_t)L * 2 * DIM);
    }

    assemble_pooled<<<(N_GRAPHS * D3 + 255) / 256, 256, 0, stream>>>(praw, ssbuf, cntg, pooled);
    final_mlp<<<N_GRAPHS, 192, 0, stream>>>(pooled, PW1, PB1, PW2, PB2, out);
}

// Round 13
// 268.669 us; speedup vs baseline: 1.7763x; 1.0273x over previous
//
#include <hip/hip_runtime.h>

#define N_NODES 50000
#define N_EDGES 800000
#define DIM 64
#define N_LAYERS 3
#define N_GRAPHS 256
#define BN_EPS 1e-5f
#define D3 (DIM * N_LAYERS)
#define N_PART 8
#define NBKT 782          // ceil(50000/64) destination buckets
#define NPB 196           // partition blocks (4096 edges each)
#define ECAP 2048         // fixed capacity per bucket (mean 1023, sigma ~32)

typedef __attribute__((ext_vector_type(8))) short short8;
typedef __attribute__((ext_vector_type(4))) float floatx4;

// ---------------------------------------------------------- bf16 split utils
__device__ inline unsigned short bf16_rn(float f) {
    unsigned u = __float_as_uint(f);
    u += 0x7FFF + ((u >> 16) & 1);
    return (unsigned short)(u >> 16);
}
__device__ inline float bf16_f(unsigned short b) {
    return __uint_as_float(((unsigned)b) << 16);
}
__device__ inline void split8(float4 a, float4 b, short8* hi, short8* lo) {
    float v[8] = {a.x, a.y, a.z, a.w, b.x, b.y, b.z, b.w};
#pragma unroll
    for (int i = 0; i < 8; i++) {
        unsigned short h = bf16_rn(v[i]);
        (*hi)[i] = (short)h;
        (*lo)[i] = (short)bf16_rn(v[i] - bf16_f(h));
    }
}

// --------------------------------------- x (f32) -> xb (bf16), elementwise
__global__ __launch_bounds__(256) void convert_x(const float* __restrict__ x,
                                                 unsigned short* __restrict__ xb) {
    int i = blockIdx.x * 256 + threadIdx.x;
    if (i >= N_NODES * DIM / 4) return;
    float4 v = ((const float4*)x)[i];
    ushort4 o;
    o.x = bf16_rn(v.x); o.y = bf16_rn(v.y);
    o.z = bf16_rn(v.z); o.w = bf16_rn(v.w);
    ((ushort4*)xb)[i] = o;
}

// -------- pass 1: per-block LDS hist over buckets -> counts[bucket][block]
__global__ __launch_bounds__(256) void pass1_hist(const int* __restrict__ dst,
                                                  int* __restrict__ counts) {
    __shared__ int hcnt[NBKT];
    for (int i = threadIdx.x; i < NBKT; i += 256) hcnt[i] = 0;
    __syncthreads();
    int base = blockIdx.x * 4096;
#pragma unroll
    for (int k = 0; k < 16; k++) {
        int e = base + k * 256 + threadIdx.x;
        if (e < N_EDGES) atomicAdd(&hcnt[dst[e] >> 6], 1);   // LDS atomic (native)
    }
    __syncthreads();
    for (int i = threadIdx.x; i < NBKT; i += 256)
        counts[i * NPB + blockIdx.x] = hcnt[i];
}

// -------- per-bucket exclusive scan over the 196 block counts -> offs, totals
__global__ __launch_bounds__(256) void bucket_scan(const int* __restrict__ counts,
                                                   int* __restrict__ offs,
                                                   int* __restrict__ bcnt) {
    __shared__ int s[256];
    int b = blockIdx.x, t = threadIdx.x;
    int v = (t < NPB) ? counts[b * NPB + t] : 0;
    s[t] = v;
    __syncthreads();
    for (int off = 1; off < 256; off <<= 1) {
        int u = (t >= off) ? s[t - off] : 0;
        __syncthreads();
        s[t] += u;
        __syncthreads();
    }
    if (t < NPB) offs[b * NPB + t] = s[t] - v;
    if (t == NPB - 1) bcnt[b] = s[t];
}

// -------- pass 2: deterministic scatter via LDS position counters
__global__ __launch_bounds__(256) void pass2_scatter(const int* __restrict__ src,
                                                     const int* __restrict__ dst,
                                                     const int* __restrict__ offs,
                                                     unsigned* __restrict__ ebuf) {
    __shared__ int loff[NBKT];
    int blk = blockIdx.x;
    for (int i = threadIdx.x; i < NBKT; i += 256)
        loff[i] = offs[i * NPB + blk];
    __syncthreads();
    int base = blk * 4096;
#pragma unroll
    for (int k = 0; k < 16; k++) {
        int e = base + k * 256 + threadIdx.x;
        if (e < N_EDGES) {
            int d = dst[e];
            int b = d >> 6;
            int pos = atomicAdd(&loff[b], 1);     // LDS int atomic (native)
            ebuf[(size_t)b * ECAP + pos] = ((unsigned)src[e] << 6) | (unsigned)(d & 63);
        }
    }
}

// --------- counting-sort each bucket's edges by dst&63 -> fixed-region CSR
// csr region for bucket b is [b*ECAP, b*ECAP+T_b); rp2 has 65-stride per bucket
__global__ __launch_bounds__(256) void bucket_sort(const unsigned* __restrict__ ebuf,
                                                   const int* __restrict__ bcnt,
                                                   int* __restrict__ csr,
                                                   int* __restrict__ rp2) {
    __shared__ unsigned ent[ECAP];
    __shared__ int cnt[64], basea[64], fill[64];
    int b = blockIdx.x, tid = threadIdx.x;
    int start = b * ECAP;
    int T = bcnt[b];
    const unsigned* eb = ebuf + (size_t)b * ECAP;
    if (tid < 64) cnt[tid] = 0;
    for (int i = tid; i < T; i += 256) ent[i] = eb[i];
    __syncthreads();
    for (int i = tid; i < T; i += 256) atomicAdd(&cnt[ent[i] & 63], 1);
    __syncthreads();
    if (tid < 64) {
        int v = cnt[tid], x = v;
#pragma unroll
        for (int off = 1; off < 64; off <<= 1) {
            int y = __shfl_up(x, off);
            if (tid >= off) x += y;
        }
        basea[tid] = x - v;
        fill[tid] = 0;
        rp2[b * 65 + tid] = start + x - v;
        if (tid == 63) rp2[b * 65 + 64] = start + x;   // inclusive total
    }
    __syncthreads();
    for (int i = tid; i < T; i += 256) {
        unsigned e = ent[i];
        int c = e & 63;
        int pos = basea[c] + atomicAdd(&fill[c], 1);
        csr[start + pos] = (int)(e >> 6);
    }
}

// ------------------- per-graph node counts via binary search (batch sorted)
__global__ void graph_bounds(const int* __restrict__ batch, int* __restrict__ cntg) {
    int g = threadIdx.x;   // 256
    int lo = 0, hi = N_NODES;
    while (lo < hi) { int mid = (lo + hi) >> 1; if (batch[mid] < g) lo = mid + 1; else hi = mid; }
    int start = lo;
    lo = 0; hi = N_NODES;
    while (lo < hi) { int mid = (lo + hi) >> 1; if (batch[mid] < g + 1) lo = mid + 1; else hi = mid; }
    cntg[g] = lo - start;
}

// -------- gather (bf16 rows) + prev-layer BN affine computed in-block
// 8 lanes per row; one wave-wide ushort8 load fetches 8 neighbor rows.
// z[i] = sc*(h[i]+sum h[j]) + (1+deg)*sh   (spPrev==null -> identity)
__global__ __launch_bounds__(256) void gather_bf16(const unsigned short* __restrict__ hb,
                                                   float* __restrict__ z,
                                                   const int* __restrict__ rp2,
                                                   const int* __restrict__ csr,
                                                   const float* __restrict__ spPrev,
                                                   const float* __restrict__ gammaL,
                                                   const float* __restrict__ betaL) {
    __shared__ float sRed[2 * DIM];
    __shared__ float sSS[2 * DIM];
    int tid = threadIdx.x;
    if (spPrev) {                       // fold finalize_stats into every block
        if (tid < 2 * DIM) {
            float s = 0.f;
#pragma unroll
            for (int p = 0; p < N_PART; p++) s += spPrev[p * 2 * DIM + tid];
            sRed[tid] = s;
        }
        __syncthreads();
        if (tid < DIM) {
            const float inv_n = 1.0f / (float)N_NODES;
            float mu  = sRed[tid] * inv_n;
            float var = sRed[DIM + tid] * inv_n - mu * mu;
            float sc  = gammaL[tid] / sqrtf(var + BN_EPS);
            sSS[tid]       = sc;
            sSS[DIM + tid] = betaL[tid] - mu * sc;
        }
        __syncthreads();
    }

    int node = blockIdx.x * 4 + (tid >> 6);     // 12500*4 == 50000: no remainder
    int lane = tid & 63;
    int c8 = lane & 7, sub = lane >> 3;
    int rbase = (node >> 6) * 65 + (node & 63);
    int e = rp2[rbase], end = rp2[rbase + 1];
    float degf = 1.f + (float)(end - e);
    float a[8];
#pragma unroll
    for (int i = 0; i < 8; i++) a[i] = 0.f;
    if (sub == 0) {
        short8 sv = *(const short8*)&hb[(size_t)node * DIM + c8 * 8];
#pragma unroll
        for (int i = 0; i < 8; i++) a[i] = bf16_f((unsigned short)sv[i]);
    }
    for (; e + 16 <= end; e += 16) {
        int i0 = csr[e + sub];
        int i1 = csr[e + 8 + sub];
        short8 r0 = *(const short8*)&hb[(size_t)i0 * DIM + c8 * 8];
        short8 r1 = *(const short8*)&hb[(size_t)i1 * DIM + c8 * 8];
#pragma unroll
        for (int i = 0; i < 8; i++)
            a[i] += bf16_f((unsigned short)r0[i]) + bf16_f((unsigned short)r1[i]);
    }
    for (; e + 8 <= end; e += 8) {
        int i0 = csr[e + sub];
        short8 r0 = *(const short8*)&hb[(size_t)i0 * DIM + c8 * 8];
#pragma unroll
        for (int i = 0; i < 8; i++) a[i] += bf16_f((unsigned short)r0[i]);
    }
    int rem = end - e;
    if (sub < rem) {
        short8 r0 = *(const short8*)&hb[(size_t)csr[e + sub] * DIM + c8 * 8];
#pragma unroll
        for (int i = 0; i < 8; i++) a[i] += bf16_f((unsigned short)r0[i]);
    }
#pragma unroll
    for (int i = 0; i < 8; i++) {
        a[i] += __shfl_xor(a[i], 8);
        a[i] += __shfl_xor(a[i], 16);
        a[i] += __shfl_xor(a[i], 32);
    }
    if (sub == 0) {
        int ch = c8 * 8;
        float4 o1, o2;
        if (spPrev) {
            o1.x = fmaf(a[0], sSS[ch + 0], degf * sSS[DIM + ch + 0]);
            o1.y = fmaf(a[1], sSS[ch + 1], degf * sSS[DIM + ch + 1]);
            o1.z = fmaf(a[2], sSS[ch + 2], degf * sSS[DIM + ch + 2]);
            o1.w = fmaf(a[3], sSS[ch + 3], degf * sSS[DIM + ch + 3]);
            o2.x = fmaf(a[4], sSS[ch + 4], degf * sSS[DIM + ch + 4]);
            o2.y = fmaf(a[5], sSS[ch + 5], degf * sSS[DIM + ch + 5]);
            o2.z = fmaf(a[6], sSS[ch + 6], degf * sSS[DIM + ch + 6]);
            o2.w = fmaf(a[7], sSS[ch + 7], degf * sSS[DIM + ch + 7]);
        } else {
            o1.x = a[0]; o1.y = a[1]; o1.z = a[2]; o1.w = a[3];
            o2.x = a[4]; o2.y = a[5]; o2.z = a[6]; o2.w = a[7];
        }
        *(float4*)&z[(size_t)node * DIM + ch] = o1;
        *(float4*)&z[(size_t)node * DIM + ch + 4] = o2;
    }
}

// --------------- pack W1/W2 into MFMA B-operand fragments, split bf16 hi/lo
__global__ __launch_bounds__(256) void prep_weights(const float* __restrict__ W1,
                                                    const float* __restrict__ W2,
                                                    unsigned short* __restrict__ wf) {
    int idx = blockIdx.x * 256 + threadIdx.x;
    if (idx >= N_LAYERS * 2 * 4096) return;
    int j    = idx & 7;
    int lane = (idx >> 3) & 63;
    int ks   = (idx >> 9) & 1;
    int nt   = (idx >> 10) & 3;
    int gemm = (idx >> 12) & 1;
    int layer = idx >> 13;
    int n = nt * 16 + (lane & 15);
    int k = ks * 32 + (lane >> 4) * 8 + j;
    const float* W = (gemm ? W2 : W1) + (size_t)layer * DIM * DIM;
    float w = W[k * DIM + n];
    unsigned short hi = bf16_rn(w);
    unsigned short lo = bf16_rn(w - bf16_f(hi));
    size_t base = ((size_t)layer * 2 + gemm) * 8192;
    int f = nt * 2 + ks;
    wf[base + f * 512 + lane * 8 + j]        = hi;
    wf[base + 4096 + f * 512 + lane * 8 + j] = lo;
}

// ------- MFMA MLP: bf16 z' = relu(relu(zW1+B1)W2+B2) + BN partials + raw pool
#define HS_STRIDE 68
__global__ __launch_bounds__(256) void mlp_mfma(const float* __restrict__ z,
    unsigned short* __restrict__ zb,
    const unsigned short* __restrict__ wfL,
    const float* __restrict__ B1, const float* __restrict__ B2,
    float* __restrict__ sums_part, float* __restrict__ praw,
    const int* __restrict__ batch, int write_z) {
    __shared__ float sH[4][16 * HS_STRIDE];
    __shared__ float sSum[2 * DIM];
    __shared__ int   sBatch[64];

    int tid = threadIdx.x, wave = tid >> 6, lane = tid & 63;
    int blk0 = blockIdx.x * 64;
    if (tid < 2 * DIM) sSum[tid] = 0.f;
    if (tid < 64) sBatch[tid] = (blk0 + tid < N_NODES) ? batch[blk0 + tid] : -1;
    __syncthreads();

    int m = lane & 15, quad = lane >> 4;
    int row0 = blk0 + wave * 16;
    int grow = row0 + m;
    int ar = grow < N_NODES ? grow : N_NODES - 1;

    const float4* zr = (const float4*)(z + (size_t)ar * DIM);
    float4 a0 = zr[quad * 2],     a1 = zr[quad * 2 + 1];
    float4 a2 = zr[8 + quad * 2], a3 = zr[8 + quad * 2 + 1];
    short8 Ah0, Al0, Ah1, Al1;
    split8(a0, a1, &Ah0, &Al0);
    split8(a2, a3, &Ah1, &Al1);

    floatx4 acc[4];
#pragma unroll
    for (int nt = 0; nt < 4; nt++) acc[nt] = (floatx4){0.f, 0.f, 0.f, 0.f};
#pragma unroll
    for (int nt = 0; nt < 4; nt++) {
#pragma unroll
        for (int ks = 0; ks < 2; ks++) {
            const short8 Bh = *(const short8*)(wfL + (nt * 2 + ks) * 512 + lane * 8);
            const short8 Bl = *(const short8*)(wfL + 4096 + (nt * 2 + ks) * 512 + lane * 8);
            short8 Ahf = ks ? Ah1 : Ah0;
            short8 Alf = ks ? Al1 : Al0;
            acc[nt] = __builtin_amdgcn_mfma_f32_16x16x32_bf16(Ahf, Bh, acc[nt], 0, 0, 0);
            acc[nt] = __builtin_amdgcn_mfma_f32_16x16x32_bf16(Ahf, Bl, acc[nt], 0, 0, 0);
            acc[nt] = __builtin_amdgcn_mfma_f32_16x16x32_bf16(Alf, Bh, acc[nt], 0, 0, 0);
        }
    }

    float* Hs = sH[wave];
#pragma unroll
    for (int nt = 0; nt < 4; nt++) {
        int col = nt * 16 + m;
        float b = B1[col];
#pragma unroll
        for (int r = 0; r < 4; r++) {
            int lr = quad * 4 + r;
            Hs[lr * HS_STRIDE + col] = fmaxf(acc[nt][r] + b, 0.f);
        }
    }
    float4 h0 = *(const float4*)&Hs[m * HS_STRIDE + quad * 8];
    float4 h1 = *(const float4*)&Hs[m * HS_STRIDE + quad * 8 + 4];
    float4 h2 = *(const float4*)&Hs[m * HS_STRIDE + 32 + quad * 8];
    float4 h3 = *(const float4*)&Hs[m * HS_STRIDE + 32 + quad * 8 + 4];
    short8 Hh0, Hl0, Hh1, Hl1;
    split8(h0, h1, &Hh0, &Hl0);
    split8(h2, h3, &Hh1, &Hl1);

    floatx4 acc2[4];
#pragma unroll
    for (int nt = 0; nt < 4; nt++) acc2[nt] = (floatx4){0.f, 0.f, 0.f, 0.f};
    const unsigned short* wg2 = wfL + 8192;
#pragma unroll
    for (int nt = 0; nt < 4; nt++) {
#pragma unroll
        for (int ks = 0; ks < 2; ks++) {
            const short8 Bh = *(const short8*)(wg2 + (nt * 2 + ks) * 512 + lane * 8);
            const short8 Bl = *(const short8*)(wg2 + 4096 + (nt * 2 + ks) * 512 + lane * 8);
            short8 Ahf = ks ? Hh1 : Hh0;
            short8 Alf = ks ? Hl1 : Hl0;
            acc2[nt] = __builtin_amdgcn_mfma_f32_16x16x32_bf16(Ahf, Bh, acc2[nt], 0, 0, 0);
            acc2[nt] = __builtin_amdgcn_mfma_f32_16x16x32_bf16(Ahf, Bl, acc2[nt], 0, 0, 0);
            acc2[nt] = __builtin_amdgcn_mfma_f32_16x16x32_bf16(Alf, Bh, acc2[nt], 0, 0, 0);
        }
    }

    // ---- epilogue: bf16 z write + BN partials + per-graph raw pooling
    int widx = wave * 16;
    int gfirst = sBatch[widx], glast = sBatch[widx + 15];
    bool uni = (gfirst == glast) && (gfirst >= 0);
#pragma unroll
    for (int nt = 0; nt < 4; nt++) {
        int col = nt * 16 + m;
        float b = B2[col];
        float vv[4];
        float s = 0.f, s2 = 0.f;
#pragma unroll
        for (int r = 0; r < 4; r++) {
            int gr = row0 + quad * 4 + r;
            float v = fmaxf(acc2[nt][r] + b, 0.f);
            if (gr < N_NODES) {
                if (write_z) zb[(size_t)gr * DIM + col] = bf16_rn(v);
                s += v;
                s2 = fmaf(v, v, s2);
                vv[r] = v;
            } else {
                vv[r] = 0.f;
            }
        }
        float sf = s, s2f = s2;
        sf  += __shfl_xor(sf, 16);  sf  += __shfl_xor(sf, 32);
        s2f += __shfl_xor(s2f, 16); s2f += __shfl_xor(s2f, 32);
        if (quad == 0) {
            atomicAdd(&sSum[col], sf);
            atomicAdd(&sSum[DIM + col], s2f);
            if (uni) atomicAdd(&praw[(size_t)gfirst * DIM + col], sf);
        }
        if (!uni) {
            int cur = -1; float run = 0.f;
#pragma unroll
            for (int r = 0; r < 4; r++) {
                int g = sBatch[widx + quad * 4 + r];
                if (g != cur) {
                    if (cur >= 0 && run != 0.f)
                        atomicAdd(&praw[(size_t)cur * DIM + col], run);
                    run = 0.f; cur = g;
                }
                run += vv[r];
            }
            if (cur >= 0 && run != 0.f)
                atomicAdd(&praw[(size_t)cur * DIM + col], run);
        }
    }
    __syncthreads();
    if (tid < 2 * DIM)
        atomicAdd(&sums_part[(size_t)(blockIdx.x & (N_PART - 1)) * 2 * DIM + tid], sSum[tid]);
}

// ------------------- pooled[g][L*64+c] = sc*praw + cnt_g*sh (stats inline)
__global__ __launch_bounds__(256) void assemble_pooled(const float* __restrict__ sums_part,
                                                       const float* __restrict__ praw,
                                                       const float* __restrict__ gamma,
                                                       const float* __restrict__ beta,
                                                       const int* __restrict__ cntg,
                                                       float* __restrict__ pooled) {
    int idx = blockIdx.x * 256 + threadIdx.x;
    if (idx >= N_GRAPHS * D3) return;
    int g = idx / D3, j = idx - g * D3, L = j >> 6, c = j & 63;
    const float* sp = sums_part + (size_t)L * N_PART * 2 * DIM;
    float s = 0.f, q = 0.f;
#pragma unroll
    for (int p = 0; p < N_PART; p++) {
        s += sp[p * 2 * DIM + c];
        q += sp[p * 2 * DIM + DIM + c];
    }
    const float inv_n = 1.0f / (float)N_NODES;
    float mu  = s * inv_n;
    float var = q * inv_n - mu * mu;
    float sc  = gamma[L * DIM + c] / sqrtf(var + BN_EPS);
    float sh  = beta[L * DIM + c] - mu * sc;
    pooled[idx] = fmaf(sc, praw[((size_t)L * N_GRAPHS + g) * DIM + c],
                       (float)cntg[g] * sh);
}

// ------------------------------------------------ final 2-layer MLP on pooled
__global__ __launch_bounds__(192) void final_mlp(const float* __restrict__ pooled,
    const float* __restrict__ PW1, const float* __restrict__ PB1,
    const float* __restrict__ PW2, const float* __restrict__ PB2,
    float* __restrict__ out) {
    __shared__ float row[D3];
    __shared__ float hid[D3];
    int g = blockIdx.x, j = threadIdx.x;
    row[j] = pooled[(size_t)g * D3 + j];
    __syncthreads();
    float acc = PB1[j];
    for (int k = 0; k < D3; k++) acc = fmaf(row[k], PW1[k * D3 + j], acc);
    hid[j] = fmaxf(acc, 0.f);
    __syncthreads();
    float acc2 = PB2[j];
    for (int k = 0; k < D3; k++) acc2 = fmaf(hid[k], PW2[k * D3 + j], acc2);
    out[(size_t)g * D3 + j] = acc2;
}

extern "C" void kernel_launch(void* const* d_in, const int* in_sizes, int n_in,
                              void* d_out, int out_size, void* d_ws, size_t ws_size,
                              hipStream_t stream) {
    const float* x     = (const float*)d_in[0];
    const int*   ei    = (const int*)d_in[1];
    const int*   batch = (const int*)d_in[2];
    const float* W1    = (const float*)d_in[3];
    const float* B1    = (const float*)d_in[4];
    const float* W2    = (const float*)d_in[5];
    const float* B2    = (const float*)d_in[6];
    const float* gamma = (const float*)d_in[7];
    const float* beta  = (const float*)d_in[8];
    const float* PW1   = (const float*)d_in[9];
    const float* PB1   = (const float*)d_in[10];
    const float* PW2   = (const float*)d_in[11];
    const float* PB2   = (const float*)d_in[12];
    float* out = (float*)d_out;

    // -------- workspace layout (~50 MB of 256 MB)
    float*    bufA  = (float*)d_ws;                              // 3,200,000 f (gather out)
    unsigned short* zb = (unsigned short*)(bufA + (size_t)N_NODES * DIM); // 3,200,000 u16
    unsigned short* xb = zb + (size_t)N_NODES * DIM;             // 3,200,000 u16
    unsigned* ebuf  = (unsigned*)(xb + (size_t)N_NODES * DIM);   // 782*2048 u32
    int*      csr   = (int*)(ebuf + (size_t)NBKT * ECAP);        // 782*2048 i (fixed regions)
    int*      rp2   = csr + NBKT * ECAP;                         // 782*65 = 50,830 -> 50,832
    int*      bcnt  = rp2 + 50832;                               // 784 i (written fully)
    int*      counts = bcnt + 784;                               // 153,272 i (written fully)
    int*      offs   = counts + NBKT * NPB;                      // 153,272 i (written fully)
    unsigned short* wfrag = (unsigned short*)(offs + NBKT * NPB); // 49,152 u16
    float*    pooled = (float*)(wfrag + 49152);                  // 49,152 f
    int*      cntg  = (int*)(pooled + N_GRAPHS * D3);            // 256 i (written fully)
    // ---- zeroed region
    float*    sums_part = (float*)(cntg + N_GRAPHS);             // 3*8*128 = 3,072 f
    float*    praw  = sums_part + N_LAYERS * N_PART * 2 * DIM;   // 49,152 f

    const int* src = ei;
    const int* dst = ei + N_EDGES;

    const size_t zero_bytes =
        (size_t)(N_LAYERS * N_PART * 2 * DIM + N_LAYERS * N_GRAPHS * DIM) * sizeof(float);
    hipMemsetAsync(sums_part, 0, zero_bytes, stream);

    // -------- CSR build: deterministic two-pass partition (no global atomics)
    pass1_hist<<<NPB, 256, 0, stream>>>(dst, counts);
    bucket_scan<<<NBKT, 256, 0, stream>>>(counts, offs, bcnt);
    pass2_scatter<<<NPB, 256, 0, stream>>>(src, dst, offs, ebuf);
    bucket_sort<<<NBKT, 256, 0, stream>>>(ebuf, bcnt, csr, rp2);
    convert_x<<<(N_NODES * DIM / 4 + 255) / 256, 256, 0, stream>>>(x, xb);
    prep_weights<<<(N_LAYERS * 2 * 4096 + 255) / 256, 256, 0, stream>>>(W1, W2, wfrag);
    graph_bounds<<<1, 256, 0, stream>>>(batch, cntg);

    // -------- layers: gather(+in-block BN stats) -> mlp(bf16 z + stats + pool)
    const int GB = (N_NODES + 3) / 4;     // 12500
    const int MB = (N_NODES + 63) / 64;   // 782
    for (int L = 0; L < N_LAYERS; ++L) {
        int write_z = (L < N_LAYERS - 1);
        gather_bf16<<<GB, 256, 0, stream>>>(
            (L == 0) ? xb : zb, bufA, rp2, csr,
            (L == 0) ? (const float*)nullptr : sums_part + (size_t)(L - 1) * N_PART * 2 * DIM,
            gamma + (size_t)(L ? L - 1 : 0) * DIM,
            beta + (size_t)(L ? L - 1 : 0) * DIM);
        mlp_mfma<<<MB, 256, 0, stream>>>(
            bufA, zb,
            wfrag + (size_t)L * 2 * 8192, B1 + (size_t)L * DIM, B2 + (size_t)L * DIM,
            sums_part + (size_t)L * N_PART * 2 * DIM,
            praw + (size_t)L * N_GRAPHS * DIM, batch, write_z);
    }

    assemble_pooled<<<(N_GRAPHS * D3 + 255) / 256, 256, 0, stream>>>(
        sums_part, praw, gamma, beta, cntg, pooled);
    final_mlp<<<N_GRAPHS, 192, 0, stream>>>(pooled, PW1, PB1, PW2, PB2, out);
}

// Round 14
// 258.813 us; speedup vs baseline: 1.8440x; 1.0381x over previous
//
#include <hip/hip_runtime.h>

#define N_NODES 50000
#define N_EDGES 800000
#define DIM 64
#define N_LAYERS 3
#define N_GRAPHS 256
#define BN_EPS 1e-5f
#define D3 (DIM * N_LAYERS)
#define N_PART 8
#define NBKT 782          // ceil(50000/64) destination buckets
#define NPB 196           // partition blocks (4096 edges each)
#define ECAP 2048         // fixed capacity per bucket (mean 1023, sigma ~32)
#define CVT_BLOCKS 3125   // convert_x blocks (800,000 float4 / 256)
#define PREP_BLOCKS 96    // prep_weights blocks (24,576 / 256)

typedef __attribute__((ext_vector_type(8))) short short8;
typedef __attribute__((ext_vector_type(4))) float floatx4;

// ---------------------------------------------------------- bf16 split utils
__device__ inline unsigned short bf16_rn(float f) {
    unsigned u = __float_as_uint(f);
    u += 0x7FFF + ((u >> 16) & 1);
    return (unsigned short)(u >> 16);
}
__device__ inline float bf16_f(unsigned short b) {
    return __uint_as_float(((unsigned)b) << 16);
}
__device__ inline void split8(float4 a, float4 b, short8* hi, short8* lo) {
    float v[8] = {a.x, a.y, a.z, a.w, b.x, b.y, b.z, b.w};
#pragma unroll
    for (int i = 0; i < 8; i++) {
        unsigned short h = bf16_rn(v[i]);
        (*hi)[i] = (short)h;
        (*lo)[i] = (short)bf16_rn(v[i] - bf16_f(h));
    }
}

// -------- pass 1: per-block LDS hist over buckets -> counts[bucket][block]
__global__ __launch_bounds__(256) void pass1_hist(const int* __restrict__ dst,
                                                  int* __restrict__ counts) {
    __shared__ int hcnt[NBKT];
    for (int i = threadIdx.x; i < NBKT; i += 256) hcnt[i] = 0;
    __syncthreads();
    int base = blockIdx.x * 4096;
#pragma unroll
    for (int k = 0; k < 16; k++) {
        int e = base + k * 256 + threadIdx.x;
        if (e < N_EDGES) atomicAdd(&hcnt[dst[e] >> 6], 1);   // LDS atomic (native)
    }
    __syncthreads();
    for (int i = threadIdx.x; i < NBKT; i += 256)
        counts[i * NPB + blockIdx.x] = hcnt[i];
}

// -------- per-bucket exclusive scan over the 196 block counts -> offs, totals
__global__ __launch_bounds__(256) void bucket_scan(const int* __restrict__ counts,
                                                   int* __restrict__ offs,
                                                   int* __restrict__ bcnt) {
    __shared__ int s[256];
    int b = blockIdx.x, t = threadIdx.x;
    int v = (t < NPB) ? counts[b * NPB + t] : 0;
    s[t] = v;
    __syncthreads();
    for (int off = 1; off < 256; off <<= 1) {
        int u = (t >= off) ? s[t - off] : 0;
        __syncthreads();
        s[t] += u;
        __syncthreads();
    }
    if (t < NPB) offs[b * NPB + t] = s[t] - v;
    if (t == NPB - 1) bcnt[b] = s[t];
}

// -------- pass 2: deterministic scatter via LDS position counters
__global__ __launch_bounds__(256) void pass2_scatter(const int* __restrict__ src,
                                                     const int* __restrict__ dst,
                                                     const int* __restrict__ offs,
                                                     unsigned* __restrict__ ebuf) {
    __shared__ int loff[NBKT];
    int blk = blockIdx.x;
    for (int i = threadIdx.x; i < NBKT; i += 256)
        loff[i] = offs[i * NPB + blk];
    __syncthreads();
    int base = blk * 4096;
#pragma unroll
    for (int k = 0; k < 16; k++) {
        int e = base + k * 256 + threadIdx.x;
        if (e < N_EDGES) {
            int d = dst[e];
            int b = d >> 6;
            int pos = atomicAdd(&loff[b], 1);     // LDS int atomic (native)
            ebuf[(size_t)b * ECAP + pos] = ((unsigned)src[e] << 6) | (unsigned)(d & 63);
        }
    }
}

// ===== fused: bucket counting-sort (blocks [0,NBKT)) + setup work
//       blocks [NBKT, NBKT+CVT_BLOCKS)          : x f32 -> bf16
//       blocks [.., +PREP_BLOCKS)               : weight fragment pack
//       last block                               : per-graph counts (bin search)
__global__ __launch_bounds__(256) void sort_and_setup(
    const unsigned* __restrict__ ebuf, const int* __restrict__ bcnt,
    int* __restrict__ csr, int* __restrict__ rp2,
    const float* __restrict__ x, unsigned short* __restrict__ xb,
    const float* __restrict__ W1, const float* __restrict__ W2,
    unsigned short* __restrict__ wf,
    const int* __restrict__ batch, int* __restrict__ cntg) {
    int blk = blockIdx.x, tid = threadIdx.x;

    if (blk < NBKT) {                     // ---- bucket counting sort
        __shared__ unsigned ent[ECAP];
        __shared__ int cnt[64], basea[64], fill[64];
        int b = blk;
        int start = b * ECAP;
        int T = bcnt[b];
        const unsigned* eb = ebuf + (size_t)b * ECAP;
        if (tid < 64) cnt[tid] = 0;
        for (int i = tid; i < T; i += 256) ent[i] = eb[i];
        __syncthreads();
        for (int i = tid; i < T; i += 256) atomicAdd(&cnt[ent[i] & 63], 1);
        __syncthreads();
        if (tid < 64) {
            int v = cnt[tid], xp = v;
#pragma unroll
            for (int off = 1; off < 64; off <<= 1) {
                int y = __shfl_up(xp, off);
                if (tid >= off) xp += y;
            }
            basea[tid] = xp - v;
            fill[tid] = 0;
            rp2[b * 65 + tid] = start + xp - v;
            if (tid == 63) rp2[b * 65 + 64] = start + xp;
        }
        __syncthreads();
        for (int i = tid; i < T; i += 256) {
            unsigned e = ent[i];
            int c = e & 63;
            int pos = basea[c] + atomicAdd(&fill[c], 1);
            csr[start + pos] = (int)(e >> 6);
        }
        return;
    }
    int sb = blk - NBKT;
    if (sb < CVT_BLOCKS) {                // ---- convert x to bf16
        int i = sb * 256 + tid;
        float4 v = ((const float4*)x)[i];
        ushort4 o;
        o.x = bf16_rn(v.x); o.y = bf16_rn(v.y);
        o.z = bf16_rn(v.z); o.w = bf16_rn(v.w);
        ((ushort4*)xb)[i] = o;
        return;
    }
    sb -= CVT_BLOCKS;
    if (sb < PREP_BLOCKS) {               // ---- pack weight fragments
        int idx = sb * 256 + tid;
        int j    = idx & 7;
        int lane = (idx >> 3) & 63;
        int ks   = (idx >> 9) & 1;
        int nt   = (idx >> 10) & 3;
        int gemm = (idx >> 12) & 1;
        int layer = idx >> 13;
        int n = nt * 16 + (lane & 15);
        int k = ks * 32 + (lane >> 4) * 8 + j;
        const float* W = (gemm ? W2 : W1) + (size_t)layer * DIM * DIM;
        float w = W[k * DIM + n];
        unsigned short hi = bf16_rn(w);
        unsigned short lo = bf16_rn(w - bf16_f(hi));
        size_t base = ((size_t)layer * 2 + gemm) * 8192;
        int f = nt * 2 + ks;
        wf[base + f * 512 + lane * 8 + j]        = hi;
        wf[base + 4096 + f * 512 + lane * 8 + j] = lo;
        return;
    }
    // ---- per-graph node counts via binary search (batch sorted)
    int g = tid;
    int lo = 0, hi = N_NODES;
    while (lo < hi) { int mid = (lo + hi) >> 1; if (batch[mid] < g) lo = mid + 1; else hi = mid; }
    int start = lo;
    lo = 0; hi = N_NODES;
    while (lo < hi) { int mid = (lo + hi) >> 1; if (batch[mid] < g + 1) lo = mid + 1; else hi = mid; }
    cntg[g] = lo - start;
}

// -------- gather (bf16 rows) + prev-layer BN affine computed in-block
// 8 lanes per row; one wave-wide ushort8 load fetches 8 neighbor rows.
__global__ __launch_bounds__(256) void gather_bf16(const unsigned short* __restrict__ hb,
                                                   float* __restrict__ z,
                                                   const int* __restrict__ rp2,
                                                   const int* __restrict__ csr,
                                                   const float* __restrict__ spPrev,
                                                   const float* __restrict__ gammaL,
                                                   const float* __restrict__ betaL) {
    __shared__ float sRed[2 * DIM];
    __shared__ float sSS[2 * DIM];
    int tid = threadIdx.x;
    if (spPrev) {                       // finalize_stats folded into every block
        if (tid < 2 * DIM) {
            float s = 0.f;
#pragma unroll
            for (int p = 0; p < N_PART; p++) s += spPrev[p * 2 * DIM + tid];
            sRed[tid] = s;
        }
        __syncthreads();
        if (tid < DIM) {
            const float inv_n = 1.0f / (float)N_NODES;
            float mu  = sRed[tid] * inv_n;
            float var = sRed[DIM + tid] * inv_n - mu * mu;
            float sc  = gammaL[tid] / sqrtf(var + BN_EPS);
            sSS[tid]       = sc;
            sSS[DIM + tid] = betaL[tid] - mu * sc;
        }
        __syncthreads();
    }

    int node = blockIdx.x * 4 + (tid >> 6);     // 12500*4 == 50000: exact
    int lane = tid & 63;
    int c8 = lane & 7, sub = lane >> 3;
    int rbase = (node >> 6) * 65 + (node & 63);
    int e = rp2[rbase], end = rp2[rbase + 1];
    float degf = 1.f + (float)(end - e);
    float a[8];
#pragma unroll
    for (int i = 0; i < 8; i++) a[i] = 0.f;
    if (sub == 0) {
        short8 sv = *(const short8*)&hb[(size_t)node * DIM + c8 * 8];
#pragma unroll
        for (int i = 0; i < 8; i++) a[i] = bf16_f((unsigned short)sv[i]);
    }
    for (; e + 16 <= end; e += 16) {
        int i0 = csr[e + sub];
        int i1 = csr[e + 8 + sub];
        short8 r0 = *(const short8*)&hb[(size_t)i0 * DIM + c8 * 8];
        short8 r1 = *(const short8*)&hb[(size_t)i1 * DIM + c8 * 8];
#pragma unroll
        for (int i = 0; i < 8; i++)
            a[i] += bf16_f((unsigned short)r0[i]) + bf16_f((unsigned short)r1[i]);
    }
    for (; e + 8 <= end; e += 8) {
        int i0 = csr[e + sub];
        short8 r0 = *(const short8*)&hb[(size_t)i0 * DIM + c8 * 8];
#pragma unroll
        for (int i = 0; i < 8; i++) a[i] += bf16_f((unsigned short)r0[i]);
    }
    int rem = end - e;
    if (sub < rem) {
        short8 r0 = *(const short8*)&hb[(size_t)csr[e + sub] * DIM + c8 * 8];
#pragma unroll
        for (int i = 0; i < 8; i++) a[i] += bf16_f((unsigned short)r0[i]);
    }
#pragma unroll
    for (int i = 0; i < 8; i++) {
        a[i] += __shfl_xor(a[i], 8);
        a[i] += __shfl_xor(a[i], 16);
        a[i] += __shfl_xor(a[i], 32);
    }
    if (sub == 0) {
        int ch = c8 * 8;
        float4 o1, o2;
        if (spPrev) {
            o1.x = fmaf(a[0], sSS[ch + 0], degf * sSS[DIM + ch + 0]);
            o1.y = fmaf(a[1], sSS[ch + 1], degf * sSS[DIM + ch + 1]);
            o1.z = fmaf(a[2], sSS[ch + 2], degf * sSS[DIM + ch + 2]);
            o1.w = fmaf(a[3], sSS[ch + 3], degf * sSS[DIM + ch + 3]);
            o2.x = fmaf(a[4], sSS[ch + 4], degf * sSS[DIM + ch + 4]);
            o2.y = fmaf(a[5], sSS[ch + 5], degf * sSS[DIM + ch + 5]);
            o2.z = fmaf(a[6], sSS[ch + 6], degf * sSS[DIM + ch + 6]);
            o2.w = fmaf(a[7], sSS[ch + 7], degf * sSS[DIM + ch + 7]);
        } else {
            o1.x = a[0]; o1.y = a[1]; o1.z = a[2]; o1.w = a[3];
            o2.x = a[4]; o2.y = a[5]; o2.z = a[6]; o2.w = a[7];
        }
        *(float4*)&z[(size_t)node * DIM + ch] = o1;
        *(float4*)&z[(size_t)node * DIM + ch + 4] = o2;
    }
}

// ------- MFMA MLP: bf16 z' = relu(relu(zW1+B1)W2+B2) + BN partials + raw pool
#define HS_STRIDE 68
__global__ __launch_bounds__(256) void mlp_mfma(const float* __restrict__ z,
    unsigned short* __restrict__ zb,
    const unsigned short* __restrict__ wfL,
    const float* __restrict__ B1, const float* __restrict__ B2,
    float* __restrict__ sums_part, float* __restrict__ praw,
    const int* __restrict__ batch, int write_z) {
    __shared__ float sH[4][16 * HS_STRIDE];
    __shared__ float sSum[2 * DIM];
    __shared__ int   sBatch[64];

    int tid = threadIdx.x, wave = tid >> 6, lane = tid & 63;
    int blk0 = blockIdx.x * 64;
    if (tid < 2 * DIM) sSum[tid] = 0.f;
    if (tid < 64) sBatch[tid] = (blk0 + tid < N_NODES) ? batch[blk0 + tid] : -1;
    __syncthreads();

    int m = lane & 15, quad = lane >> 4;
    int row0 = blk0 + wave * 16;
    int grow = row0 + m;
    int ar = grow < N_NODES ? grow : N_NODES - 1;

    const float4* zr = (const float4*)(z + (size_t)ar * DIM);
    float4 a0 = zr[quad * 2],     a1 = zr[quad * 2 + 1];
    float4 a2 = zr[8 + quad * 2], a3 = zr[8 + quad * 2 + 1];
    short8 Ah0, Al0, Ah1, Al1;
    split8(a0, a1, &Ah0, &Al0);
    split8(a2, a3, &Ah1, &Al1);

    floatx4 acc[4];
#pragma unroll
    for (int nt = 0; nt < 4; nt++) acc[nt] = (floatx4){0.f, 0.f, 0.f, 0.f};
#pragma unroll
    for (int nt = 0; nt < 4; nt++) {
#pragma unroll
        for (int ks = 0; ks < 2; ks++) {
            const short8 Bh = *(const short8*)(wfL + (nt * 2 + ks) * 512 + lane * 8);
            const short8 Bl = *(const short8*)(wfL + 4096 + (nt * 2 + ks) * 512 + lane * 8);
            short8 Ahf = ks ? Ah1 : Ah0;
            short8 Alf = ks ? Al1 : Al0;
            acc[nt] = __builtin_amdgcn_mfma_f32_16x16x32_bf16(Ahf, Bh, acc[nt], 0, 0, 0);
            acc[nt] = __builtin_amdgcn_mfma_f32_16x16x32_bf16(Ahf, Bl, acc[nt], 0, 0, 0);
            acc[nt] = __builtin_amdgcn_mfma_f32_16x16x32_bf16(Alf, Bh, acc[nt], 0, 0, 0);
        }
    }

    float* Hs = sH[wave];
#pragma unroll
    for (int nt = 0; nt < 4; nt++) {
        int col = nt * 16 + m;
        float b = B1[col];
#pragma unroll
        for (int r = 0; r < 4; r++) {
            int lr = quad * 4 + r;
            Hs[lr * HS_STRIDE + col] = fmaxf(acc[nt][r] + b, 0.f);
        }
    }
    float4 h0 = *(const float4*)&Hs[m * HS_STRIDE + quad * 8];
    float4 h1 = *(const float4*)&Hs[m * HS_STRIDE + quad * 8 + 4];
    float4 h2 = *(const float4*)&Hs[m * HS_STRIDE + 32 + quad * 8];
    float4 h3 = *(const float4*)&Hs[m * HS_STRIDE + 32 + quad * 8 + 4];
    short8 Hh0, Hl0, Hh1, Hl1;
    split8(h0, h1, &Hh0, &Hl0);
    split8(h2, h3, &Hh1, &Hl1);

    floatx4 acc2[4];
#pragma unroll
    for (int nt = 0; nt < 4; nt++) acc2[nt] = (floatx4){0.f, 0.f, 0.f, 0.f};
    const unsigned short* wg2 = wfL + 8192;
#pragma unroll
    for (int nt = 0; nt < 4; nt++) {
#pragma unroll
        for (int ks = 0; ks < 2; ks++) {
            const short8 Bh = *(const short8*)(wg2 + (nt * 2 + ks) * 512 + lane * 8);
            const short8 Bl = *(const short8*)(wg2 + 4096 + (nt * 2 + ks) * 512 + lane * 8);
            short8 Ahf = ks ? Hh1 : Hh0;
            short8 Alf = ks ? Hl1 : Hl0;
            acc2[nt] = __builtin_amdgcn_mfma_f32_16x16x32_bf16(Ahf, Bh, acc2[nt], 0, 0, 0);
            acc2[nt] = __builtin_amdgcn_mfma_f32_16x16x32_bf16(Ahf, Bl, acc2[nt], 0, 0, 0);
            acc2[nt] = __builtin_amdgcn_mfma_f32_16x16x32_bf16(Alf, Bh, acc2[nt], 0, 0, 0);
        }
    }

    // ---- epilogue: bf16 z write + BN partials + per-graph raw pooling
    int widx = wave * 16;
    int gfirst = sBatch[widx], glast = sBatch[widx + 15];
    bool uni = (gfirst == glast) && (gfirst >= 0);
#pragma unroll
    for (int nt = 0; nt < 4; nt++) {
        int col = nt * 16 + m;
        float b = B2[col];
        float vv[4];
        float s = 0.f, s2 = 0.f;
#pragma unroll
        for (int r = 0; r < 4; r++) {
            int gr = row0 + quad * 4 + r;
            float v = fmaxf(acc2[nt][r] + b, 0.f);
            if (gr < N_NODES) {
                if (write_z) zb[(size_t)gr * DIM + col] = bf16_rn(v);
                s += v;
                s2 = fmaf(v, v, s2);
                vv[r] = v;
            } else {
                vv[r] = 0.f;
            }
        }
        float sf = s, s2f = s2;
        sf  += __shfl_xor(sf, 16);  sf  += __shfl_xor(sf, 32);
        s2f += __shfl_xor(s2f, 16); s2f += __shfl_xor(s2f, 32);
        if (quad == 0) {
            atomicAdd(&sSum[col], sf);
            atomicAdd(&sSum[DIM + col], s2f);
            if (uni) atomicAdd(&praw[(size_t)gfirst * DIM + col], sf);
        }
        if (!uni) {
            int cur = -1; float run = 0.f;
#pragma unroll
            for (int r = 0; r < 4; r++) {
                int g = sBatch[widx + quad * 4 + r];
                if (g != cur) {
                    if (cur >= 0 && run != 0.f)
                        atomicAdd(&praw[(size_t)cur * DIM + col], run);
                    run = 0.f; cur = g;
                }
                run += vv[r];
            }
            if (cur >= 0 && run != 0.f)
                atomicAdd(&praw[(size_t)cur * DIM + col], run);
        }
    }
    __syncthreads();
    if (tid < 2 * DIM)
        atomicAdd(&sums_part[(size_t)(blockIdx.x & (N_PART - 1)) * 2 * DIM + tid], sSum[tid]);
}

// ---------- final 2-layer MLP; pooled row assembled inline from partials
__global__ __launch_bounds__(192) void final_mlp(const float* __restrict__ sums_part,
    const float* __restrict__ praw,
    const float* __restrict__ gamma, const float* __restrict__ beta,
    const int* __restrict__ cntg,
    const float* __restrict__ PW1, const float* __restrict__ PB1,
    const float* __restrict__ PW2, const float* __restrict__ PB2,
    float* __restrict__ out) {
    __shared__ float row[D3];
    __shared__ float hid[D3];
    int g = blockIdx.x, j = threadIdx.x;
    {   // inline assemble_pooled for element (g, j)
        int L = j >> 6, c = j & 63;
        const float* sp = sums_part + (size_t)L * N_PART * 2 * DIM;
        float s = 0.f, q = 0.f;
#pragma unroll
        for (int p = 0; p < N_PART; p++) {
            s += sp[p * 2 * DIM + c];
            q += sp[p * 2 * DIM + DIM + c];
        }
        const float inv_n = 1.0f / (float)N_NODES;
        float mu  = s * inv_n;
        float var = q * inv_n - mu * mu;
        float sc  = gamma[L * DIM + c] / sqrtf(var + BN_EPS);
        float sh  = beta[L * DIM + c] - mu * sc;
        row[j] = fmaf(sc, praw[((size_t)L * N_GRAPHS + g) * DIM + c],
                      (float)cntg[g] * sh);
    }
    __syncthreads();
    float acc = PB1[j];
    for (int k = 0; k < D3; k++) acc = fmaf(row[k], PW1[k * D3 + j], acc);
    hid[j] = fmaxf(acc, 0.f);
    __syncthreads();
    float acc2 = PB2[j];
    for (int k = 0; k < D3; k++) acc2 = fmaf(hid[k], PW2[k * D3 + j], acc2);
    out[(size_t)g * D3 + j] = acc2;
}

extern "C" void kernel_launch(void* const* d_in, const int* in_sizes, int n_in,
                              void* d_out, int out_size, void* d_ws, size_t ws_size,
                              hipStream_t stream) {
    const float* x     = (const float*)d_in[0];
    const int*   ei    = (const int*)d_in[1];
    const int*   batch = (const int*)d_in[2];
    const float* W1    = (const float*)d_in[3];
    const float* B1    = (const float*)d_in[4];
    const float* W2    = (const float*)d_in[5];
    const float* B2    = (const float*)d_in[6];
    const float* gamma = (const float*)d_in[7];
    const float* beta  = (const float*)d_in[8];
    const float* PW1   = (const float*)d_in[9];
    const float* PB1   = (const float*)d_in[10];
    const float* PW2   = (const float*)d_in[11];
    const float* PB2   = (const float*)d_in[12];
    float* out = (float*)d_out;

    // -------- workspace layout (~50 MB of 256 MB)
    float*    bufA  = (float*)d_ws;                              // 3,200,000 f (gather out)
    unsigned short* zb = (unsigned short*)(bufA + (size_t)N_NODES * DIM); // 3,200,000 u16
    unsigned short* xb = zb + (size_t)N_NODES * DIM;             // 3,200,000 u16
    unsigned* ebuf  = (unsigned*)(xb + (size_t)N_NODES * DIM);   // 782*2048 u32
    int*      csr   = (int*)(ebuf + (size_t)NBKT * ECAP);        // 782*2048 i (fixed regions)
    int*      rp2   = csr + NBKT * ECAP;                         // 782*65 -> 50,832
    int*      bcnt  = rp2 + 50832;                               // 784 i (written fully)
    int*      counts = bcnt + 784;                               // 153,272 i (written fully)
    int*      offs   = counts + NBKT * NPB;                      // 153,272 i (written fully)
    unsigned short* wfrag = (unsigned short*)(offs + NBKT * NPB); // 49,152 u16
    int*      cntg  = (int*)(wfrag + 49152);                     // 256 i (written fully)
    // ---- zeroed region
    float*    sums_part = (float*)(cntg + N_GRAPHS);             // 3*8*128 = 3,072 f
    float*    praw  = sums_part + N_LAYERS * N_PART * 2 * DIM;   // 49,152 f

    const int* src = ei;
    const int* dst = ei + N_EDGES;

    const size_t zero_bytes =
        (size_t)(N_LAYERS * N_PART * 2 * DIM + N_LAYERS * N_GRAPHS * DIM) * sizeof(float);
    hipMemsetAsync(sums_part, 0, zero_bytes, stream);

    // -------- CSR build: deterministic two-pass partition (no global atomics)
    pass1_hist<<<NPB, 256, 0, stream>>>(dst, counts);
    bucket_scan<<<NBKT, 256, 0, stream>>>(counts, offs, bcnt);
    pass2_scatter<<<NPB, 256, 0, stream>>>(src, dst, offs, ebuf);
    sort_and_setup<<<NBKT + CVT_BLOCKS + PREP_BLOCKS + 1, 256, 0, stream>>>(
        ebuf, bcnt, csr, rp2, x, xb, W1, W2, wfrag, batch, cntg);

    // -------- layers: gather(+in-block BN stats) -> mlp(bf16 z + stats + pool)
    const int GB = (N_NODES + 3) / 4;     // 12500
    const int MB = (N_NODES + 63) / 64;   // 782
    for (int L = 0; L < N_LAYERS; ++L) {
        int write_z = (L < N_LAYERS - 1);
        gather_bf16<<<GB, 256, 0, stream>>>(
            (L == 0) ? xb : zb, bufA, rp2, csr,
            (L == 0) ? (const float*)nullptr : sums_part + (size_t)(L - 1) * N_PART * 2 * DIM,
            gamma + (size_t)(L ? L - 1 : 0) * DIM,
            beta + (size_t)(L ? L - 1 : 0) * DIM);
        mlp_mfma<<<MB, 256, 0, stream>>>(
            bufA, zb,
            wfrag + (size_t)L * 2 * 8192, B1 + (size_t)L * DIM, B2 + (size_t)L * DIM,
            sums_part + (size_t)L * N_PART * 2 * DIM,
            praw + (size_t)L * N_GRAPHS * DIM, batch, write_z);
    }

    final_mlp<<<N_GRAPHS, 192, 0, stream>>>(
        sums_part, praw, gamma, beta, cntg, PW1, PB1, PW2, PB2, out);
}

// Round 15
// 256.885 us; speedup vs baseline: 1.8578x; 1.0075x over previous
//
#include <hip/hip_runtime.h>

#define N_NODES 50000
#define N_EDGES 800000
#define DIM 64
#define N_LAYERS 3
#define N_GRAPHS 256
#define BN_EPS 1e-5f
#define D3 (DIM * N_LAYERS)
#define N_PART 8
#define NBKT 782          // ceil(50000/64) destination buckets
#define NPB 196           // partition blocks (4096 edges each)
#define ECAP 2048         // fixed capacity per bucket (mean 1023, sigma ~32)
#define CVT_BLOCKS 3125   // convert_x blocks (800,000 float4 / 256)
#define PREP_BLOCKS 96    // prep_weights blocks (24,576 / 256)
#define ZF4 13056         // float4s to zero: (3*8*128 + 3*256*64)/4

typedef __attribute__((ext_vector_type(8))) short short8;
typedef __attribute__((ext_vector_type(4))) float floatx4;

// ---------------------------------------------------------- bf16 split utils
__device__ inline unsigned short bf16_rn(float f) {
    unsigned u = __float_as_uint(f);
    u += 0x7FFF + ((u >> 16) & 1);
    return (unsigned short)(u >> 16);
}
__device__ inline float bf16_f(unsigned short b) {
    return __uint_as_float(((unsigned)b) << 16);
}
__device__ inline void split8(float4 a, float4 b, short8* hi, short8* lo) {
    float v[8] = {a.x, a.y, a.z, a.w, b.x, b.y, b.z, b.w};
#pragma unroll
    for (int i = 0; i < 8; i++) {
        unsigned short h = bf16_rn(v[i]);
        (*hi)[i] = (short)h;
        (*lo)[i] = (short)bf16_rn(v[i] - bf16_f(h));
    }
}

// -------- pass 1: per-block LDS hist -> counts[bucket][block]; also zeros
// the sums_part/praw accumulator region (replaces a hipMemsetAsync dispatch)
__global__ __launch_bounds__(256) void pass1_hist(const int* __restrict__ dst,
                                                  int* __restrict__ counts,
                                                  float4* __restrict__ zbuf) {
    int zi = blockIdx.x * 256 + threadIdx.x;
    if (zi < ZF4) zbuf[zi] = (float4){0.f, 0.f, 0.f, 0.f};
    __shared__ int hcnt[NBKT];
    for (int i = threadIdx.x; i < NBKT; i += 256) hcnt[i] = 0;
    __syncthreads();
    int base = blockIdx.x * 4096;
#pragma unroll
    for (int k = 0; k < 16; k++) {
        int e = base + k * 256 + threadIdx.x;
        if (e < N_EDGES) atomicAdd(&hcnt[dst[e] >> 6], 1);   // LDS atomic (native)
    }
    __syncthreads();
    for (int i = threadIdx.x; i < NBKT; i += 256)
        counts[i * NPB + blockIdx.x] = hcnt[i];
}

// -------- per-bucket exclusive scan over the 196 block counts -> offs, totals
__global__ __launch_bounds__(256) void bucket_scan(const int* __restrict__ counts,
                                                   int* __restrict__ offs,
                                                   int* __restrict__ bcnt) {
    __shared__ int s[256];
    int b = blockIdx.x, t = threadIdx.x;
    int v = (t < NPB) ? counts[b * NPB + t] : 0;
    s[t] = v;
    __syncthreads();
    for (int off = 1; off < 256; off <<= 1) {
        int u = (t >= off) ? s[t - off] : 0;
        __syncthreads();
        s[t] += u;
        __syncthreads();
    }
    if (t < NPB) offs[b * NPB + t] = s[t] - v;
    if (t == NPB - 1) bcnt[b] = s[t];
}

// -------- pass 2: deterministic scatter via LDS position counters
__global__ __launch_bounds__(256) void pass2_scatter(const int* __restrict__ src,
                                                     const int* __restrict__ dst,
                                                     const int* __restrict__ offs,
                                                     unsigned* __restrict__ ebuf) {
    __shared__ int loff[NBKT];
    int blk = blockIdx.x;
    for (int i = threadIdx.x; i < NBKT; i += 256)
        loff[i] = offs[i * NPB + blk];
    __syncthreads();
    int base = blk * 4096;
#pragma unroll
    for (int k = 0; k < 16; k++) {
        int e = base + k * 256 + threadIdx.x;
        if (e < N_EDGES) {
            int d = dst[e];
            int b = d >> 6;
            int pos = atomicAdd(&loff[b], 1);     // LDS int atomic (native)
            ebuf[(size_t)b * ECAP + pos] = ((unsigned)src[e] << 6) | (unsigned)(d & 63);
        }
    }
}

// ===== fused: bucket counting-sort (blocks [0,NBKT)) + setup work
__global__ __launch_bounds__(256) void sort_and_setup(
    const unsigned* __restrict__ ebuf, const int* __restrict__ bcnt,
    int* __restrict__ csr, int* __restrict__ rp2,
    const float* __restrict__ x, unsigned short* __restrict__ xb,
    const float* __restrict__ W1, const float* __restrict__ W2,
    unsigned short* __restrict__ wf,
    const int* __restrict__ batch, int* __restrict__ cntg) {
    int blk = blockIdx.x, tid = threadIdx.x;

    if (blk < NBKT) {                     // ---- bucket counting sort
        __shared__ unsigned ent[ECAP];
        __shared__ int cnt[64], basea[64], fill[64];
        int b = blk;
        int start = b * ECAP;
        int T = bcnt[b];
        const unsigned* eb = ebuf + (size_t)b * ECAP;
        if (tid < 64) cnt[tid] = 0;
        for (int i = tid; i < T; i += 256) ent[i] = eb[i];
        __syncthreads();
        for (int i = tid; i < T; i += 256) atomicAdd(&cnt[ent[i] & 63], 1);
        __syncthreads();
        if (tid < 64) {
            int v = cnt[tid], xp = v;
#pragma unroll
            for (int off = 1; off < 64; off <<= 1) {
                int y = __shfl_up(xp, off);
                if (tid >= off) xp += y;
            }
            basea[tid] = xp - v;
            fill[tid] = 0;
            rp2[b * 65 + tid] = start + xp - v;
            if (tid == 63) rp2[b * 65 + 64] = start + xp;
        }
        __syncthreads();
        for (int i = tid; i < T; i += 256) {
            unsigned e = ent[i];
            int c = e & 63;
            int pos = basea[c] + atomicAdd(&fill[c], 1);
            csr[start + pos] = (int)(e >> 6);
        }
        return;
    }
    int sb = blk - NBKT;
    if (sb < CVT_BLOCKS) {                // ---- convert x to bf16
        int i = sb * 256 + tid;
        float4 v = ((const float4*)x)[i];
        ushort4 o;
        o.x = bf16_rn(v.x); o.y = bf16_rn(v.y);
        o.z = bf16_rn(v.z); o.w = bf16_rn(v.w);
        ((ushort4*)xb)[i] = o;
        return;
    }
    sb -= CVT_BLOCKS;
    if (sb < PREP_BLOCKS) {               // ---- pack weight fragments
        int idx = sb * 256 + tid;
        int j    = idx & 7;
        int lane = (idx >> 3) & 63;
        int ks   = (idx >> 9) & 1;
        int nt   = (idx >> 10) & 3;
        int gemm = (idx >> 12) & 1;
        int layer = idx >> 13;
        int n = nt * 16 + (lane & 15);
        int k = ks * 32 + (lane >> 4) * 8 + j;
        const float* W = (gemm ? W2 : W1) + (size_t)layer * DIM * DIM;
        float w = W[k * DIM + n];
        unsigned short hi = bf16_rn(w);
        unsigned short lo = bf16_rn(w - bf16_f(hi));
        size_t base = ((size_t)layer * 2 + gemm) * 8192;
        int f = nt * 2 + ks;
        wf[base + f * 512 + lane * 8 + j]        = hi;
        wf[base + 4096 + f * 512 + lane * 8 + j] = lo;
        return;
    }
    // ---- per-graph node counts via binary search (batch sorted)
    int g = tid;
    int lo = 0, hi = N_NODES;
    while (lo < hi) { int mid = (lo + hi) >> 1; if (batch[mid] < g) lo = mid + 1; else hi = mid; }
    int start = lo;
    lo = 0; hi = N_NODES;
    while (lo < hi) { int mid = (lo + hi) >> 1; if (batch[mid] < g + 1) lo = mid + 1; else hi = mid; }
    cntg[g] = lo - start;
}

// -------- gather (bf16 rows) + prev-layer BN affine computed in-block
// 8 lanes per row; one wave-wide ushort8 load fetches 8 neighbor rows.
__global__ __launch_bounds__(256) void gather_bf16(const unsigned short* __restrict__ hb,
                                                   float* __restrict__ z,
                                                   const int* __restrict__ rp2,
                                                   const int* __restrict__ csr,
                                                   const float* __restrict__ spPrev,
                                                   const float* __restrict__ gammaL,
                                                   const float* __restrict__ betaL) {
    __shared__ float sRed[2 * DIM];
    __shared__ float sSS[2 * DIM];
    int tid = threadIdx.x;

    // issue row-pointer (and self-row) loads BEFORE the stats preamble so
    // they are in flight during the LDS reduction + barriers
    int node = blockIdx.x * 4 + (tid >> 6);     // 12500*4 == 50000: exact
    int lane = tid & 63;
    int c8 = lane & 7, sub = lane >> 3;
    int rbase = (node >> 6) * 65 + (node & 63);
    int e0 = rp2[rbase], end = rp2[rbase + 1];

    if (spPrev) {                       // finalize_stats folded into every block
        if (tid < 2 * DIM) {
            float s = 0.f;
#pragma unroll
            for (int p = 0; p < N_PART; p++) s += spPrev[p * 2 * DIM + tid];
            sRed[tid] = s;
        }
        __syncthreads();
        if (tid < DIM) {
            const float inv_n = 1.0f / (float)N_NODES;
            float mu  = sRed[tid] * inv_n;
            float var = sRed[DIM + tid] * inv_n - mu * mu;
            float sc  = gammaL[tid] / sqrtf(var + BN_EPS);
            sSS[tid]       = sc;
            sSS[DIM + tid] = betaL[tid] - mu * sc;
        }
        __syncthreads();
    }

    int e = e0;
    float degf = 1.f + (float)(end - e);
    float a[8];
#pragma unroll
    for (int i = 0; i < 8; i++) a[i] = 0.f;
    if (sub == 0) {
        short8 sv = *(const short8*)&hb[(size_t)node * DIM + c8 * 8];
#pragma unroll
        for (int i = 0; i < 8; i++) a[i] = bf16_f((unsigned short)sv[i]);
    }
    for (; e + 16 <= end; e += 16) {
        int i0 = csr[e + sub];
        int i1 = csr[e + 8 + sub];
        short8 r0 = *(const short8*)&hb[(size_t)i0 * DIM + c8 * 8];
        short8 r1 = *(const short8*)&hb[(size_t)i1 * DIM + c8 * 8];
#pragma unroll
        for (int i = 0; i < 8; i++)
            a[i] += bf16_f((unsigned short)r0[i]) + bf16_f((unsigned short)r1[i]);
    }
    for (; e + 8 <= end; e += 8) {
        int i0 = csr[e + sub];
        short8 r0 = *(const short8*)&hb[(size_t)i0 * DIM + c8 * 8];
#pragma unroll
        for (int i = 0; i < 8; i++) a[i] += bf16_f((unsigned short)r0[i]);
    }
    int rem = end - e;
    if (sub < rem) {
        short8 r0 = *(const short8*)&hb[(size_t)csr[e + sub] * DIM + c8 * 8];
#pragma unroll
        for (int i = 0; i < 8; i++) a[i] += bf16_f((unsigned short)r0[i]);
    }
#pragma unroll
    for (int i = 0; i < 8; i++) {
        a[i] += __shfl_xor(a[i], 8);
        a[i] += __shfl_xor(a[i], 16);
        a[i] += __shfl_xor(a[i], 32);
    }
    if (sub == 0) {
        int ch = c8 * 8;
        float4 o1, o2;
        if (spPrev) {
            o1.x = fmaf(a[0], sSS[ch + 0], degf * sSS[DIM + ch + 0]);
            o1.y = fmaf(a[1], sSS[ch + 1], degf * sSS[DIM + ch + 1]);
            o1.z = fmaf(a[2], sSS[ch + 2], degf * sSS[DIM + ch + 2]);
            o1.w = fmaf(a[3], sSS[ch + 3], degf * sSS[DIM + ch + 3]);
            o2.x = fmaf(a[4], sSS[ch + 4], degf * sSS[DIM + ch + 4]);
            o2.y = fmaf(a[5], sSS[ch + 5], degf * sSS[DIM + ch + 5]);
            o2.z = fmaf(a[6], sSS[ch + 6], degf * sSS[DIM + ch + 6]);
            o2.w = fmaf(a[7], sSS[ch + 7], degf * sSS[DIM + ch + 7]);
        } else {
            o1.x = a[0]; o1.y = a[1]; o1.z = a[2]; o1.w = a[3];
            o2.x = a[4]; o2.y = a[5]; o2.z = a[6]; o2.w = a[7];
        }
        *(float4*)&z[(size_t)node * DIM + ch] = o1;
        *(float4*)&z[(size_t)node * DIM + ch + 4] = o2;
    }
}

// ------- MFMA MLP: bf16 z' = relu(relu(zW1+B1)W2+B2) + BN partials + raw pool
#define HS_STRIDE 68
__global__ __launch_bounds__(256) void mlp_mfma(const float* __restrict__ z,
    unsigned short* __restrict__ zb,
    const unsigned short* __restrict__ wfL,
    const float* __restrict__ B1, const float* __restrict__ B2,
    float* __restrict__ sums_part, float* __restrict__ praw,
    const int* __restrict__ batch, int write_z) {
    __shared__ float sH[4][16 * HS_STRIDE];
    __shared__ float sSum[2 * DIM];
    __shared__ int   sBatch[64];

    int tid = threadIdx.x, wave = tid >> 6, lane = tid & 63;
    int blk0 = blockIdx.x * 64;
    if (tid < 2 * DIM) sSum[tid] = 0.f;
    if (tid < 64) sBatch[tid] = (blk0 + tid < N_NODES) ? batch[blk0 + tid] : -1;
    __syncthreads();

    int m = lane & 15, quad = lane >> 4;
    int row0 = blk0 + wave * 16;
    int grow = row0 + m;
    int ar = grow < N_NODES ? grow : N_NODES - 1;

    const float4* zr = (const float4*)(z + (size_t)ar * DIM);
    float4 a0 = zr[quad * 2],     a1 = zr[quad * 2 + 1];
    float4 a2 = zr[8 + quad * 2], a3 = zr[8 + quad * 2 + 1];
    short8 Ah0, Al0, Ah1, Al1;
    split8(a0, a1, &Ah0, &Al0);
    split8(a2, a3, &Ah1, &Al1);

    floatx4 acc[4];
#pragma unroll
    for (int nt = 0; nt < 4; nt++) acc[nt] = (floatx4){0.f, 0.f, 0.f, 0.f};
#pragma unroll
    for (int nt = 0; nt < 4; nt++) {
#pragma unroll
        for (int ks = 0; ks < 2; ks++) {
            const short8 Bh = *(const short8*)(wfL + (nt * 2 + ks) * 512 + lane * 8);
            const short8 Bl = *(const short8*)(wfL + 4096 + (nt * 2 + ks) * 512 + lane * 8);
            short8 Ahf = ks ? Ah1 : Ah0;
            short8 Alf = ks ? Al1 : Al0;
            acc[nt] = __builtin_amdgcn_mfma_f32_16x16x32_bf16(Ahf, Bh, acc[nt], 0, 0, 0);
            acc[nt] = __builtin_amdgcn_mfma_f32_16x16x32_bf16(Ahf, Bl, acc[nt], 0, 0, 0);
            acc[nt] = __builtin_amdgcn_mfma_f32_16x16x32_bf16(Alf, Bh, acc[nt], 0, 0, 0);
        }
    }

    float* Hs = sH[wave];
#pragma unroll
    for (int nt = 0; nt < 4; nt++) {
        int col = nt * 16 + m;
        float b = B1[col];
#pragma unroll
        for (int r = 0; r < 4; r++) {
            int lr = quad * 4 + r;
            Hs[lr * HS_STRIDE + col] = fmaxf(acc[nt][r] + b, 0.f);
        }
    }
    float4 h0 = *(const float4*)&Hs[m * HS_STRIDE + quad * 8];
    float4 h1 = *(const float4*)&Hs[m * HS_STRIDE + quad * 8 + 4];
    float4 h2 = *(const float4*)&Hs[m * HS_STRIDE + 32 + quad * 8];
    float4 h3 = *(const float4*)&Hs[m * HS_STRIDE + 32 + quad * 8 + 4];
    short8 Hh0, Hl0, Hh1, Hl1;
    split8(h0, h1, &Hh0, &Hl0);
    split8(h2, h3, &Hh1, &Hl1);

    floatx4 acc2[4];
#pragma unroll
    for (int nt = 0; nt < 4; nt++) acc2[nt] = (floatx4){0.f, 0.f, 0.f, 0.f};
    const unsigned short* wg2 = wfL + 8192;
#pragma unroll
    for (int nt = 0; nt < 4; nt++) {
#pragma unroll
        for (int ks = 0; ks < 2; ks++) {
            const short8 Bh = *(const short8*)(wg2 + (nt * 2 + ks) * 512 + lane * 8);
            const short8 Bl = *(const short8*)(wg2 + 4096 + (nt * 2 + ks) * 512 + lane * 8);
            short8 Ahf = ks ? Hh1 : Hh0;
            short8 Alf = ks ? Hl1 : Hl0;
            acc2[nt] = __builtin_amdgcn_mfma_f32_16x16x32_bf16(Ahf, Bh, acc2[nt], 0, 0, 0);
            acc2[nt] = __builtin_amdgcn_mfma_f32_16x16x32_bf16(Ahf, Bl, acc2[nt], 0, 0, 0);
            acc2[nt] = __builtin_amdgcn_mfma_f32_16x16x32_bf16(Alf, Bh, acc2[nt], 0, 0, 0);
        }
    }

    // ---- epilogue: bf16 z write + BN partials + per-graph raw pooling
    int widx = wave * 16;
    int gfirst = sBatch[widx], glast = sBatch[widx + 15];
    bool uni = (gfirst == glast) && (gfirst >= 0);
#pragma unroll
    for (int nt = 0; nt < 4; nt++) {
        int col = nt * 16 + m;
        float b = B2[col];
        float vv[4];
        float s = 0.f, s2 = 0.f;
#pragma unroll
        for (int r = 0; r < 4; r++) {
            int gr = row0 + quad * 4 + r;
            float v = fmaxf(acc2[nt][r] + b, 0.f);
            if (gr < N_NODES) {
                if (write_z) zb[(size_t)gr * DIM + col] = bf16_rn(v);
                s += v;
                s2 = fmaf(v, v, s2);
                vv[r] = v;
            } else {
                vv[r] = 0.f;
            }
        }
        float sf = s, s2f = s2;
        sf  += __shfl_xor(sf, 16);  sf  += __shfl_xor(sf, 32);
        s2f += __shfl_xor(s2f, 16); s2f += __shfl_xor(s2f, 32);
        if (quad == 0) {
            atomicAdd(&sSum[col], sf);
            atomicAdd(&sSum[DIM + col], s2f);
            if (uni) atomicAdd(&praw[(size_t)gfirst * DIM + col], sf);
        }
        if (!uni) {
            int cur = -1; float run = 0.f;
#pragma unroll
            for (int r = 0; r < 4; r++) {
                int g = sBatch[widx + quad * 4 + r];
                if (g != cur) {
                    if (cur >= 0 && run != 0.f)
                        atomicAdd(&praw[(size_t)cur * DIM + col], run);
                    run = 0.f; cur = g;
                }
                run += vv[r];
            }
            if (cur >= 0 && run != 0.f)
                atomicAdd(&praw[(size_t)cur * DIM + col], run);
        }
    }
    __syncthreads();
    if (tid < 2 * DIM)
        atomicAdd(&sums_part[(size_t)(blockIdx.x & (N_PART - 1)) * 2 * DIM + tid], sSum[tid]);
}

// ---------- final 2-layer MLP; pooled row assembled inline from partials
__global__ __launch_bounds__(192) void final_mlp(const float* __restrict__ sums_part,
    const float* __restrict__ praw,
    const float* __restrict__ gamma, const float* __restrict__ beta,
    const int* __restrict__ cntg,
    const float* __restrict__ PW1, const float* __restrict__ PB1,
    const float* __restrict__ PW2, const float* __restrict__ PB2,
    float* __restrict__ out) {
    __shared__ float row[D3];
    __shared__ float hid[D3];
    int g = blockIdx.x, j = threadIdx.x;
    {   // inline assemble_pooled for element (g, j)
        int L = j >> 6, c = j & 63;
        const float* sp = sums_part + (size_t)L * N_PART * 2 * DIM;
        float s = 0.f, q = 0.f;
#pragma unroll
        for (int p = 0; p < N_PART; p++) {
            s += sp[p * 2 * DIM + c];
            q += sp[p * 2 * DIM + DIM + c];
        }
        const float inv_n = 1.0f / (float)N_NODES;
        float mu  = s * inv_n;
        float var = q * inv_n - mu * mu;
        float sc  = gamma[L * DIM + c] / sqrtf(var + BN_EPS);
        float sh  = beta[L * DIM + c] - mu * sc;
        row[j] = fmaf(sc, praw[((size_t)L * N_GRAPHS + g) * DIM + c],
                      (float)cntg[g] * sh);
    }
    __syncthreads();
    float acc = PB1[j];
    for (int k = 0; k < D3; k++) acc = fmaf(row[k], PW1[k * D3 + j], acc);
    hid[j] = fmaxf(acc, 0.f);
    __syncthreads();
    float acc2 = PB2[j];
    for (int k = 0; k < D3; k++) acc2 = fmaf(hid[k], PW2[k * D3 + j], acc2);
    out[(size_t)g * D3 + j] = acc2;
}

extern "C" void kernel_launch(void* const* d_in, const int* in_sizes, int n_in,
                              void* d_out, int out_size, void* d_ws, size_t ws_size,
                              hipStream_t stream) {
    const float* x     = (const float*)d_in[0];
    const int*   ei    = (const int*)d_in[1];
    const int*   batch = (const int*)d_in[2];
    const float* W1    = (const float*)d_in[3];
    const float* B1    = (const float*)d_in[4];
    const float* W2    = (const float*)d_in[5];
    const float* B2    = (const float*)d_in[6];
    const float* gamma = (const float*)d_in[7];
    const float* beta  = (const float*)d_in[8];
    const float* PW1   = (const float*)d_in[9];
    const float* PB1   = (const float*)d_in[10];
    const float* PW2   = (const float*)d_in[11];
    const float* PB2   = (const float*)d_in[12];
    float* out = (float*)d_out;

    // -------- workspace layout (~50 MB of 256 MB)
    float*    bufA  = (float*)d_ws;                              // 3,200,000 f (gather out)
    unsigned short* zb = (unsigned short*)(bufA + (size_t)N_NODES * DIM); // 3,200,000 u16
    unsigned short* xb = zb + (size_t)N_NODES * DIM;             // 3,200,000 u16
    unsigned* ebuf  = (unsigned*)(xb + (size_t)N_NODES * DIM);   // 782*2048 u32
    int*      csr   = (int*)(ebuf + (size_t)NBKT * ECAP);        // 782*2048 i (fixed regions)
    int*      rp2   = csr + NBKT * ECAP;                         // 782*65 -> 50,832
    int*      bcnt  = rp2 + 50832;                               // 784 i (written fully)
    int*      counts = bcnt + 784;                               // 153,272 i (written fully)
    int*      offs   = counts + NBKT * NPB;                      // 153,272 i (written fully)
    unsigned short* wfrag = (unsigned short*)(offs + NBKT * NPB); // 49,152 u16
    int*      cntg  = (int*)(wfrag + 49152);                     // 256 i (written fully)
    // ---- accumulator region (zeroed by pass1_hist)
    float*    sums_part = (float*)(cntg + N_GRAPHS);             // 3*8*128 = 3,072 f
    float*    praw  = sums_part + N_LAYERS * N_PART * 2 * DIM;   // 49,152 f

    const int* src = ei;
    const int* dst = ei + N_EDGES;

    // -------- CSR build: deterministic two-pass partition (no global atomics)
    pass1_hist<<<NPB, 256, 0, stream>>>(dst, counts, (float4*)sums_part);
    bucket_scan<<<NBKT, 256, 0, stream>>>(counts, offs, bcnt);
    pass2_scatter<<<NPB, 256, 0, stream>>>(src, dst, offs, ebuf);
    sort_and_setup<<<NBKT + CVT_BLOCKS + PREP_BLOCKS + 1, 256, 0, stream>>>(
        ebuf, bcnt, csr, rp2, x, xb, W1, W2, wfrag, batch, cntg);

    // -------- layers: gather(+in-block BN stats) -> mlp(bf16 z + stats + pool)
    const int GB = (N_NODES + 3) / 4;     // 12500
    const int MB = (N_NODES + 63) / 64;   // 782
    for (int L = 0; L < N_LAYERS; ++L) {
        int write_z = (L < N_LAYERS - 1);
        gather_bf16<<<GB, 256, 0, stream>>>(
            (L == 0) ? xb : zb, bufA, rp2, csr,
            (L == 0) ? (const float*)nullptr : sums_part + (size_t)(L - 1) * N_PART * 2 * DIM,
            gamma + (size_t)(L ? L - 1 : 0) * DIM,
            beta + (size_t)(L ? L - 1 : 0) * DIM);
        mlp_mfma<<<MB, 256, 0, stream>>>(
            bufA, zb,
            wfrag + (size_t)L * 2 * 8192, B1 + (size_t)L * DIM, B2 + (size_t)L * DIM,
            sums_part + (size_t)L * N_PART * 2 * DIM,
            praw + (size_t)L * N_GRAPHS * DIM, batch, write_z);
    }

    final_mlp<<<N_GRAPHS, 192, 0, stream>>>(
        sums_part, praw, gamma, beta, cntg, PW1, PB1, PW2, PB2, out);
}